// Round 1
// baseline (4077.291 us; speedup 1.0000x reference)
//
#include <hip/hip_runtime.h>

#define NN 50000
#define DD 128
#define EE 800000
#define TT 400000
#define KM 32

static constexpr float INV_SQRT_D = 0.08838834764831845f; // 1/sqrt(128)
static constexpr float INV_D = 1.f / 128.f;

__device__ __forceinline__ float softplus_f(float x) {
  return (x > 20.f) ? x : log1pf(__expf(x));
}

__device__ __forceinline__ float gelu_tanh(float x) {
  float x3 = x * x * x;
  float u = 0.7978845608028654f * (x + 0.044715f * x3);
  u = fminf(fmaxf(u, -15.f), 15.f);
  float e = __expf(2.f * u);
  float t = (e - 1.f) / (e + 1.f);
  return 0.5f * x * (1.f + t);
}

// order-preserving float<->uint for atomicMax on floats
__device__ __forceinline__ unsigned ford(float f) {
  unsigned u = __float_as_uint(f);
  return (u & 0x80000000u) ? ~u : (u | 0x80000000u);
}
__device__ __forceinline__ float forddec(unsigned u) {
  return __uint_as_float((u & 0x80000000u) ? (u & 0x7fffffffu) : ~u);
}

__device__ __forceinline__ float wredsum(float v) {
#pragma unroll
  for (int m = 32; m; m >>= 1) v += __shfl_xor(v, m, 64);
  return v;
}

// ---------------- LayerNorm forward ----------------
__global__ __launch_bounds__(256) void ln_fwd(const float* __restrict__ X,
                                              const float* __restrict__ gamma,
                                              const float* __restrict__ beta,
                                              float* __restrict__ G,
                                              float* __restrict__ meanv,
                                              float* __restrict__ rstdv) {
  int row = blockIdx.x * 4 + (threadIdx.x >> 6);
  if (row >= NN) return;
  int l = threadIdx.x & 63;
  float2 x2 = *(const float2*)(X + row * DD + 2 * l);
  float mu = wredsum(x2.x + x2.y) * (1.f / DD);
  float d0 = x2.x - mu, d1 = x2.y - mu;
  float var = wredsum(d0 * d0 + d1 * d1) * (1.f / DD);
  float rstd = rsqrtf(var + 1e-5f);
  float2 g2 = *(const float2*)(gamma + 2 * l);
  float2 b2 = *(const float2*)(beta + 2 * l);
  float2 o;
  o.x = d0 * rstd * g2.x + b2.x;
  o.y = d1 * rstd * g2.y + b2.y;
  *(float2*)(G + row * DD + 2 * l) = o;
  if (l == 0) { meanv[row] = mu; rstdv[row] = rstd; }
}

// ---------------- generic 128-wide GEMM: C[M,128] = A[M,128] @ (W or W^T) ----------------
__global__ __launch_bounds__(256, 1) void gemm128(const float* __restrict__ A,
                                                  const float* __restrict__ W,
                                                  float* __restrict__ C, int M,
                                                  int transW, int accum) {
  __shared__ float As[64][132];
  __shared__ float Wst[128][136]; // Wst[k][j] = contribution weight for depth k, out col j
  const int tid = threadIdx.x;
  const int r0 = blockIdx.x * 64;
  for (int idx = tid; idx < 128 * 128; idx += 256) {
    int k = idx >> 7, j = idx & 127;
    Wst[k][j] = transW ? W[j * 128 + k] : W[k * 128 + j];
  }
  for (int idx = tid; idx < 64 * 128; idx += 256) {
    int r = idx >> 7, d = idx & 127;
    int gr = r0 + r;
    As[r][d] = (gr < M) ? A[gr * 128 + d] : 0.f;
  }
  __syncthreads();
  const int tx = tid & 15, ty = tid >> 4;
  float acc[4][8];
#pragma unroll
  for (int i = 0; i < 4; i++)
#pragma unroll
    for (int j = 0; j < 8; j++) acc[i][j] = 0.f;
  for (int k = 0; k < 128; k += 4) {
    float a[4][4];
#pragma unroll
    for (int i = 0; i < 4; i++) {
      float4 v = *(const float4*)&As[ty * 4 + i][k];
      a[i][0] = v.x; a[i][1] = v.y; a[i][2] = v.z; a[i][3] = v.w;
    }
    float w[4][8];
#pragma unroll
    for (int dk = 0; dk < 4; dk++) {
      float4 v0 = *(const float4*)&Wst[k + dk][tx * 8];
      float4 v1 = *(const float4*)&Wst[k + dk][tx * 8 + 4];
      w[dk][0] = v0.x; w[dk][1] = v0.y; w[dk][2] = v0.z; w[dk][3] = v0.w;
      w[dk][4] = v1.x; w[dk][5] = v1.y; w[dk][6] = v1.z; w[dk][7] = v1.w;
    }
#pragma unroll
    for (int dk = 0; dk < 4; dk++)
#pragma unroll
      for (int i = 0; i < 4; i++)
#pragma unroll
        for (int j = 0; j < 8; j++)
          acc[i][j] = fmaf(a[i][dk], w[dk][j], acc[i][j]);
  }
#pragma unroll
  for (int i = 0; i < 4; i++) {
    int gr = r0 + ty * 4 + i;
    if (gr < M) {
      float* cp = C + gr * 128 + tx * 8;
      if (accum) {
#pragma unroll
        for (int j = 0; j < 8; j++) cp[j] += acc[i][j];
      } else {
#pragma unroll
        for (int j = 0; j < 8; j++) cp[j] = acc[i][j];
      }
    }
  }
}

// ---------------- edge MLP: a2[e] = gelu(ea @ We1 + be1) @ We2 + be2 ----------------
__global__ __launch_bounds__(256) void edge_mlp(const float* __restrict__ EA,
                                                const float* __restrict__ We1,
                                                const float* __restrict__ be1,
                                                const float* __restrict__ We2,
                                                const float* __restrict__ be2,
                                                float* __restrict__ a2) {
  __shared__ float sW1[16 * 128];
  __shared__ float sb1[128];
  __shared__ float sW2[128];
  int tid = threadIdx.x;
  for (int i = tid; i < 2048; i += 256) sW1[i] = We1[i];
  if (tid < 128) { sb1[tid] = be1[tid]; sW2[tid] = We2[tid]; }
  __syncthreads();
  int e = blockIdx.x * 256 + tid;
  if (e >= EE) return;
  float ea[16];
#pragma unroll
  for (int q = 0; q < 4; q++) {
    float4 v = *(const float4*)(EA + (size_t)e * 16 + q * 4);
    ea[q * 4 + 0] = v.x; ea[q * 4 + 1] = v.y; ea[q * 4 + 2] = v.z; ea[q * 4 + 3] = v.w;
  }
  float acc = 0.f;
  for (int j = 0; j < 128; j += 4) {
    float4 h = *(const float4*)&sb1[j];
#pragma unroll
    for (int k = 0; k < 16; k++) {
      float4 wv = *(const float4*)&sW1[k * 128 + j];
      h.x = fmaf(ea[k], wv.x, h.x);
      h.y = fmaf(ea[k], wv.y, h.y);
      h.z = fmaf(ea[k], wv.z, h.z);
      h.w = fmaf(ea[k], wv.w, h.w);
    }
    float4 w2 = *(const float4*)&sW2[j];
    acc = fmaf(gelu_tanh(h.x), w2.x, acc);
    acc = fmaf(gelu_tanh(h.y), w2.y, acc);
    acc = fmaf(gelu_tanh(h.z), w2.z, acc);
    acc = fmaf(gelu_tanh(h.w), w2.w, acc);
  }
  a2[e] = acc + be2[0];
}

// ---------------- order-2 edge passes ----------------
__global__ __launch_bounds__(256) void e2_pass1(const float* __restrict__ Q2,
                                                const float* __restrict__ K2,
                                                const float* __restrict__ a2,
                                                const int* __restrict__ c2,
                                                const int* __restrict__ u2,
                                                const float* __restrict__ pbeta2,
                                                float* __restrict__ s2,
                                                unsigned* __restrict__ m2u) {
  int e = blockIdx.x * 4 + (int)(threadIdx.x >> 6);
  if (e >= EE) return;
  int l = threadIdx.x & 63;
  float b2 = fminf(softplus_f(pbeta2[0]), 5.f);
  int c = c2[e], u = u2[e];
  float2 q = *(const float2*)(Q2 + c * DD + 2 * l);
  float2 k = *(const float2*)(K2 + u * DD + 2 * l);
  float dot = wredsum(q.x * k.x + q.y * k.y);
  if (l == 0) {
    float s = b2 * dot * INV_SQRT_D + a2[e];
    s2[e] = s;
    atomicMax(&m2u[c], ford(s));
  }
}

__global__ __launch_bounds__(256) void e2_pass2(const float* __restrict__ s2,
                                                const int* __restrict__ c2,
                                                const unsigned* __restrict__ m2u,
                                                float* __restrict__ z2) {
  int e = blockIdx.x * 256 + threadIdx.x;
  if (e >= EE) return;
  int c = c2[e];
  atomicAdd(&z2[c], __expf(s2[e] - forddec(m2u[c])));
}

__global__ __launch_bounds__(256) void e2_bwd(const float* __restrict__ Q2,
                                              const float* __restrict__ K2,
                                              const float* __restrict__ s2,
                                              const float* __restrict__ L2,
                                              const int* __restrict__ c2,
                                              const int* __restrict__ u2,
                                              const float* __restrict__ plam2,
                                              float* __restrict__ dQ2,
                                              float* __restrict__ dK2) {
  int e = blockIdx.x * 4 + (int)(threadIdx.x >> 6);
  if (e >= EE) return;
  int l = threadIdx.x & 63;
  float sp = softplus_f(plam2[0]);
  int c = c2[e], u = u2[e];
  float w = -sp * INV_SQRT_D * __expf(s2[e] - L2[c]);
  float2 q = *(const float2*)(Q2 + c * DD + 2 * l);
  float2 k = *(const float2*)(K2 + u * DD + 2 * l);
  atomicAdd(dQ2 + c * DD + 2 * l, w * k.x);
  atomicAdd(dQ2 + c * DD + 2 * l + 1, w * k.y);
  atomicAdd(dK2 + u * DD + 2 * l, w * q.x);
  atomicAdd(dK2 + u * DD + 2 * l + 1, w * q.y);
}

// ---------------- order-3 triplet passes ----------------
__global__ __launch_bounds__(256) void t3_pass1(const float* __restrict__ Q3,
                                                const float* __restrict__ K3,
                                                const float* __restrict__ Tt,
                                                const int* __restrict__ c3,
                                                const int* __restrict__ u3,
                                                const int* __restrict__ v3,
                                                const int* __restrict__ ttau,
                                                const float* __restrict__ pbeta3,
                                                float* __restrict__ s3,
                                                unsigned* __restrict__ m3u) {
  int e = blockIdx.x * 4 + (int)(threadIdx.x >> 6);
  if (e >= TT) return;
  int l = threadIdx.x & 63;
  float b3 = fminf(softplus_f(pbeta3[0]), 5.f);
  int c = c3[e], u = u3[e], v = v3[e], t = ttau[e];
  float2 q = *(const float2*)(Q3 + c * DD + 2 * l);
  float2 ku = *(const float2*)(K3 + u * DD + 2 * l);
  float2 kv = *(const float2*)(K3 + v * DD + 2 * l);
  float2 tv = *(const float2*)(Tt + t * DD + 2 * l);
  float dot = wredsum(q.x * ku.x * kv.x * tv.x + q.y * ku.y * kv.y * tv.y);
  if (l == 0) {
    float s = b3 * dot * INV_D;
    s3[e] = s;
    atomicMax(&m3u[c], ford(s));
  }
}

__global__ __launch_bounds__(256) void t3_pass2(const float* __restrict__ s3,
                                                const int* __restrict__ c3,
                                                const unsigned* __restrict__ m3u,
                                                float* __restrict__ z3) {
  int e = blockIdx.x * 256 + threadIdx.x;
  if (e >= TT) return;
  int c = c3[e];
  atomicAdd(&z3[c], __expf(s3[e] - forddec(m3u[c])));
}

__global__ __launch_bounds__(256) void t3_bwd(const float* __restrict__ Q3,
                                              const float* __restrict__ K3,
                                              const float* __restrict__ Tt,
                                              const float* __restrict__ s3,
                                              const float* __restrict__ L3,
                                              const int* __restrict__ c3,
                                              const int* __restrict__ u3,
                                              const int* __restrict__ v3,
                                              const int* __restrict__ ttau,
                                              const float* __restrict__ plam3,
                                              float* __restrict__ dQ3,
                                              float* __restrict__ dK3) {
  int e = blockIdx.x * 4 + (int)(threadIdx.x >> 6);
  if (e >= TT) return;
  int l = threadIdx.x & 63;
  float sp = softplus_f(plam3[0]);
  int c = c3[e], u = u3[e], v = v3[e], t = ttau[e];
  float w = -sp * INV_D * __expf(s3[e] - L3[c]);
  float2 q = *(const float2*)(Q3 + c * DD + 2 * l);
  float2 ku = *(const float2*)(K3 + u * DD + 2 * l);
  float2 kv = *(const float2*)(K3 + v * DD + 2 * l);
  float2 tv = *(const float2*)(Tt + t * DD + 2 * l);
  atomicAdd(dQ3 + c * DD + 2 * l, w * ku.x * kv.x * tv.x);
  atomicAdd(dQ3 + c * DD + 2 * l + 1, w * ku.y * kv.y * tv.y);
  atomicAdd(dK3 + u * DD + 2 * l, w * q.x * kv.x * tv.x);
  atomicAdd(dK3 + u * DD + 2 * l + 1, w * q.y * kv.y * tv.y);
  atomicAdd(dK3 + v * DD + 2 * l, w * q.x * ku.x * tv.x);
  atomicAdd(dK3 + v * DD + 2 * l + 1, w * q.y * ku.y * tv.y);
}

// ---------------- segment finalize: L = log z + m ----------------
__global__ __launch_bounds__(256) void seg_fin(const unsigned* __restrict__ m2u,
                                               const float* __restrict__ z2,
                                               const unsigned* __restrict__ m3u,
                                               const float* __restrict__ z3,
                                               float* __restrict__ L2,
                                               float* __restrict__ L3) {
  int i = blockIdx.x * 256 + threadIdx.x;
  if (i >= NN) return;
  float z = z2[i];
  L2[i] = (z > 0.f) ? (__logf(z) + forddec(m2u[i])) : 0.f;
  z = z3[i];
  L3[i] = (z > 0.f) ? (__logf(z) + forddec(m3u[i])) : 0.f;
}

// ---------------- memory-bank energy row kernel ----------------
__global__ __launch_bounds__(256) void em_row(const float* __restrict__ Qm,
                                              const float* __restrict__ Km,
                                              const float* __restrict__ pbetam,
                                              const float* __restrict__ plamm,
                                              float* __restrict__ dQm,
                                              float* __restrict__ Lm) {
  __shared__ float sKm[KM * DD];
  int tid = threadIdx.x;
  for (int i = tid; i < KM * DD; i += 256) sKm[i] = Km[i];
  __syncthreads();
  int row = blockIdx.x * 4 + (tid >> 6);
  if (row >= NN) return;
  int l = tid & 63;
  float bm = fminf(softplus_f(pbetam[0]), 5.f);
  float splm = softplus_f(plamm[0]);
  int k = l & 31, h = l >> 5;
  const float* qrow = Qm + row * DD;
  float part = 0.f;
  for (int d0 = 0; d0 < 64; d0++) {
    int d = h * 64 + d0;
    part = fmaf(qrow[d], sKm[k * DD + d], part);
  }
  part += __shfl_xor(part, 32, 64); // full dot for k on all 64 lanes (replicated)
  float sk = bm * part * INV_SQRT_D;
  float mx = sk;
#pragma unroll
  for (int m = 16; m; m >>= 1) mx = fmaxf(mx, __shfl_xor(mx, m, 64));
  float ex = __expf(sk - mx);
  float zz = ex;
#pragma unroll
  for (int m = 16; m; m >>= 1) zz += __shfl_xor(zz, m, 64);
  float lse = mx + __logf(zz);
  if (l == 0) Lm[row] = lse;
  float pk = ex / zz;
  float accx = 0.f, accy = 0.f;
#pragma unroll
  for (int kk = 0; kk < 32; kk++) {
    float pkk = __shfl(pk, kk, 64);
    accx = fmaf(pkk, sKm[kk * DD + 2 * l], accx);
    accy = fmaf(pkk, sKm[kk * DD + 2 * l + 1], accy);
  }
  float cw = -splm * INV_SQRT_D;
  float2 o; o.x = cw * accx; o.y = cw * accy;
  *(float2*)(dQm + row * DD + 2 * l) = o;
}

// ---------------- LN backward + grad clip + update + state clip ----------------
__global__ __launch_bounds__(256) void ln_bwd(const float* __restrict__ X,
                                              const float* __restrict__ dG,
                                              const float* __restrict__ gamma,
                                              const float* __restrict__ meanv,
                                              const float* __restrict__ rstdv,
                                              float* __restrict__ out) {
  int row = blockIdx.x * 4 + (threadIdx.x >> 6);
  if (row >= NN) return;
  int l = threadIdx.x & 63;
  float mu = meanv[row], rstd = rstdv[row];
  float2 x2 = *(const float2*)(X + row * DD + 2 * l);
  float2 g2 = *(const float2*)(dG + row * DD + 2 * l);
  float2 ga = *(const float2*)(gamma + 2 * l);
  float xh0 = (x2.x - mu) * rstd, xh1 = (x2.y - mu) * rstd;
  float dh0 = g2.x * ga.x, dh1 = g2.y * ga.y;
  float sa = wredsum(dh0 + dh1) * (1.f / DD);
  float sb = wredsum(dh0 * xh0 + dh1 * xh1) * (1.f / DD);
  float dx0 = rstd * (dh0 - sa - xh0 * sb);
  float dx1 = rstd * (dh1 - sa - xh1 * sb);
  float gn = fmaxf(sqrtf(wredsum(dx0 * dx0 + dx1 * dx1)), 1e-6f);
  float sc = fminf(1.f / gn, 1.f);
  dx0 *= sc; dx1 *= sc;
  float xn0 = x2.x - 0.1f * 0.9999f * dx0;
  float xn1 = x2.y - 0.1f * 0.9999f * dx1;
  float sn = fmaxf(sqrtf(wredsum(xn0 * xn0 + xn1 * xn1)), 1e-6f);
  float sc2 = fminf(10.f / sn, 1.f);
  float2 o; o.x = xn0 * sc2; o.y = xn1 * sc2;
  *(float2*)(out + row * DD + 2 * l) = o;
}

// ---------------- final energy scalar ----------------
__global__ __launch_bounds__(256) void eval_write(const float* __restrict__ L2,
                                                  const float* __restrict__ L3,
                                                  const float* __restrict__ Lm,
                                                  const float* __restrict__ pl2,
                                                  const float* __restrict__ pl3,
                                                  const float* __restrict__ plm,
                                                  const float* __restrict__ pb2,
                                                  const float* __restrict__ pb3,
                                                  const float* __restrict__ pbm,
                                                  float* __restrict__ out) {
  int tid = threadIdx.x;
  float a2 = 0.f, a3 = 0.f, am = 0.f;
  for (int i = tid; i < NN; i += 256) { a2 += L2[i]; a3 += L3[i]; am += Lm[i]; }
  a2 = wredsum(a2); a3 = wredsum(a3); am = wredsum(am);
  __shared__ float r2[4], r3[4], rm[4];
  int wv = tid >> 6, l = tid & 63;
  if (l == 0) { r2[wv] = a2; r3[wv] = a3; rm[wv] = am; }
  __syncthreads();
  if (tid == 0) {
    float S2 = r2[0] + r2[1] + r2[2] + r2[3];
    float S3 = r3[0] + r3[1] + r3[2] + r3[3];
    float Sm = rm[0] + rm[1] + rm[2] + rm[3];
    float b2 = fminf(softplus_f(pb2[0]), 5.f);
    float b3 = fminf(softplus_f(pb3[0]), 5.f);
    float bm = fminf(softplus_f(pbm[0]), 5.f);
    out[0] = -(softplus_f(pl2[0]) / b2) * S2
             - (softplus_f(pl3[0]) / b3) * S3
             - (softplus_f(plm[0]) / bm) * Sm;
  }
}

extern "C" void kernel_launch(void* const* d_in, const int* in_sizes, int n_in,
                              void* d_out, int out_size, void* d_ws, size_t ws_size,
                              hipStream_t stream) {
  (void)in_sizes; (void)n_in; (void)out_size;
  const float* X = (const float*)d_in[0];
  const float* EA = (const float*)d_in[1];
  const float* ln_g = (const float*)d_in[2];
  const float* ln_b = (const float*)d_in[3];
  const float* W_Q2 = (const float*)d_in[4];
  const float* W_K2 = (const float*)d_in[5];
  const float* W_Q3 = (const float*)d_in[6];
  const float* W_K3 = (const float*)d_in[7];
  const float* T_tau = (const float*)d_in[8];
  const float* W_Qm = (const float*)d_in[9];
  const float* W_Km = (const float*)d_in[10];
  const float* B_mem = (const float*)d_in[11];
  const float* We1 = (const float*)d_in[12];
  const float* be1 = (const float*)d_in[13];
  const float* We2 = (const float*)d_in[14];
  const float* be2 = (const float*)d_in[15];
  const float* l2s = (const float*)d_in[16];
  const float* l3s = (const float*)d_in[17];
  const float* lms = (const float*)d_in[18];
  const float* b2s = (const float*)d_in[19];
  const float* b3s = (const float*)d_in[20];
  const float* bms = (const float*)d_in[21];
  const int* c2 = (const int*)d_in[22];
  const int* u2 = (const int*)d_in[23];
  const int* c3 = (const int*)d_in[24];
  const int* u3 = (const int*)d_in[25];
  const int* v3 = (const int*)d_in[26];
  const int* ttau = (const int*)d_in[27];
  float* out = (float*)d_out;

  float* ws = (float*)d_ws;
  size_t off = 0;
  auto alloc = [&](size_t n) { float* p = ws + off; off += n; return p; };
  const size_t ND = (size_t)NN * DD;
  // buf0: G -> dA(dQ2) -> dA(dQ3) -> dQm ; buf1: Q2 -> dG
  float* buf0 = alloc(ND);
  float* buf1 = alloc(ND);
  float* K2 = alloc(ND);
  float* Q3 = alloc(ND);
  float* K3 = alloc(ND);
  float* Qm = alloc(ND);
  float* dB = alloc(ND);
  float* Km = alloc((size_t)KM * DD);
  float* a2 = alloc(EE);
  float* s2 = alloc(EE);
  float* s3 = alloc(TT);
  float* meanv = alloc(NN);
  float* rstdv = alloc(NN);
  float* L2 = alloc(NN);
  float* L3 = alloc(NN);
  float* Lm = alloc(NN);
  unsigned* m2u = (unsigned*)alloc(NN);
  float* z2 = alloc(NN);
  unsigned* m3u = (unsigned*)alloc(NN);
  float* z3 = alloc(NN);
  if (off * sizeof(float) > ws_size) return; // workspace too small — fail loudly via wrong output

  float* G = buf0;
  float* Q2 = buf1;
  float* dA = buf0;
  float* dG = buf1;

  // zero segment-softmax accumulators (m2u,z2,m3u,z3 contiguous)
  hipMemsetAsync(m2u, 0, 4ull * NN * sizeof(float), stream);

  int gemmB = (NN + 63) / 64;

  ln_fwd<<<(NN + 3) / 4, 256, 0, stream>>>(X, ln_g, ln_b, G, meanv, rstdv);

  gemm128<<<gemmB, 256, 0, stream>>>(G, W_Q2, Q2, NN, 0, 0);
  gemm128<<<gemmB, 256, 0, stream>>>(G, W_K2, K2, NN, 0, 0);
  gemm128<<<gemmB, 256, 0, stream>>>(G, W_Q3, Q3, NN, 0, 0);
  gemm128<<<gemmB, 256, 0, stream>>>(G, W_K3, K3, NN, 0, 0);
  gemm128<<<gemmB, 256, 0, stream>>>(G, W_Qm, Qm, NN, 0, 0);
  gemm128<<<1, 256, 0, stream>>>(B_mem, W_Km, Km, KM, 0, 0);

  edge_mlp<<<(EE + 255) / 256, 256, 0, stream>>>(EA, We1, be1, We2, be2, a2);

  e2_pass1<<<(EE + 3) / 4, 256, 0, stream>>>(Q2, K2, a2, c2, u2, b2s, s2, m2u);
  t3_pass1<<<(TT + 3) / 4, 256, 0, stream>>>(Q3, K3, T_tau, c3, u3, v3, ttau, b3s, s3, m3u);
  e2_pass2<<<(EE + 255) / 256, 256, 0, stream>>>(s2, c2, m2u, z2);
  t3_pass2<<<(TT + 255) / 256, 256, 0, stream>>>(s3, c3, m3u, z3);
  seg_fin<<<(NN + 255) / 256, 256, 0, stream>>>(m2u, z2, m3u, z3, L2, L3);

  // order-2 backward (G dead now; buf0 = dQ2, dB = dK2)
  hipMemsetAsync(dA, 0, ND * sizeof(float), stream);
  hipMemsetAsync(dB, 0, ND * sizeof(float), stream);
  e2_bwd<<<(EE + 3) / 4, 256, 0, stream>>>(Q2, K2, s2, L2, c2, u2, l2s, dA, dB);
  gemm128<<<gemmB, 256, 0, stream>>>(dA, W_Q2, dG, NN, 1, 0); // dG := dQ2 @ W_Q2^T (Q2 dead)
  gemm128<<<gemmB, 256, 0, stream>>>(dB, W_K2, dG, NN, 1, 1);

  // order-3 backward
  hipMemsetAsync(dA, 0, ND * sizeof(float), stream);
  hipMemsetAsync(dB, 0, ND * sizeof(float), stream);
  t3_bwd<<<(TT + 3) / 4, 256, 0, stream>>>(Q3, K3, T_tau, s3, L3, c3, u3, v3, ttau, l3s, dA, dB);
  gemm128<<<gemmB, 256, 0, stream>>>(dA, W_Q3, dG, NN, 1, 1);
  gemm128<<<gemmB, 256, 0, stream>>>(dB, W_K3, dG, NN, 1, 1);

  // memory-bank energy + dQm (full overwrite of dA)
  em_row<<<(NN + 3) / 4, 256, 0, stream>>>(Qm, Km, bms, lms, dA, Lm);
  gemm128<<<gemmB, 256, 0, stream>>>(dA, W_Qm, dG, NN, 1, 1);

  // LN backward + clip + update + clip -> X_next
  ln_bwd<<<(NN + 3) / 4, 256, 0, stream>>>(X, dG, ln_g, meanv, rstdv, out);

  eval_write<<<1, 256, 0, stream>>>(L2, L3, Lm, l2s, l3s, lms, b2s, b3s, bms, out + ND);
}

// Round 2
// 2722.736 us; speedup vs baseline: 1.4975x; 1.4975x over previous
//
#include <hip/hip_runtime.h>

#define NN 50000
#define DD 128
#define EE 800000
#define TT 400000
#define KM 32

static constexpr float INV_SQRT_D = 0.08838834764831845f; // 1/sqrt(128)
static constexpr float INV_D = 1.f / 128.f;

__device__ __forceinline__ float softplus_f(float x) {
  return (x > 20.f) ? x : log1pf(__expf(x));
}

__device__ __forceinline__ float gelu_tanh(float x) {
  float x3 = x * x * x;
  float u = 0.7978845608028654f * (x + 0.044715f * x3);
  u = fminf(fmaxf(u, -15.f), 15.f);
  float e = __expf(2.f * u);
  float t = (e - 1.f) / (e + 1.f);
  return 0.5f * x * (1.f + t);
}

// order-preserving float<->uint for atomicMax on floats
__device__ __forceinline__ unsigned ford(float f) {
  unsigned u = __float_as_uint(f);
  return (u & 0x80000000u) ? ~u : (u | 0x80000000u);
}
__device__ __forceinline__ float forddec(unsigned u) {
  return __uint_as_float((u & 0x80000000u) ? (u & 0x7fffffffu) : ~u);
}

__device__ __forceinline__ float wredsum(float v) {
#pragma unroll
  for (int m = 32; m; m >>= 1) v += __shfl_xor(v, m, 64);
  return v;
}

// ---------------- LayerNorm forward ----------------
__global__ __launch_bounds__(256) void ln_fwd(const float* __restrict__ X,
                                              const float* __restrict__ gamma,
                                              const float* __restrict__ beta,
                                              float* __restrict__ G,
                                              float* __restrict__ meanv,
                                              float* __restrict__ rstdv) {
  int row = blockIdx.x * 4 + (threadIdx.x >> 6);
  if (row >= NN) return;
  int l = threadIdx.x & 63;
  float2 x2 = *(const float2*)(X + row * DD + 2 * l);
  float mu = wredsum(x2.x + x2.y) * (1.f / DD);
  float d0 = x2.x - mu, d1 = x2.y - mu;
  float var = wredsum(d0 * d0 + d1 * d1) * (1.f / DD);
  float rstd = rsqrtf(var + 1e-5f);
  float2 g2 = *(const float2*)(gamma + 2 * l);
  float2 b2 = *(const float2*)(beta + 2 * l);
  float2 o;
  o.x = d0 * rstd * g2.x + b2.x;
  o.y = d1 * rstd * g2.y + b2.y;
  *(float2*)(G + row * DD + 2 * l) = o;
  if (l == 0) { meanv[row] = mu; rstdv[row] = rstd; }
}

// ---------------- generic 128-wide GEMM: C[M,128] = A[M,128] @ (W or W^T) ----------------
__global__ __launch_bounds__(256, 1) void gemm128(const float* __restrict__ A,
                                                  const float* __restrict__ W,
                                                  float* __restrict__ C, int M,
                                                  int transW, int accum) {
  __shared__ float As[64][132];
  __shared__ float Wst[128][136];
  const int tid = threadIdx.x;
  const int r0 = blockIdx.x * 64;
  for (int idx = tid; idx < 128 * 128; idx += 256) {
    int k = idx >> 7, j = idx & 127;
    Wst[k][j] = transW ? W[j * 128 + k] : W[k * 128 + j];
  }
  for (int idx = tid; idx < 64 * 128; idx += 256) {
    int r = idx >> 7, d = idx & 127;
    int gr = r0 + r;
    As[r][d] = (gr < M) ? A[gr * 128 + d] : 0.f;
  }
  __syncthreads();
  const int tx = tid & 15, ty = tid >> 4;
  float acc[4][8];
#pragma unroll
  for (int i = 0; i < 4; i++)
#pragma unroll
    for (int j = 0; j < 8; j++) acc[i][j] = 0.f;
  for (int k = 0; k < 128; k += 4) {
    float a[4][4];
#pragma unroll
    for (int i = 0; i < 4; i++) {
      float4 v = *(const float4*)&As[ty * 4 + i][k];
      a[i][0] = v.x; a[i][1] = v.y; a[i][2] = v.z; a[i][3] = v.w;
    }
    float w[4][8];
#pragma unroll
    for (int dk = 0; dk < 4; dk++) {
      float4 v0 = *(const float4*)&Wst[k + dk][tx * 8];
      float4 v1 = *(const float4*)&Wst[k + dk][tx * 8 + 4];
      w[dk][0] = v0.x; w[dk][1] = v0.y; w[dk][2] = v0.z; w[dk][3] = v0.w;
      w[dk][4] = v1.x; w[dk][5] = v1.y; w[dk][6] = v1.z; w[dk][7] = v1.w;
    }
#pragma unroll
    for (int dk = 0; dk < 4; dk++)
#pragma unroll
      for (int i = 0; i < 4; i++)
#pragma unroll
        for (int j = 0; j < 8; j++)
          acc[i][j] = fmaf(a[i][dk], w[dk][j], acc[i][j]);
  }
#pragma unroll
  for (int i = 0; i < 4; i++) {
    int gr = r0 + ty * 4 + i;
    if (gr < M) {
      float* cp = C + gr * 128 + tx * 8;
      if (accum) {
#pragma unroll
        for (int j = 0; j < 8; j++) cp[j] += acc[i][j];
      } else {
#pragma unroll
        for (int j = 0; j < 8; j++) cp[j] = acc[i][j];
      }
    }
  }
}

// ---------------- edge MLP ----------------
__global__ __launch_bounds__(256) void edge_mlp(const float* __restrict__ EA,
                                                const float* __restrict__ We1,
                                                const float* __restrict__ be1,
                                                const float* __restrict__ We2,
                                                const float* __restrict__ be2,
                                                float* __restrict__ a2) {
  __shared__ float sW1[16 * 128];
  __shared__ float sb1[128];
  __shared__ float sW2[128];
  int tid = threadIdx.x;
  for (int i = tid; i < 2048; i += 256) sW1[i] = We1[i];
  if (tid < 128) { sb1[tid] = be1[tid]; sW2[tid] = We2[tid]; }
  __syncthreads();
  int e = blockIdx.x * 256 + tid;
  if (e >= EE) return;
  float ea[16];
#pragma unroll
  for (int q = 0; q < 4; q++) {
    float4 v = *(const float4*)(EA + (size_t)e * 16 + q * 4);
    ea[q * 4 + 0] = v.x; ea[q * 4 + 1] = v.y; ea[q * 4 + 2] = v.z; ea[q * 4 + 3] = v.w;
  }
  float acc = 0.f;
  for (int j = 0; j < 128; j += 4) {
    float4 h = *(const float4*)&sb1[j];
#pragma unroll
    for (int k = 0; k < 16; k++) {
      float4 wv = *(const float4*)&sW1[k * 128 + j];
      h.x = fmaf(ea[k], wv.x, h.x);
      h.y = fmaf(ea[k], wv.y, h.y);
      h.z = fmaf(ea[k], wv.z, h.z);
      h.w = fmaf(ea[k], wv.w, h.w);
    }
    float4 w2 = *(const float4*)&sW2[j];
    acc = fmaf(gelu_tanh(h.x), w2.x, acc);
    acc = fmaf(gelu_tanh(h.y), w2.y, acc);
    acc = fmaf(gelu_tanh(h.z), w2.z, acc);
    acc = fmaf(gelu_tanh(h.w), w2.w, acc);
  }
  a2[e] = acc + be2[0];
}

// ---------------- CSR build: histogram / scan / scatter ----------------
__global__ __launch_bounds__(256) void hist2(const int* __restrict__ a,
                                             const int* __restrict__ b,
                                             int* __restrict__ ca,
                                             int* __restrict__ cb, int n) {
  int e = blockIdx.x * 256 + threadIdx.x;
  if (e >= n) return;
  atomicAdd(&ca[a[e]], 1);
  atomicAdd(&cb[b[e]], 1);
}

__global__ __launch_bounds__(256) void hist_t3(const int* __restrict__ c,
                                               const int* __restrict__ u,
                                               const int* __restrict__ v,
                                               int* __restrict__ cc,
                                               int* __restrict__ cuv, int n) {
  int t = blockIdx.x * 256 + threadIdx.x;
  if (t >= n) return;
  atomicAdd(&cc[c[t]], 1);
  atomicAdd(&cuv[u[t]], 1);
  atomicAdd(&cuv[v[t]], 1);
}

// one block per count-array; exclusive scan of NN bins -> rowptr (NN+1) and cursor copy
__global__ __launch_bounds__(256) void scan4(const int* __restrict__ cnt,
                                             int* __restrict__ rowptr,
                                             int* __restrict__ cursor) {
  const int* c = cnt + (size_t)blockIdx.x * NN;
  int* rp = rowptr + (size_t)blockIdx.x * (NN + 1);
  int* cur = cursor + (size_t)blockIdx.x * NN;
  __shared__ int wt[4];
  int tid = threadIdx.x, lane = tid & 63, wid = tid >> 6;
  int base = 0;
  for (int i0 = 0; i0 < NN; i0 += 256) {
    int i = i0 + tid;
    int v = (i < NN) ? c[i] : 0;
    int x = v;
#pragma unroll
    for (int d = 1; d < 64; d <<= 1) {
      int y = __shfl_up(x, d, 64);
      if (lane >= d) x += y;
    }
    __syncthreads();
    if (lane == 63) wt[wid] = x;
    __syncthreads();
    int add = 0;
    for (int w = 0; w < wid; w++) add += wt[w];
    int excl = base + add + x - v;
    if (i < NN) { rp[i] = excl; cur[i] = excl; }
    base += wt[0] + wt[1] + wt[2] + wt[3];
  }
  if (tid == 0) rp[NN] = base;
}

__global__ __launch_bounds__(256) void scat2(const int* __restrict__ a,
                                             const int* __restrict__ b,
                                             int* __restrict__ ca,
                                             int* __restrict__ cb,
                                             int* __restrict__ ea,
                                             int* __restrict__ eb, int n) {
  int e = blockIdx.x * 256 + threadIdx.x;
  if (e >= n) return;
  int p = atomicAdd(&ca[a[e]], 1);
  ea[p] = e;
  p = atomicAdd(&cb[b[e]], 1);
  eb[p] = e;
}

__global__ __launch_bounds__(256) void scat_t3(const int* __restrict__ c,
                                               const int* __restrict__ u,
                                               const int* __restrict__ v,
                                               int* __restrict__ cc,
                                               int* __restrict__ cuv,
                                               int* __restrict__ ec,
                                               int* __restrict__ euv, int n) {
  int t = blockIdx.x * 256 + threadIdx.x;
  if (t >= n) return;
  int p = atomicAdd(&cc[c[t]], 1);
  ec[p] = t;
  p = atomicAdd(&cuv[u[t]], 1);
  euv[p] = 2 * t;
  p = atomicAdd(&cuv[v[t]], 1);
  euv[p] = 2 * t + 1;
}

// ---------------- order-2 forward passes ----------------
__global__ __launch_bounds__(256) void e2_pass1(const float* __restrict__ Q2,
                                                const float* __restrict__ K2,
                                                const float* __restrict__ a2,
                                                const int* __restrict__ c2,
                                                const int* __restrict__ u2,
                                                const float* __restrict__ pbeta2,
                                                float* __restrict__ s2,
                                                unsigned* __restrict__ m2u) {
  int e = blockIdx.x * 4 + (int)(threadIdx.x >> 6);
  if (e >= EE) return;
  int l = threadIdx.x & 63;
  float b2 = fminf(softplus_f(pbeta2[0]), 5.f);
  int c = c2[e], u = u2[e];
  float2 q = *(const float2*)(Q2 + c * DD + 2 * l);
  float2 k = *(const float2*)(K2 + u * DD + 2 * l);
  float dot = wredsum(q.x * k.x + q.y * k.y);
  if (l == 0) {
    float s = b2 * dot * INV_SQRT_D + a2[e];
    s2[e] = s;
    atomicMax(&m2u[c], ford(s));
  }
}

__global__ __launch_bounds__(256) void e2_pass2(const float* __restrict__ s2,
                                                const int* __restrict__ c2,
                                                const unsigned* __restrict__ m2u,
                                                float* __restrict__ z2) {
  int e = blockIdx.x * 256 + threadIdx.x;
  if (e >= EE) return;
  int c = c2[e];
  atomicAdd(&z2[c], __expf(s2[e] - forddec(m2u[c])));
}

// ---------------- order-3 forward passes ----------------
__global__ __launch_bounds__(256) void t3_pass1(const float* __restrict__ Q3,
                                                const float* __restrict__ K3,
                                                const float* __restrict__ Tt,
                                                const int* __restrict__ c3,
                                                const int* __restrict__ u3,
                                                const int* __restrict__ v3,
                                                const int* __restrict__ ttau,
                                                const float* __restrict__ pbeta3,
                                                float* __restrict__ s3,
                                                unsigned* __restrict__ m3u) {
  int e = blockIdx.x * 4 + (int)(threadIdx.x >> 6);
  if (e >= TT) return;
  int l = threadIdx.x & 63;
  float b3 = fminf(softplus_f(pbeta3[0]), 5.f);
  int c = c3[e], u = u3[e], v = v3[e], t = ttau[e];
  float2 q = *(const float2*)(Q3 + c * DD + 2 * l);
  float2 ku = *(const float2*)(K3 + u * DD + 2 * l);
  float2 kv = *(const float2*)(K3 + v * DD + 2 * l);
  float2 tv = *(const float2*)(Tt + t * DD + 2 * l);
  float dot = wredsum(q.x * ku.x * kv.x * tv.x + q.y * ku.y * kv.y * tv.y);
  if (l == 0) {
    float s = b3 * dot * INV_D;
    s3[e] = s;
    atomicMax(&m3u[c], ford(s));
  }
}

__global__ __launch_bounds__(256) void t3_pass2(const float* __restrict__ s3,
                                                const int* __restrict__ c3,
                                                const unsigned* __restrict__ m3u,
                                                float* __restrict__ z3) {
  int e = blockIdx.x * 256 + threadIdx.x;
  if (e >= TT) return;
  int c = c3[e];
  atomicAdd(&z3[c], __expf(s3[e] - forddec(m3u[c])));
}

// ---------------- segment finalize: L = log z + m ----------------
__global__ __launch_bounds__(256) void seg_fin(const unsigned* __restrict__ m2u,
                                               const float* __restrict__ z2,
                                               const unsigned* __restrict__ m3u,
                                               const float* __restrict__ z3,
                                               float* __restrict__ L2,
                                               float* __restrict__ L3) {
  int i = blockIdx.x * 256 + threadIdx.x;
  if (i >= NN) return;
  float z = z2[i];
  L2[i] = (z > 0.f) ? (__logf(z) + forddec(m2u[i])) : 0.f;
  z = z3[i];
  L3[i] = (z > 0.f) ? (__logf(z) + forddec(m3u[i])) : 0.f;
}

// ---------------- per-edge backward weights (in-place over s) ----------------
__global__ __launch_bounds__(256) void e2_w(float* __restrict__ s2,
                                            const float* __restrict__ L2,
                                            const int* __restrict__ c2,
                                            const float* __restrict__ plam) {
  int e = blockIdx.x * 256 + threadIdx.x;
  if (e >= EE) return;
  float sp = softplus_f(plam[0]);
  s2[e] = -sp * INV_SQRT_D * __expf(s2[e] - L2[c2[e]]);
}

__global__ __launch_bounds__(256) void t3_w(float* __restrict__ s3,
                                            const float* __restrict__ L3,
                                            const int* __restrict__ c3,
                                            const float* __restrict__ plam) {
  int t = blockIdx.x * 256 + threadIdx.x;
  if (t >= TT) return;
  float sp = softplus_f(plam[0]);
  s3[t] = -sp * INV_D * __expf(s3[t] - L3[c3[t]]);
}

// ---------------- gather backward: order-2 (one wave per dest node) ----------------
__global__ __launch_bounds__(256) void gather_e2(const float* __restrict__ P,
                                                 const int* __restrict__ oth,
                                                 const float* __restrict__ w,
                                                 const int* __restrict__ eidx,
                                                 const int* __restrict__ rp,
                                                 float* __restrict__ dst) {
  int row = blockIdx.x * 4 + (int)(threadIdx.x >> 6);
  if (row >= NN) return;
  int l = threadIdx.x & 63;
  int s = rp[row], e = rp[row + 1];
  float ax = 0.f, ay = 0.f;
  for (int i = s; i < e; i++) {
    int ed = eidx[i];
    float ww = w[ed];
    int o = oth[ed];
    float2 k = *(const float2*)(P + (size_t)o * DD + 2 * l);
    ax = fmaf(ww, k.x, ax);
    ay = fmaf(ww, k.y, ay);
  }
  float2 o2; o2.x = ax; o2.y = ay;
  *(float2*)(dst + (size_t)row * DD + 2 * l) = o2;
}

// ---------------- gather backward: order-3 dQ3 (c3-CSR) ----------------
__global__ __launch_bounds__(256) void gather_q3(const float* __restrict__ K3,
                                                 const float* __restrict__ Tt,
                                                 const int* __restrict__ u3,
                                                 const int* __restrict__ v3,
                                                 const int* __restrict__ ttau,
                                                 const float* __restrict__ w,
                                                 const int* __restrict__ eidx,
                                                 const int* __restrict__ rp,
                                                 float* __restrict__ dst) {
  __shared__ float sT[2 * DD];
  int tid = threadIdx.x;
  sT[tid] = Tt[tid]; // 2*128 == 256
  __syncthreads();
  int row = blockIdx.x * 4 + (tid >> 6);
  if (row >= NN) return;
  int l = tid & 63;
  int s = rp[row], e = rp[row + 1];
  float ax = 0.f, ay = 0.f;
  float2* sT2 = (float2*)sT;
  for (int i = s; i < e; i++) {
    int t = eidx[i];
    float ww = w[t];
    int uu = u3[t], vv = v3[t], ta = ttau[t];
    float2 ku = *(const float2*)(K3 + (size_t)uu * DD + 2 * l);
    float2 kv = *(const float2*)(K3 + (size_t)vv * DD + 2 * l);
    float2 tv = sT2[ta * 64 + l];
    ax = fmaf(ww * tv.x, ku.x * kv.x, ax);
    ay = fmaf(ww * tv.y, ku.y * kv.y, ay);
  }
  float2 o2; o2.x = ax; o2.y = ay;
  *(float2*)(dst + (size_t)row * DD + 2 * l) = o2;
}

// ---------------- gather backward: order-3 dK3 (merged u/v CSR) ----------------
__global__ __launch_bounds__(256) void gather_k3(const float* __restrict__ Q3,
                                                 const float* __restrict__ K3,
                                                 const float* __restrict__ Tt,
                                                 const int* __restrict__ c3,
                                                 const int* __restrict__ u3,
                                                 const int* __restrict__ v3,
                                                 const int* __restrict__ ttau,
                                                 const float* __restrict__ w,
                                                 const int* __restrict__ eidx,
                                                 const int* __restrict__ rp,
                                                 float* __restrict__ dst) {
  __shared__ float sT[2 * DD];
  int tid = threadIdx.x;
  sT[tid] = Tt[tid];
  __syncthreads();
  int row = blockIdx.x * 4 + (tid >> 6);
  if (row >= NN) return;
  int l = tid & 63;
  int s = rp[row], e = rp[row + 1];
  float ax = 0.f, ay = 0.f;
  float2* sT2 = (float2*)sT;
  for (int i = s; i < e; i++) {
    int ent = eidx[i];
    int t = ent >> 1, slot = ent & 1;
    float ww = w[t];
    int cc = c3[t], ta = ttau[t];
    int o = slot ? u3[t] : v3[t]; // if I'm u (slot0), partner is v; if I'm v, partner is u
    float2 q = *(const float2*)(Q3 + (size_t)cc * DD + 2 * l);
    float2 ko = *(const float2*)(K3 + (size_t)o * DD + 2 * l);
    float2 tv = sT2[ta * 64 + l];
    ax = fmaf(ww * tv.x, q.x * ko.x, ax);
    ay = fmaf(ww * tv.y, q.y * ko.y, ay);
  }
  float2 o2; o2.x = ax; o2.y = ay;
  *(float2*)(dst + (size_t)row * DD + 2 * l) = o2;
}

// ---------------- memory-bank energy row kernel ----------------
__global__ __launch_bounds__(256) void em_row(const float* __restrict__ Qm,
                                              const float* __restrict__ Km,
                                              const float* __restrict__ pbetam,
                                              const float* __restrict__ plamm,
                                              float* __restrict__ dQm,
                                              float* __restrict__ Lm) {
  __shared__ float sKm[KM * DD];
  int tid = threadIdx.x;
  for (int i = tid; i < KM * DD; i += 256) sKm[i] = Km[i];
  __syncthreads();
  int row = blockIdx.x * 4 + (tid >> 6);
  if (row >= NN) return;
  int l = tid & 63;
  float bm = fminf(softplus_f(pbetam[0]), 5.f);
  float splm = softplus_f(plamm[0]);
  int k = l & 31, h = l >> 5;
  const float* qrow = Qm + row * DD;
  float part = 0.f;
  for (int d0 = 0; d0 < 64; d0++) {
    int d = h * 64 + d0;
    part = fmaf(qrow[d], sKm[k * DD + d], part);
  }
  part += __shfl_xor(part, 32, 64);
  float sk = bm * part * INV_SQRT_D;
  float mx = sk;
#pragma unroll
  for (int m = 16; m; m >>= 1) mx = fmaxf(mx, __shfl_xor(mx, m, 64));
  float ex = __expf(sk - mx);
  float zz = ex;
#pragma unroll
  for (int m = 16; m; m >>= 1) zz += __shfl_xor(zz, m, 64);
  float lse = mx + __logf(zz);
  if (l == 0) Lm[row] = lse;
  float pk = ex / zz;
  float accx = 0.f, accy = 0.f;
#pragma unroll
  for (int kk = 0; kk < 32; kk++) {
    float pkk = __shfl(pk, kk, 64);
    accx = fmaf(pkk, sKm[kk * DD + 2 * l], accx);
    accy = fmaf(pkk, sKm[kk * DD + 2 * l + 1], accy);
  }
  float cw = -splm * INV_SQRT_D;
  float2 o; o.x = cw * accx; o.y = cw * accy;
  *(float2*)(dQm + row * DD + 2 * l) = o;
}

// ---------------- LN backward + grad clip + update + state clip ----------------
__global__ __launch_bounds__(256) void ln_bwd(const float* __restrict__ X,
                                              const float* __restrict__ dG,
                                              const float* __restrict__ gamma,
                                              const float* __restrict__ meanv,
                                              const float* __restrict__ rstdv,
                                              float* __restrict__ out) {
  int row = blockIdx.x * 4 + (threadIdx.x >> 6);
  if (row >= NN) return;
  int l = threadIdx.x & 63;
  float mu = meanv[row], rstd = rstdv[row];
  float2 x2 = *(const float2*)(X + row * DD + 2 * l);
  float2 g2 = *(const float2*)(dG + row * DD + 2 * l);
  float2 ga = *(const float2*)(gamma + 2 * l);
  float xh0 = (x2.x - mu) * rstd, xh1 = (x2.y - mu) * rstd;
  float dh0 = g2.x * ga.x, dh1 = g2.y * ga.y;
  float sa = wredsum(dh0 + dh1) * (1.f / DD);
  float sb = wredsum(dh0 * xh0 + dh1 * xh1) * (1.f / DD);
  float dx0 = rstd * (dh0 - sa - xh0 * sb);
  float dx1 = rstd * (dh1 - sa - xh1 * sb);
  float gn = fmaxf(sqrtf(wredsum(dx0 * dx0 + dx1 * dx1)), 1e-6f);
  float sc = fminf(1.f / gn, 1.f);
  dx0 *= sc; dx1 *= sc;
  float xn0 = x2.x - 0.1f * 0.9999f * dx0;
  float xn1 = x2.y - 0.1f * 0.9999f * dx1;
  float sn = fmaxf(sqrtf(wredsum(xn0 * xn0 + xn1 * xn1)), 1e-6f);
  float sc2 = fminf(10.f / sn, 1.f);
  float2 o; o.x = xn0 * sc2; o.y = xn1 * sc2;
  *(float2*)(out + row * DD + 2 * l) = o;
}

// ---------------- final energy scalar ----------------
__global__ __launch_bounds__(256) void eval_write(const float* __restrict__ L2,
                                                  const float* __restrict__ L3,
                                                  const float* __restrict__ Lm,
                                                  const float* __restrict__ pl2,
                                                  const float* __restrict__ pl3,
                                                  const float* __restrict__ plm,
                                                  const float* __restrict__ pb2,
                                                  const float* __restrict__ pb3,
                                                  const float* __restrict__ pbm,
                                                  float* __restrict__ out) {
  int tid = threadIdx.x;
  float a2 = 0.f, a3 = 0.f, am = 0.f;
  for (int i = tid; i < NN; i += 256) { a2 += L2[i]; a3 += L3[i]; am += Lm[i]; }
  a2 = wredsum(a2); a3 = wredsum(a3); am = wredsum(am);
  __shared__ float r2[4], r3[4], rm[4];
  int wv = tid >> 6, l = tid & 63;
  if (l == 0) { r2[wv] = a2; r3[wv] = a3; rm[wv] = am; }
  __syncthreads();
  if (tid == 0) {
    float S2 = r2[0] + r2[1] + r2[2] + r2[3];
    float S3 = r3[0] + r3[1] + r3[2] + r3[3];
    float Sm = rm[0] + rm[1] + rm[2] + rm[3];
    float b2 = fminf(softplus_f(pb2[0]), 5.f);
    float b3 = fminf(softplus_f(pb3[0]), 5.f);
    float bm = fminf(softplus_f(pbm[0]), 5.f);
    out[0] = -(softplus_f(pl2[0]) / b2) * S2
             - (softplus_f(pl3[0]) / b3) * S3
             - (softplus_f(plm[0]) / bm) * Sm;
  }
}

extern "C" void kernel_launch(void* const* d_in, const int* in_sizes, int n_in,
                              void* d_out, int out_size, void* d_ws, size_t ws_size,
                              hipStream_t stream) {
  (void)in_sizes; (void)n_in; (void)out_size;
  const float* X = (const float*)d_in[0];
  const float* EA = (const float*)d_in[1];
  const float* ln_g = (const float*)d_in[2];
  const float* ln_b = (const float*)d_in[3];
  const float* W_Q2 = (const float*)d_in[4];
  const float* W_K2 = (const float*)d_in[5];
  const float* W_Q3 = (const float*)d_in[6];
  const float* W_K3 = (const float*)d_in[7];
  const float* T_tau = (const float*)d_in[8];
  const float* W_Qm = (const float*)d_in[9];
  const float* W_Km = (const float*)d_in[10];
  const float* B_mem = (const float*)d_in[11];
  const float* We1 = (const float*)d_in[12];
  const float* be1 = (const float*)d_in[13];
  const float* We2 = (const float*)d_in[14];
  const float* be2 = (const float*)d_in[15];
  const float* l2s = (const float*)d_in[16];
  const float* l3s = (const float*)d_in[17];
  const float* lms = (const float*)d_in[18];
  const float* b2s = (const float*)d_in[19];
  const float* b3s = (const float*)d_in[20];
  const float* bms = (const float*)d_in[21];
  const int* c2 = (const int*)d_in[22];
  const int* u2 = (const int*)d_in[23];
  const int* c3 = (const int*)d_in[24];
  const int* u3 = (const int*)d_in[25];
  const int* v3 = (const int*)d_in[26];
  const int* ttau = (const int*)d_in[27];
  float* out = (float*)d_out;

  float* ws = (float*)d_ws;
  size_t off = 0;
  auto alloc = [&](size_t n) { float* p = ws + off; off += n; return p; };
  const size_t ND = (size_t)NN * DD;
  // buf0: G -> dA(dQ2/dQ3/dQm) ; buf1: Q2 -> dG ; K2 buffer doubles as dB after K2 dead
  float* buf0 = alloc(ND);
  float* buf1 = alloc(ND);
  float* K2b = alloc(ND);
  float* Q3 = alloc(ND);
  float* K3 = alloc(ND);
  float* Qm = alloc(ND);
  float* Km = alloc((size_t)KM * DD);
  float* a2 = alloc(EE);
  float* s2 = alloc(EE);
  float* s3 = alloc(TT);
  float* meanv = alloc(NN);
  float* rstdv = alloc(NN);
  float* L2 = alloc(NN);
  float* L3 = alloc(NN);
  float* Lm = alloc(NN);
  unsigned* m2u = (unsigned*)alloc(NN);
  float* z2 = alloc(NN);
  unsigned* m3u = (unsigned*)alloc(NN);
  float* z3 = alloc(NN);
  // CSR arrays: counts (4*NN contiguous for one memset), rowptr (4*(NN+1)), cursors (4*NN)
  int* cnt = (int*)alloc(4 * (size_t)NN);
  int* rowptr = (int*)alloc(4 * (size_t)(NN + 1));
  int* cursor = (int*)alloc(4 * (size_t)NN);
  int* eidx_c2 = (int*)alloc(EE);
  int* eidx_u2 = (int*)alloc(EE);
  int* eidx_c3 = (int*)alloc(TT);
  int* eidx_uv = (int*)alloc(2 * (size_t)TT);
  if (off * sizeof(float) > ws_size) return; // would corrupt — fail loudly via wrong output

  float* G = buf0;
  float* Q2 = buf1;
  float* dA = buf0;
  float* dB = K2b; // reused AFTER gather_dQ2 consumed K2
  float* dG = buf1; // reused AFTER gather_dK2 consumed Q2

  int* cnt_c2 = cnt, *cnt_u2 = cnt + NN, *cnt_c3 = cnt + 2 * NN, *cnt_uv = cnt + 3 * NN;
  int* rp_c2 = rowptr, *rp_u2 = rowptr + (NN + 1), *rp_c3 = rowptr + 2 * (NN + 1), *rp_uv = rowptr + 3 * (NN + 1);
  int* cu_c2 = cursor, *cu_u2 = cursor + NN, *cu_c3 = cursor + 2 * NN, *cu_uv = cursor + 3 * NN;

  // zero segment accumulators (m2u,z2,m3u,z3 contiguous) and CSR counts
  hipMemsetAsync(m2u, 0, 4ull * NN * sizeof(float), stream);
  hipMemsetAsync(cnt, 0, 4ull * NN * sizeof(int), stream);

  int gemmB = (NN + 63) / 64;

  ln_fwd<<<(NN + 3) / 4, 256, 0, stream>>>(X, ln_g, ln_b, G, meanv, rstdv);

  gemm128<<<gemmB, 256, 0, stream>>>(G, W_Q2, Q2, NN, 0, 0);
  gemm128<<<gemmB, 256, 0, stream>>>(G, W_K2, K2b, NN, 0, 0);
  gemm128<<<gemmB, 256, 0, stream>>>(G, W_Q3, Q3, NN, 0, 0);
  gemm128<<<gemmB, 256, 0, stream>>>(G, W_K3, K3, NN, 0, 0);
  gemm128<<<gemmB, 256, 0, stream>>>(G, W_Qm, Qm, NN, 0, 0);
  gemm128<<<1, 256, 0, stream>>>(B_mem, W_Km, Km, KM, 0, 0);

  edge_mlp<<<(EE + 255) / 256, 256, 0, stream>>>(EA, We1, be1, We2, be2, a2);

  // CSR build (independent of everything above except the memset)
  hist2<<<(EE + 255) / 256, 256, 0, stream>>>(c2, u2, cnt_c2, cnt_u2, EE);
  hist_t3<<<(TT + 255) / 256, 256, 0, stream>>>(c3, u3, v3, cnt_c3, cnt_uv, TT);
  scan4<<<4, 256, 0, stream>>>(cnt, rowptr, cursor);
  scat2<<<(EE + 255) / 256, 256, 0, stream>>>(c2, u2, cu_c2, cu_u2, eidx_c2, eidx_u2, EE);
  scat_t3<<<(TT + 255) / 256, 256, 0, stream>>>(c3, u3, v3, cu_c3, cu_uv, eidx_c3, eidx_uv, TT);

  // forward scores + segment logsumexp
  e2_pass1<<<(EE + 3) / 4, 256, 0, stream>>>(Q2, K2b, a2, c2, u2, b2s, s2, m2u);
  t3_pass1<<<(TT + 3) / 4, 256, 0, stream>>>(Q3, K3, T_tau, c3, u3, v3, ttau, b3s, s3, m3u);
  e2_pass2<<<(EE + 255) / 256, 256, 0, stream>>>(s2, c2, m2u, z2);
  t3_pass2<<<(TT + 255) / 256, 256, 0, stream>>>(s3, c3, m3u, z3);
  seg_fin<<<(NN + 255) / 256, 256, 0, stream>>>(m2u, z2, m3u, z3, L2, L3);

  // per-edge backward weights (in place over s2/s3)
  e2_w<<<(EE + 255) / 256, 256, 0, stream>>>(s2, L2, c2, l2s);
  t3_w<<<(TT + 255) / 256, 256, 0, stream>>>(s3, L3, c3, l3s);

  int rowB = (NN + 3) / 4;
  // order-2 backward via gather (no atomics, no memsets)
  gather_e2<<<rowB, 256, 0, stream>>>(K2b, u2, s2, eidx_c2, rp_c2, dA); // dQ2 (K2 last read)
  gather_e2<<<rowB, 256, 0, stream>>>(Q2, c2, s2, eidx_u2, rp_u2, dB);  // dK2 into K2's storage (Q2 last read)
  gemm128<<<gemmB, 256, 0, stream>>>(dA, W_Q2, dG, NN, 1, 0); // dG := dQ2 @ W_Q2^T (overwrites Q2 storage)
  gemm128<<<gemmB, 256, 0, stream>>>(dB, W_K2, dG, NN, 1, 1);

  // order-3 backward via gather
  gather_q3<<<rowB, 256, 0, stream>>>(K3, T_tau, u3, v3, ttau, s3, eidx_c3, rp_c3, dA);
  gather_k3<<<rowB, 256, 0, stream>>>(Q3, K3, T_tau, c3, u3, v3, ttau, s3, eidx_uv, rp_uv, dB);
  gemm128<<<gemmB, 256, 0, stream>>>(dA, W_Q3, dG, NN, 1, 1);
  gemm128<<<gemmB, 256, 0, stream>>>(dB, W_K3, dG, NN, 1, 1);

  // memory-bank energy + dQm (full overwrite of dA)
  em_row<<<rowB, 256, 0, stream>>>(Qm, Km, bms, lms, dA, Lm);
  gemm128<<<gemmB, 256, 0, stream>>>(dA, W_Qm, dG, NN, 1, 1);

  // LN backward + clip + update + clip -> X_next
  ln_bwd<<<rowB, 256, 0, stream>>>(X, dG, ln_g, meanv, rstdv, out);

  eval_write<<<1, 256, 0, stream>>>(L2, L3, Lm, l2s, l3s, lms, b2s, b3s, bms, out + ND);
}

// Round 3
// 2157.879 us; speedup vs baseline: 1.8895x; 1.2618x over previous
//
#include <hip/hip_runtime.h>

#define NN 50000
#define DD 128
#define EE 800000
#define TT 400000
#define KM 32

static constexpr float INV_SQRT_D = 0.08838834764831845f; // 1/sqrt(128)
static constexpr float INV_D = 1.f / 128.f;

__device__ __forceinline__ float softplus_f(float x) {
  return (x > 20.f) ? x : log1pf(__expf(x));
}

__device__ __forceinline__ float gelu_tanh(float x) {
  float x3 = x * x * x;
  float u = 0.7978845608028654f * (x + 0.044715f * x3);
  u = fminf(fmaxf(u, -15.f), 15.f);
  float e = __expf(2.f * u);
  float t = (e - 1.f) / (e + 1.f);
  return 0.5f * x * (1.f + t);
}

__device__ __forceinline__ float wredsum(float v) {
#pragma unroll
  for (int m = 32; m; m >>= 1) v += __shfl_xor(v, m, 64);
  return v;
}

// bf16 helpers: packed u32 = two bf16 (lo = elem 2l, hi = elem 2l+1)
__device__ __forceinline__ float blo(unsigned w) { return __uint_as_float(w << 16); }
__device__ __forceinline__ float bhi(unsigned w) { return __uint_as_float(w & 0xffff0000u); }
__device__ __forceinline__ unsigned pack_bf16(float a, float b) {
  unsigned ua = __float_as_uint(a); ua += 0x7fff + ((ua >> 16) & 1);
  unsigned ub = __float_as_uint(b); ub += 0x7fff + ((ub >> 16) & 1);
  return (ua >> 16) | (ub & 0xffff0000u);
}

// ---------------- scalar params (one thread) ----------------
// params: [0]=b2 [1]=b3 [2]=bm [3]=cw2 [4]=cw3 [5]=cwm [6]=-sp2/b2 [7]=-sp3/b3 [8]=-spm/bm
__global__ void params_k(const float* l2, const float* l3, const float* lm,
                         const float* b2, const float* b3, const float* bm,
                         float* __restrict__ P) {
  if (threadIdx.x != 0) return;
  float B2 = fminf(softplus_f(b2[0]), 5.f);
  float B3 = fminf(softplus_f(b3[0]), 5.f);
  float Bm = fminf(softplus_f(bm[0]), 5.f);
  float S2 = softplus_f(l2[0]);
  float S3 = softplus_f(l3[0]);
  float Sm = softplus_f(lm[0]);
  P[0] = B2; P[1] = B3; P[2] = Bm;
  P[3] = -S2 * INV_SQRT_D; P[4] = -S3 * INV_D; P[5] = -Sm * INV_SQRT_D;
  P[6] = -S2 / B2; P[7] = -S3 / B3; P[8] = -Sm / Bm;
}

// ---------------- LayerNorm forward ----------------
__global__ __launch_bounds__(256) void ln_fwd(const float* __restrict__ X,
                                              const float* __restrict__ gamma,
                                              const float* __restrict__ beta,
                                              float* __restrict__ G,
                                              float* __restrict__ meanv,
                                              float* __restrict__ rstdv) {
  int row = blockIdx.x * 4 + (threadIdx.x >> 6);
  if (row >= NN) return;
  int l = threadIdx.x & 63;
  float2 x2 = *(const float2*)(X + row * DD + 2 * l);
  float mu = wredsum(x2.x + x2.y) * (1.f / DD);
  float d0 = x2.x - mu, d1 = x2.y - mu;
  float var = wredsum(d0 * d0 + d1 * d1) * (1.f / DD);
  float rstd = rsqrtf(var + 1e-5f);
  float2 g2 = *(const float2*)(gamma + 2 * l);
  float2 b2 = *(const float2*)(beta + 2 * l);
  float2 o;
  o.x = d0 * rstd * g2.x + b2.x;
  o.y = d1 * rstd * g2.y + b2.y;
  *(float2*)(G + row * DD + 2 * l) = o;
  if (l == 0) { meanv[row] = mu; rstdv[row] = rstd; }
}

// ---------------- 128-wide GEMM: C[M,128] = A[M,128] @ (W or W^T) ----------------
// mode: 0 = f32 store, 1 = f32 accumulate, 2 = bf16 store
__global__ __launch_bounds__(256, 1) void gemm128(const float* __restrict__ A,
                                                  const float* __restrict__ W,
                                                  void* __restrict__ Cv, int M,
                                                  int transW, int mode) {
  __shared__ float As[64][132];
  __shared__ float Wst[128][136];
  const int tid = threadIdx.x;
  const int r0 = blockIdx.x * 64;
  for (int idx = tid; idx < 128 * 128; idx += 256) {
    int k = idx >> 7, j = idx & 127;
    Wst[k][j] = transW ? W[j * 128 + k] : W[k * 128 + j];
  }
  for (int idx = tid; idx < 64 * 128; idx += 256) {
    int r = idx >> 7, d = idx & 127;
    int gr = r0 + r;
    As[r][d] = (gr < M) ? A[gr * 128 + d] : 0.f;
  }
  __syncthreads();
  const int tx = tid & 15, ty = tid >> 4;
  float acc[4][8];
#pragma unroll
  for (int i = 0; i < 4; i++)
#pragma unroll
    for (int j = 0; j < 8; j++) acc[i][j] = 0.f;
  for (int k = 0; k < 128; k += 4) {
    float a[4][4];
#pragma unroll
    for (int i = 0; i < 4; i++) {
      float4 v = *(const float4*)&As[ty * 4 + i][k];
      a[i][0] = v.x; a[i][1] = v.y; a[i][2] = v.z; a[i][3] = v.w;
    }
    float w[4][8];
#pragma unroll
    for (int dk = 0; dk < 4; dk++) {
      float4 v0 = *(const float4*)&Wst[k + dk][tx * 8];
      float4 v1 = *(const float4*)&Wst[k + dk][tx * 8 + 4];
      w[dk][0] = v0.x; w[dk][1] = v0.y; w[dk][2] = v0.z; w[dk][3] = v0.w;
      w[dk][4] = v1.x; w[dk][5] = v1.y; w[dk][6] = v1.z; w[dk][7] = v1.w;
    }
#pragma unroll
    for (int dk = 0; dk < 4; dk++)
#pragma unroll
      for (int i = 0; i < 4; i++)
#pragma unroll
        for (int j = 0; j < 8; j++)
          acc[i][j] = fmaf(a[i][dk], w[dk][j], acc[i][j]);
  }
#pragma unroll
  for (int i = 0; i < 4; i++) {
    int gr = r0 + ty * 4 + i;
    if (gr >= M) continue;
    if (mode == 2) {
      unsigned* cp = (unsigned*)Cv + gr * 64 + tx * 4;
      uint4 pk;
      pk.x = pack_bf16(acc[i][0], acc[i][1]);
      pk.y = pack_bf16(acc[i][2], acc[i][3]);
      pk.z = pack_bf16(acc[i][4], acc[i][5]);
      pk.w = pack_bf16(acc[i][6], acc[i][7]);
      *(uint4*)cp = pk;
    } else {
      float* cp = (float*)Cv + gr * 128 + tx * 8;
      if (mode == 1) {
#pragma unroll
        for (int j = 0; j < 8; j++) cp[j] += acc[i][j];
      } else {
#pragma unroll
        for (int j = 0; j < 8; j++) cp[j] = acc[i][j];
      }
    }
  }
}

// ---------------- edge MLP ----------------
__global__ __launch_bounds__(256) void edge_mlp(const float* __restrict__ EA,
                                                const float* __restrict__ We1,
                                                const float* __restrict__ be1,
                                                const float* __restrict__ We2,
                                                const float* __restrict__ be2,
                                                float* __restrict__ a2) {
  __shared__ float sW1[16 * 128];
  __shared__ float sb1[128];
  __shared__ float sW2[128];
  int tid = threadIdx.x;
  for (int i = tid; i < 2048; i += 256) sW1[i] = We1[i];
  if (tid < 128) { sb1[tid] = be1[tid]; sW2[tid] = We2[tid]; }
  __syncthreads();
  int e = blockIdx.x * 256 + tid;
  if (e >= EE) return;
  float ea[16];
#pragma unroll
  for (int q = 0; q < 4; q++) {
    float4 v = *(const float4*)(EA + (size_t)e * 16 + q * 4);
    ea[q * 4 + 0] = v.x; ea[q * 4 + 1] = v.y; ea[q * 4 + 2] = v.z; ea[q * 4 + 3] = v.w;
  }
  float acc = 0.f;
  for (int j = 0; j < 128; j += 4) {
    float4 h = *(const float4*)&sb1[j];
#pragma unroll
    for (int k = 0; k < 16; k++) {
      float4 wv = *(const float4*)&sW1[k * 128 + j];
      h.x = fmaf(ea[k], wv.x, h.x);
      h.y = fmaf(ea[k], wv.y, h.y);
      h.z = fmaf(ea[k], wv.z, h.z);
      h.w = fmaf(ea[k], wv.w, h.w);
    }
    float4 w2 = *(const float4*)&sW2[j];
    acc = fmaf(gelu_tanh(h.x), w2.x, acc);
    acc = fmaf(gelu_tanh(h.y), w2.y, acc);
    acc = fmaf(gelu_tanh(h.z), w2.z, acc);
    acc = fmaf(gelu_tanh(h.w), w2.w, acc);
  }
  a2[e] = acc + be2[0];
}

// ---------------- CSR build ----------------
__global__ __launch_bounds__(256) void hist2(const int* __restrict__ a,
                                             const int* __restrict__ b,
                                             int* __restrict__ ca,
                                             int* __restrict__ cb, int n) {
  int e = blockIdx.x * 256 + threadIdx.x;
  if (e >= n) return;
  atomicAdd(&ca[a[e]], 1);
  atomicAdd(&cb[b[e]], 1);
}

__global__ __launch_bounds__(256) void hist_t3(const int* __restrict__ c,
                                               const int* __restrict__ u,
                                               const int* __restrict__ v,
                                               int* __restrict__ cc,
                                               int* __restrict__ cuv, int n) {
  int t = blockIdx.x * 256 + threadIdx.x;
  if (t >= n) return;
  atomicAdd(&cc[c[t]], 1);
  atomicAdd(&cuv[u[t]], 1);
  atomicAdd(&cuv[v[t]], 1);
}

__global__ __launch_bounds__(256) void scan4(const int* __restrict__ cnt,
                                             int* __restrict__ rowptr,
                                             int* __restrict__ cursor) {
  const int* c = cnt + (size_t)blockIdx.x * NN;
  int* rp = rowptr + (size_t)blockIdx.x * (NN + 1);
  int* cur = cursor + (size_t)blockIdx.x * NN;
  __shared__ int wt[4];
  int tid = threadIdx.x, lane = tid & 63, wid = tid >> 6;
  int base = 0;
  for (int i0 = 0; i0 < NN; i0 += 256) {
    int i = i0 + tid;
    int v = (i < NN) ? c[i] : 0;
    int x = v;
#pragma unroll
    for (int d = 1; d < 64; d <<= 1) {
      int y = __shfl_up(x, d, 64);
      if (lane >= d) x += y;
    }
    __syncthreads();
    if (lane == 63) wt[wid] = x;
    __syncthreads();
    int add = 0;
    for (int w = 0; w < wid; w++) add += wt[w];
    int excl = base + add + x - v;
    if (i < NN) { rp[i] = excl; cur[i] = excl; }
    base += wt[0] + wt[1] + wt[2] + wt[3];
  }
  if (tid == 0) rp[NN] = base;
}

// scatter with payloads: c2-CSR carries (edge id, partner u, a2); u2-CSR carries (edge id, partner c)
__global__ __launch_bounds__(256) void scat2(const int* __restrict__ c2,
                                             const int* __restrict__ u2,
                                             const float* __restrict__ a2,
                                             int* __restrict__ cuc,
                                             int* __restrict__ cuu,
                                             int* __restrict__ eidx_c, int* __restrict__ part_c,
                                             float* __restrict__ apay_c,
                                             int* __restrict__ eidx_u, int* __restrict__ part_u,
                                             int n) {
  int e = blockIdx.x * 256 + threadIdx.x;
  if (e >= n) return;
  int c = c2[e], u = u2[e];
  int p = atomicAdd(&cuc[c], 1);
  eidx_c[p] = e; part_c[p] = u; apay_c[p] = a2[e];
  p = atomicAdd(&cuu[u], 1);
  eidx_u[p] = e; part_u[p] = c;
}

// t3: c3-CSR carries (u, v, t<<1|tau); uv-CSR carries (partner o, c, t<<1|tau)
__global__ __launch_bounds__(256) void scat_t3(const int* __restrict__ c3,
                                               const int* __restrict__ u3,
                                               const int* __restrict__ v3,
                                               const int* __restrict__ ttau,
                                               int* __restrict__ cuc,
                                               int* __restrict__ cuv,
                                               int* __restrict__ pu_c, int* __restrict__ pv_c,
                                               int* __restrict__ tpk_c,
                                               int* __restrict__ po, int* __restrict__ pc,
                                               int* __restrict__ tpk_uv, int n) {
  int t = blockIdx.x * 256 + threadIdx.x;
  if (t >= n) return;
  int c = c3[t], u = u3[t], v = v3[t];
  int tp = (t << 1) | (ttau[t] & 1);
  int p = atomicAdd(&cuc[c], 1);
  pu_c[p] = u; pv_c[p] = v; tpk_c[p] = tp;
  p = atomicAdd(&cuv[u], 1);
  po[p] = v; pc[p] = c; tpk_uv[p] = tp;
  p = atomicAdd(&cuv[v], 1);
  po[p] = u; pc[p] = c; tpk_uv[p] = tp;
}

// ---------------- fused e2 forward + dQ2 (one wave per c-node, online softmax) ----------------
__global__ __launch_bounds__(256) void e2_fused(const unsigned* __restrict__ Q2b,
                                                const unsigned* __restrict__ K2b,
                                                const float* __restrict__ P,
                                                const int* __restrict__ eidx,
                                                const int* __restrict__ part,
                                                const float* __restrict__ apay,
                                                const int* __restrict__ rp,
                                                float* __restrict__ s2,
                                                float* __restrict__ L2,
                                                float* __restrict__ dA) {
  int row = blockIdx.x * 4 + (int)(threadIdx.x >> 6);
  if (row >= NN) return;
  int l = threadIdx.x & 63;
  float b2 = P[0], cw2 = P[3];
  unsigned qw = Q2b[row * 64 + l];
  float qx = blo(qw), qy = bhi(qw);
  int s = rp[row], e = rp[row + 1];
  float m = -3.0e38f, z = 0.f, ax = 0.f, ay = 0.f;
  for (int i = s; i < e; i++) {
    int ed = eidx[i];
    int u = part[i];
    unsigned kw = K2b[u * 64 + l];
    float kx = blo(kw), ky = bhi(kw);
    float dot = wredsum(qx * kx + qy * ky);
    float sv = b2 * dot * INV_SQRT_D + apay[i];
    if (l == 0) s2[ed] = sv;
    if (sv <= m) {
      float p = __expf(sv - m);
      z += p; ax = fmaf(p, kx, ax); ay = fmaf(p, ky, ay);
    } else {
      float r = __expf(m - sv);
      z = fmaf(z, r, 1.f); ax = fmaf(ax, r, kx); ay = fmaf(ay, r, ky);
      m = sv;
    }
  }
  float coef = (z > 0.f) ? cw2 / z : 0.f;
  if (l == 0) L2[row] = (z > 0.f) ? (m + __logf(z)) : 0.f;
  float2 o; o.x = coef * ax; o.y = coef * ay;
  *(float2*)(dA + (size_t)row * DD + 2 * l) = o;
}

// ---------------- dK2 gather (one wave per u-node) ----------------
__global__ __launch_bounds__(256) void dk2_gather(const unsigned* __restrict__ Q2b,
                                                  const float* __restrict__ s2,
                                                  const float* __restrict__ L2,
                                                  const float* __restrict__ P,
                                                  const int* __restrict__ eidx,
                                                  const int* __restrict__ part,
                                                  const int* __restrict__ rp,
                                                  float* __restrict__ dB) {
  int row = blockIdx.x * 4 + (int)(threadIdx.x >> 6);
  if (row >= NN) return;
  int l = threadIdx.x & 63;
  float cw2 = P[3];
  int s = rp[row], e = rp[row + 1];
  float ax = 0.f, ay = 0.f;
  for (int i = s; i < e; i++) {
    int ed = eidx[i];
    int c = part[i];
    float w = cw2 * __expf(s2[ed] - L2[c]);
    unsigned qw = Q2b[c * 64 + l];
    ax = fmaf(w, blo(qw), ax); ay = fmaf(w, bhi(qw), ay);
  }
  float2 o; o.x = ax; o.y = ay;
  *(float2*)(dB + (size_t)row * DD + 2 * l) = o;
}

// ---------------- fused t3 forward + dQ3 (one wave per c-node) ----------------
__global__ __launch_bounds__(256) void t3_fused(const unsigned* __restrict__ Q3b,
                                                const unsigned* __restrict__ K3b,
                                                const float* __restrict__ Tt,
                                                const float* __restrict__ P,
                                                const int* __restrict__ pu,
                                                const int* __restrict__ pv,
                                                const int* __restrict__ tpk,
                                                const int* __restrict__ rp,
                                                float* __restrict__ s3,
                                                float* __restrict__ L3,
                                                float* __restrict__ dA) {
  __shared__ float sT[2 * DD];
  int tid = threadIdx.x;
  sT[tid] = Tt[tid]; // 256 floats
  __syncthreads();
  int row = blockIdx.x * 4 + (tid >> 6);
  if (row >= NN) return;
  int l = tid & 63;
  float b3 = P[1], cw3 = P[4];
  float2* sT2 = (float2*)sT;
  unsigned qw = Q3b[row * 64 + l];
  float qx = blo(qw), qy = bhi(qw);
  int s = rp[row], e = rp[row + 1];
  float m = -3.0e38f, z = 0.f, ax = 0.f, ay = 0.f;
  for (int i = s; i < e; i++) {
    int u = pu[i], v = pv[i], tp = tpk[i];
    int t = tp >> 1, ta = tp & 1;
    unsigned kuw = K3b[u * 64 + l];
    unsigned kvw = K3b[v * 64 + l];
    float2 tv = sT2[ta * 64 + l];
    float e0 = blo(kuw) * blo(kvw) * tv.x;
    float e1 = bhi(kuw) * bhi(kvw) * tv.y;
    float dot = wredsum(qx * e0 + qy * e1);
    float sv = b3 * dot * INV_D;
    if (l == 0) s3[t] = sv;
    if (sv <= m) {
      float p = __expf(sv - m);
      z += p; ax = fmaf(p, e0, ax); ay = fmaf(p, e1, ay);
    } else {
      float r = __expf(m - sv);
      z = fmaf(z, r, 1.f); ax = fmaf(ax, r, e0); ay = fmaf(ay, r, e1);
      m = sv;
    }
  }
  float coef = (z > 0.f) ? cw3 / z : 0.f;
  if (l == 0) L3[row] = (z > 0.f) ? (m + __logf(z)) : 0.f;
  float2 o; o.x = coef * ax; o.y = coef * ay;
  *(float2*)(dA + (size_t)row * DD + 2 * l) = o;
}

// ---------------- dK3 gather (one wave per node of merged u/v CSR) ----------------
__global__ __launch_bounds__(256) void dk3_gather(const unsigned* __restrict__ Q3b,
                                                  const unsigned* __restrict__ K3b,
                                                  const float* __restrict__ Tt,
                                                  const float* __restrict__ s3,
                                                  const float* __restrict__ L3,
                                                  const float* __restrict__ P,
                                                  const int* __restrict__ po,
                                                  const int* __restrict__ pc,
                                                  const int* __restrict__ tpk,
                                                  const int* __restrict__ rp,
                                                  float* __restrict__ dB) {
  __shared__ float sT[2 * DD];
  int tid = threadIdx.x;
  sT[tid] = Tt[tid];
  __syncthreads();
  int row = blockIdx.x * 4 + (tid >> 6);
  if (row >= NN) return;
  int l = tid & 63;
  float cw3 = P[4];
  float2* sT2 = (float2*)sT;
  int s = rp[row], e = rp[row + 1];
  float ax = 0.f, ay = 0.f;
  for (int i = s; i < e; i++) {
    int o = po[i], c = pc[i], tp = tpk[i];
    int t = tp >> 1, ta = tp & 1;
    float w = cw3 * __expf(s3[t] - L3[c]);
    unsigned qw = Q3b[c * 64 + l];
    unsigned kw = K3b[o * 64 + l];
    float2 tv = sT2[ta * 64 + l];
    ax = fmaf(w * tv.x, blo(qw) * blo(kw), ax);
    ay = fmaf(w * tv.y, bhi(qw) * bhi(kw), ay);
  }
  float2 o2; o2.x = ax; o2.y = ay;
  *(float2*)(dB + (size_t)row * DD + 2 * l) = o2;
}

// ---------------- memory-bank energy (bf16 Qm) ----------------
__global__ __launch_bounds__(256) void em_row(const unsigned* __restrict__ Qmb,
                                              const float* __restrict__ Km,
                                              const float* __restrict__ P,
                                              float* __restrict__ dQm,
                                              float* __restrict__ Lm) {
  __shared__ float sKm[KM * DD];
  int tid = threadIdx.x;
  for (int i = tid; i < KM * DD; i += 256) sKm[i] = Km[i];
  __syncthreads();
  int row = blockIdx.x * 4 + (tid >> 6);
  if (row >= NN) return;
  int l = tid & 63;
  float bm = P[2], cwm = P[5];
  int k = l & 31, h = l >> 5;
  const unsigned* qrow = Qmb + row * 64;
  float part = 0.f;
  for (int d2 = h * 32; d2 < h * 32 + 32; d2++) {
    unsigned qw = qrow[d2];
    part = fmaf(blo(qw), sKm[k * DD + 2 * d2], part);
    part = fmaf(bhi(qw), sKm[k * DD + 2 * d2 + 1], part);
  }
  part += __shfl_xor(part, 32, 64);
  float sk = bm * part * INV_SQRT_D;
  float mx = sk;
#pragma unroll
  for (int m = 16; m; m >>= 1) mx = fmaxf(mx, __shfl_xor(mx, m, 64));
  float ex = __expf(sk - mx);
  float zz = ex;
#pragma unroll
  for (int m = 16; m; m >>= 1) zz += __shfl_xor(zz, m, 64);
  float lse = mx + __logf(zz);
  if (l == 0) Lm[row] = lse;
  float pk = ex / zz;
  float accx = 0.f, accy = 0.f;
#pragma unroll
  for (int kk = 0; kk < 32; kk++) {
    float pkk = __shfl(pk, kk, 64);
    accx = fmaf(pkk, sKm[kk * DD + 2 * l], accx);
    accy = fmaf(pkk, sKm[kk * DD + 2 * l + 1], accy);
  }
  float2 o; o.x = cwm * accx; o.y = cwm * accy;
  *(float2*)(dQm + row * DD + 2 * l) = o;
}

// ---------------- LN backward + clips + update ----------------
__global__ __launch_bounds__(256) void ln_bwd(const float* __restrict__ X,
                                              const float* __restrict__ dG,
                                              const float* __restrict__ gamma,
                                              const float* __restrict__ meanv,
                                              const float* __restrict__ rstdv,
                                              float* __restrict__ out) {
  int row = blockIdx.x * 4 + (threadIdx.x >> 6);
  if (row >= NN) return;
  int l = threadIdx.x & 63;
  float mu = meanv[row], rstd = rstdv[row];
  float2 x2 = *(const float2*)(X + row * DD + 2 * l);
  float2 g2 = *(const float2*)(dG + row * DD + 2 * l);
  float2 ga = *(const float2*)(gamma + 2 * l);
  float xh0 = (x2.x - mu) * rstd, xh1 = (x2.y - mu) * rstd;
  float dh0 = g2.x * ga.x, dh1 = g2.y * ga.y;
  float sa = wredsum(dh0 + dh1) * (1.f / DD);
  float sb = wredsum(dh0 * xh0 + dh1 * xh1) * (1.f / DD);
  float dx0 = rstd * (dh0 - sa - xh0 * sb);
  float dx1 = rstd * (dh1 - sa - xh1 * sb);
  float gn = fmaxf(sqrtf(wredsum(dx0 * dx0 + dx1 * dx1)), 1e-6f);
  float sc = fminf(1.f / gn, 1.f);
  dx0 *= sc; dx1 *= sc;
  float xn0 = x2.x - 0.1f * 0.9999f * dx0;
  float xn1 = x2.y - 0.1f * 0.9999f * dx1;
  float sn = fmaxf(sqrtf(wredsum(xn0 * xn0 + xn1 * xn1)), 1e-6f);
  float sc2 = fminf(10.f / sn, 1.f);
  float2 o; o.x = xn0 * sc2; o.y = xn1 * sc2;
  *(float2*)(out + row * DD + 2 * l) = o;
}

// ---------------- final energy scalar ----------------
__global__ __launch_bounds__(256) void eval_write(const float* __restrict__ L2,
                                                  const float* __restrict__ L3,
                                                  const float* __restrict__ Lm,
                                                  const float* __restrict__ P,
                                                  float* __restrict__ out) {
  int tid = threadIdx.x;
  float a2 = 0.f, a3 = 0.f, am = 0.f;
  for (int i = tid; i < NN; i += 256) { a2 += L2[i]; a3 += L3[i]; am += Lm[i]; }
  a2 = wredsum(a2); a3 = wredsum(a3); am = wredsum(am);
  __shared__ float r2[4], r3[4], rm[4];
  int wv = tid >> 6, l = tid & 63;
  if (l == 0) { r2[wv] = a2; r3[wv] = a3; rm[wv] = am; }
  __syncthreads();
  if (tid == 0) {
    float S2 = r2[0] + r2[1] + r2[2] + r2[3];
    float S3 = r3[0] + r3[1] + r3[2] + r3[3];
    float Sm = rm[0] + rm[1] + rm[2] + rm[3];
    out[0] = P[6] * S2 + P[7] * S3 + P[8] * Sm;
  }
}

extern "C" void kernel_launch(void* const* d_in, const int* in_sizes, int n_in,
                              void* d_out, int out_size, void* d_ws, size_t ws_size,
                              hipStream_t stream) {
  (void)in_sizes; (void)n_in; (void)out_size;
  const float* X = (const float*)d_in[0];
  const float* EA = (const float*)d_in[1];
  const float* ln_g = (const float*)d_in[2];
  const float* ln_b = (const float*)d_in[3];
  const float* W_Q2 = (const float*)d_in[4];
  const float* W_K2 = (const float*)d_in[5];
  const float* W_Q3 = (const float*)d_in[6];
  const float* W_K3 = (const float*)d_in[7];
  const float* T_tau = (const float*)d_in[8];
  const float* W_Qm = (const float*)d_in[9];
  const float* W_Km = (const float*)d_in[10];
  const float* B_mem = (const float*)d_in[11];
  const float* We1 = (const float*)d_in[12];
  const float* be1 = (const float*)d_in[13];
  const float* We2 = (const float*)d_in[14];
  const float* be2 = (const float*)d_in[15];
  const float* l2s = (const float*)d_in[16];
  const float* l3s = (const float*)d_in[17];
  const float* lms = (const float*)d_in[18];
  const float* b2s = (const float*)d_in[19];
  const float* b3s = (const float*)d_in[20];
  const float* bms = (const float*)d_in[21];
  const int* c2 = (const int*)d_in[22];
  const int* u2 = (const int*)d_in[23];
  const int* c3 = (const int*)d_in[24];
  const int* u3 = (const int*)d_in[25];
  const int* v3 = (const int*)d_in[26];
  const int* ttau = (const int*)d_in[27];
  float* out = (float*)d_out;

  float* ws = (float*)d_ws;
  size_t off = 0;
  auto alloc = [&](size_t n) { float* p = ws + off; off += n; return p; };
  const size_t ND = (size_t)NN * DD;
  float* buf0 = alloc(ND);           // G -> dA
  float* dG = alloc(ND);
  float* dB = alloc(ND);
  unsigned* Q2b = (unsigned*)alloc(ND / 2);
  unsigned* K2b = (unsigned*)alloc(ND / 2);
  unsigned* Q3b = (unsigned*)alloc(ND / 2);
  unsigned* K3b = (unsigned*)alloc(ND / 2);
  unsigned* Qmb = (unsigned*)alloc(ND / 2);
  float* Km = alloc((size_t)KM * DD);
  float* a2 = alloc(EE);
  float* s2 = alloc(EE);
  float* s3 = alloc(TT);
  float* meanv = alloc(NN);
  float* rstdv = alloc(NN);
  float* L2 = alloc(NN);
  float* L3 = alloc(NN);
  float* Lm = alloc(NN);
  float* Pparams = alloc(16);
  int* cnt = (int*)alloc(4 * (size_t)NN);
  int* rowptr = (int*)alloc(4 * (size_t)(NN + 1));
  int* cursor = (int*)alloc(4 * (size_t)NN);
  int* eidx_c2 = (int*)alloc(EE);
  int* part_c2 = (int*)alloc(EE);
  float* apay_c2 = alloc(EE);
  int* eidx_u2 = (int*)alloc(EE);
  int* part_u2 = (int*)alloc(EE);
  int* pu_c3 = (int*)alloc(TT);
  int* pv_c3 = (int*)alloc(TT);
  int* tpk_c3 = (int*)alloc(TT);
  int* po_uv = (int*)alloc(2 * (size_t)TT);
  int* pc_uv = (int*)alloc(2 * (size_t)TT);
  int* tpk_uv = (int*)alloc(2 * (size_t)TT);
  if (off * sizeof(float) > ws_size) return;

  float* G = buf0;
  float* dA = buf0;

  int* cnt_c2 = cnt, *cnt_u2 = cnt + NN, *cnt_c3 = cnt + 2 * NN, *cnt_uv = cnt + 3 * NN;
  int* rp_c2 = rowptr, *rp_u2 = rowptr + (NN + 1), *rp_c3 = rowptr + 2 * (NN + 1), *rp_uv = rowptr + 3 * (NN + 1);
  int* cu_c2 = cursor, *cu_u2 = cursor + NN, *cu_c3 = cursor + 2 * NN, *cu_uv = cursor + 3 * NN;

  hipMemsetAsync(cnt, 0, 4ull * NN * sizeof(int), stream);

  params_k<<<1, 64, 0, stream>>>(l2s, l3s, lms, b2s, b3s, bms, Pparams);

  int gemmB = (NN + 63) / 64;
  int rowB = (NN + 3) / 4;

  ln_fwd<<<rowB, 256, 0, stream>>>(X, ln_g, ln_b, G, meanv, rstdv);

  gemm128<<<gemmB, 256, 0, stream>>>(G, W_Q2, Q2b, NN, 0, 2);
  gemm128<<<gemmB, 256, 0, stream>>>(G, W_K2, K2b, NN, 0, 2);
  gemm128<<<gemmB, 256, 0, stream>>>(G, W_Q3, Q3b, NN, 0, 2);
  gemm128<<<gemmB, 256, 0, stream>>>(G, W_K3, K3b, NN, 0, 2);
  gemm128<<<gemmB, 256, 0, stream>>>(G, W_Qm, Qmb, NN, 0, 2);
  gemm128<<<1, 256, 0, stream>>>(B_mem, W_Km, Km, KM, 0, 0);

  edge_mlp<<<(EE + 255) / 256, 256, 0, stream>>>(EA, We1, be1, We2, be2, a2);

  hist2<<<(EE + 255) / 256, 256, 0, stream>>>(c2, u2, cnt_c2, cnt_u2, EE);
  hist_t3<<<(TT + 255) / 256, 256, 0, stream>>>(c3, u3, v3, cnt_c3, cnt_uv, TT);
  scan4<<<4, 256, 0, stream>>>(cnt, rowptr, cursor);
  scat2<<<(EE + 255) / 256, 256, 0, stream>>>(c2, u2, a2, cu_c2, cu_u2,
                                              eidx_c2, part_c2, apay_c2,
                                              eidx_u2, part_u2, EE);
  scat_t3<<<(TT + 255) / 256, 256, 0, stream>>>(c3, u3, v3, ttau, cu_c3, cu_uv,
                                                pu_c3, pv_c3, tpk_c3,
                                                po_uv, pc_uv, tpk_uv, TT);

  // e2: fused forward + dQ2 (writes dA over G), then dK2 gather
  e2_fused<<<rowB, 256, 0, stream>>>(Q2b, K2b, Pparams, eidx_c2, part_c2, apay_c2,
                                     rp_c2, s2, L2, dA);
  dk2_gather<<<rowB, 256, 0, stream>>>(Q2b, s2, L2, Pparams, eidx_u2, part_u2, rp_u2, dB);
  gemm128<<<gemmB, 256, 0, stream>>>(dA, W_Q2, dG, NN, 1, 0);
  gemm128<<<gemmB, 256, 0, stream>>>(dB, W_K2, dG, NN, 1, 1);

  // t3: fused forward + dQ3, then dK3 gather
  t3_fused<<<rowB, 256, 0, stream>>>(Q3b, K3b, T_tau, Pparams, pu_c3, pv_c3, tpk_c3,
                                     rp_c3, s3, L3, dA);
  dk3_gather<<<rowB, 256, 0, stream>>>(Q3b, K3b, T_tau, s3, L3, Pparams,
                                       po_uv, pc_uv, tpk_uv, rp_uv, dB);
  gemm128<<<gemmB, 256, 0, stream>>>(dA, W_Q3, dG, NN, 1, 1);
  gemm128<<<gemmB, 256, 0, stream>>>(dB, W_K3, dG, NN, 1, 1);

  // memory bank
  em_row<<<rowB, 256, 0, stream>>>(Qmb, Km, Pparams, dA, Lm);
  gemm128<<<gemmB, 256, 0, stream>>>(dA, W_Qm, dG, NN, 1, 1);

  ln_bwd<<<rowB, 256, 0, stream>>>(X, dG, ln_g, meanv, rstdv, out);

  eval_write<<<1, 256, 0, stream>>>(L2, L3, Lm, Pparams, out + ND);
}

// Round 4
// 1113.584 us; speedup vs baseline: 3.6614x; 1.9378x over previous
//
#include <hip/hip_runtime.h>

#define NN 50000
#define DD 128
#define EE 800000
#define TT 400000
#define KM 32
#define UU 320  // uints per 640-col bf16 row

static constexpr float INV_SQRT_D = 0.08838834764831845f; // 1/sqrt(128)
static constexpr float INV_D = 1.f / 128.f;

typedef __attribute__((ext_vector_type(8))) short bf16x8;
typedef __attribute__((ext_vector_type(4))) float f32x4;
typedef unsigned short ushort_t;

__device__ __forceinline__ float softplus_f(float x) {
  return (x > 20.f) ? x : log1pf(__expf(x));
}

__device__ __forceinline__ float gelu_tanh(float x) {
  float x3 = x * x * x;
  float u = 0.7978845608028654f * (x + 0.044715f * x3);
  u = fminf(fmaxf(u, -15.f), 15.f);
  float e = __expf(2.f * u);
  float t = (e - 1.f) / (e + 1.f);
  return 0.5f * x * (1.f + t);
}

__device__ __forceinline__ float wredsum(float v) {
#pragma unroll
  for (int m = 32; m; m >>= 1) v += __shfl_xor(v, m, 64);
  return v;
}

__device__ __forceinline__ float redsum16(float v) {
#pragma unroll
  for (int m = 1; m < 16; m <<= 1) v += __shfl_xor(v, m, 64);
  return v;
}

__device__ __forceinline__ float blo(unsigned w) { return __uint_as_float(w << 16); }
__device__ __forceinline__ float bhi(unsigned w) { return __uint_as_float(w & 0xffff0000u); }
__device__ __forceinline__ unsigned pack_bf16(float a, float b) {
  unsigned ua = __float_as_uint(a); ua += 0x7fff + ((ua >> 16) & 1);
  unsigned ub = __float_as_uint(b); ub += 0x7fff + ((ub >> 16) & 1);
  return (ua >> 16) | (ub & 0xffff0000u);
}
__device__ __forceinline__ ushort_t bf16_1(float x) {
  unsigned u = __float_as_uint(x); u += 0x7fff + ((u >> 16) & 1);
  return (ushort_t)(u >> 16);
}
__device__ __forceinline__ void unp8(uint4 w, float* f) {
  f[0] = blo(w.x); f[1] = bhi(w.x); f[2] = blo(w.y); f[3] = bhi(w.y);
  f[4] = blo(w.z); f[5] = bhi(w.z); f[6] = blo(w.w); f[7] = bhi(w.w);
}
__device__ __forceinline__ uint4 pk8(const float* f) {
  uint4 r;
  r.x = pack_bf16(f[0], f[1]); r.y = pack_bf16(f[2], f[3]);
  r.z = pack_bf16(f[4], f[5]); r.w = pack_bf16(f[6], f[7]);
  return r;
}

// params: [0]=b2 [1]=b3 [2]=bm [3]=cw2 [4]=cw3 [5]=cwm [6]=-sp2/b2 [7]=-sp3/b3 [8]=-spm/bm
__global__ void params_k(const float* l2, const float* l3, const float* lm,
                         const float* b2, const float* b3, const float* bm,
                         float* __restrict__ P) {
  if (threadIdx.x != 0) return;
  float B2 = fminf(softplus_f(b2[0]), 5.f);
  float B3 = fminf(softplus_f(b3[0]), 5.f);
  float Bm = fminf(softplus_f(bm[0]), 5.f);
  float S2 = softplus_f(l2[0]);
  float S3 = softplus_f(l3[0]);
  float Sm = softplus_f(lm[0]);
  P[0] = B2; P[1] = B3; P[2] = Bm;
  P[3] = -S2 * INV_SQRT_D; P[4] = -S3 * INV_D; P[5] = -Sm * INV_SQRT_D;
  P[6] = -S2 / B2; P[7] = -S3 / B3; P[8] = -Sm / Bm;
}

// ---------------- LayerNorm forward -> bf16 G ----------------
__global__ __launch_bounds__(256) void ln_fwd(const float* __restrict__ X,
                                              const float* __restrict__ gamma,
                                              const float* __restrict__ beta,
                                              unsigned* __restrict__ Gb,
                                              float* __restrict__ meanv,
                                              float* __restrict__ rstdv) {
  int row = blockIdx.x * 4 + (threadIdx.x >> 6);
  if (row >= NN) return;
  int l = threadIdx.x & 63;
  float2 x2 = *(const float2*)(X + row * DD + 2 * l);
  float mu = wredsum(x2.x + x2.y) * (1.f / DD);
  float d0 = x2.x - mu, d1 = x2.y - mu;
  float var = wredsum(d0 * d0 + d1 * d1) * (1.f / DD);
  float rstd = rsqrtf(var + 1e-5f);
  float2 g2 = *(const float2*)(gamma + 2 * l);
  float2 b2 = *(const float2*)(beta + 2 * l);
  float o0 = d0 * rstd * g2.x + b2.x;
  float o1 = d1 * rstd * g2.y + b2.y;
  Gb[(size_t)row * 64 + l] = pack_bf16(o0, o1);
  if (l == 0) { meanv[row] = mu; rstdv[row] = rstd; }
}

// ---------------- weight conversion: Wt[n][k] (fwd) and Wc[n][k-cat] (bwd) ----------------
__global__ __launch_bounds__(256) void w_conv(const float* W0, const float* W1, const float* W2,
                                              const float* W3, const float* W4,
                                              ushort_t* __restrict__ Wt,
                                              ushort_t* __restrict__ Wc) {
  int idx = blockIdx.x * 256 + threadIdx.x;
  if (idx >= 640 * 128) return;
  const float* Ws[5] = {W0, W1, W2, W3, W4};
  int n = idx >> 7, k = idx & 127;
  Wt[idx] = bf16_1(Ws[n >> 7][(size_t)k * 128 + (n & 127)]);       // Wt[n][k] = W_i[k][n%128]
  int k2 = idx >> 7, n2 = idx & 127;
  Wc[(size_t)n2 * 640 + k2] = bf16_1(Ws[k2 >> 7][(size_t)n2 * 128 + (k2 & 127)]); // Wc[n][k] = W_i[n][k%128]
}

// ---------------- fwd MFMA GEMM: QK[M,640](bf16) = Gb[M,128](bf16) @ Wt^T ----------------
__global__ __launch_bounds__(256) void mfma_fwd(const ushort_t* __restrict__ Gb,
                                                const ushort_t* __restrict__ Wt,
                                                ushort_t* __restrict__ QK, int M) {
  __shared__ ushort_t sB[64][136];
  int tid = threadIdx.x;
  int nb = blockIdx.y * 64;
  for (int idx = tid; idx < 64 * 16; idx += 256) {
    int r = idx >> 4, c8 = idx & 15;
    *(bf16x8*)&sB[r][c8 * 8] = *(const bf16x8*)(Wt + (size_t)(nb + r) * 128 + c8 * 8);
  }
  __syncthreads();
  int w = tid >> 6, l = tid & 63, quad = l >> 4, j = l & 15;
  int row0 = blockIdx.x * 64 + w * 16;
  int arow = row0 + j; if (arow >= M) arow = M - 1;
  const bf16x8* ap = (const bf16x8*)(Gb + (size_t)arow * 128);
  f32x4 acc[4];
#pragma unroll
  for (int nt = 0; nt < 4; nt++) acc[nt] = (f32x4){0.f, 0.f, 0.f, 0.f};
#pragma unroll
  for (int kc = 0; kc < 4; kc++) {
    bf16x8 a = ap[kc * 4 + quad];
#pragma unroll
    for (int nt = 0; nt < 4; nt++) {
      bf16x8 b = *(const bf16x8*)&sB[nt * 16 + j][kc * 32 + quad * 8];
      acc[nt] = __builtin_amdgcn_mfma_f32_16x16x32_bf16(a, b, acc[nt], 0, 0, 0);
    }
  }
#pragma unroll
  for (int nt = 0; nt < 4; nt++)
#pragma unroll
    for (int r = 0; r < 4; r++) {
      int row = row0 + quad * 4 + r;
      if (row < M) QK[(size_t)row * 640 + nb + nt * 16 + j] = bf16_1(acc[nt][r]);
    }
}

// ---------------- bwd MFMA GEMM: dG[M,128](bf16) = dAll[M,640](bf16) @ Wc^T ----------------
__global__ __launch_bounds__(256) void mfma_bwd(const ushort_t* __restrict__ dAll,
                                                const ushort_t* __restrict__ Wc,
                                                unsigned* __restrict__ dG, int M) {
  __shared__ ushort_t sB[64][40];
  int tid = threadIdx.x;
  int nb = blockIdx.y * 64;
  int w = tid >> 6, l = tid & 63, quad = l >> 4, j = l & 15;
  int row0 = blockIdx.x * 64 + w * 16;
  int arow = row0 + j; if (arow >= M) arow = M - 1;
  const ushort_t* arp = dAll + (size_t)arow * 640;
  f32x4 acc[4];
#pragma unroll
  for (int nt = 0; nt < 4; nt++) acc[nt] = (f32x4){0.f, 0.f, 0.f, 0.f};
  int sr = tid >> 2, sc = tid & 3;
  for (int kc = 0; kc < 20; kc++) {
    __syncthreads();
    *(bf16x8*)&sB[sr][sc * 8] = *(const bf16x8*)(Wc + (size_t)(nb + sr) * 640 + kc * 32 + sc * 8);
    __syncthreads();
    bf16x8 a = *(const bf16x8*)(arp + kc * 32 + quad * 8);
#pragma unroll
    for (int nt = 0; nt < 4; nt++) {
      bf16x8 b = *(const bf16x8*)&sB[nt * 16 + j][quad * 8];
      acc[nt] = __builtin_amdgcn_mfma_f32_16x16x32_bf16(a, b, acc[nt], 0, 0, 0);
    }
  }
  // pack two adjacent cols into one uint: lane j covers col pairs via tile pairs
#pragma unroll
  for (int nt = 0; nt < 4; nt++)
#pragma unroll
    for (int r = 0; r < 4; r++) {
      int row = row0 + quad * 4 + r;
      if (row < M) ((ushort_t*)dG)[(size_t)row * 128 + nb + nt * 16 + j] = bf16_1(acc[nt][r]);
    }
}

// ---------------- small fp32 GEMM for Km = B_mem @ W_Km ----------------
__global__ __launch_bounds__(256, 1) void gemm_km(const float* __restrict__ A,
                                                  const float* __restrict__ W,
                                                  float* __restrict__ C, int M) {
  __shared__ float As[32][132];
  __shared__ float Wst[128][136];
  const int tid = threadIdx.x;
  for (int idx = tid; idx < 128 * 128; idx += 256) {
    int k = idx >> 7, jj = idx & 127;
    Wst[k][jj] = W[k * 128 + jj];
  }
  for (int idx = tid; idx < 32 * 128; idx += 256) {
    int r = idx >> 7, d = idx & 127;
    As[r][d] = A[r * 128 + d];
  }
  __syncthreads();
  // 256 threads: each computes 16 outputs (32*128/256)
  int r = tid >> 3, c0 = (tid & 7) * 16;
  float acc[16];
#pragma unroll
  for (int q = 0; q < 16; q++) acc[q] = 0.f;
  for (int k = 0; k < 128; k++) {
    float av = As[r][k];
#pragma unroll
    for (int q = 0; q < 16; q++) acc[q] = fmaf(av, Wst[k][c0 + q], acc[q]);
  }
#pragma unroll
  for (int q = 0; q < 16; q++) C[r * 128 + c0 + q] = acc[q];
}

// ---------------- edge MLP ----------------
__global__ __launch_bounds__(256) void edge_mlp(const float* __restrict__ EA,
                                                const float* __restrict__ We1,
                                                const float* __restrict__ be1,
                                                const float* __restrict__ We2,
                                                const float* __restrict__ be2,
                                                float* __restrict__ a2) {
  __shared__ float sW1[16 * 128];
  __shared__ float sb1[128];
  __shared__ float sW2[128];
  int tid = threadIdx.x;
  for (int i = tid; i < 2048; i += 256) sW1[i] = We1[i];
  if (tid < 128) { sb1[tid] = be1[tid]; sW2[tid] = We2[tid]; }
  __syncthreads();
  int e = blockIdx.x * 256 + tid;
  if (e >= EE) return;
  float ea[16];
#pragma unroll
  for (int q = 0; q < 4; q++) {
    float4 v = *(const float4*)(EA + (size_t)e * 16 + q * 4);
    ea[q * 4 + 0] = v.x; ea[q * 4 + 1] = v.y; ea[q * 4 + 2] = v.z; ea[q * 4 + 3] = v.w;
  }
  float acc = 0.f;
  for (int j = 0; j < 128; j += 4) {
    float4 h = *(const float4*)&sb1[j];
#pragma unroll
    for (int k = 0; k < 16; k++) {
      float4 wv = *(const float4*)&sW1[k * 128 + j];
      h.x = fmaf(ea[k], wv.x, h.x);
      h.y = fmaf(ea[k], wv.y, h.y);
      h.z = fmaf(ea[k], wv.z, h.z);
      h.w = fmaf(ea[k], wv.w, h.w);
    }
    float4 w2 = *(const float4*)&sW2[j];
    acc = fmaf(gelu_tanh(h.x), w2.x, acc);
    acc = fmaf(gelu_tanh(h.y), w2.y, acc);
    acc = fmaf(gelu_tanh(h.z), w2.z, acc);
    acc = fmaf(gelu_tanh(h.w), w2.w, acc);
  }
  a2[e] = acc + be2[0];
}

// ---------------- CSR build ----------------
__global__ __launch_bounds__(256) void hist2(const int* __restrict__ a,
                                             const int* __restrict__ b,
                                             int* __restrict__ ca,
                                             int* __restrict__ cb, int n) {
  int e = blockIdx.x * 256 + threadIdx.x;
  if (e >= n) return;
  atomicAdd(&ca[a[e]], 1);
  atomicAdd(&cb[b[e]], 1);
}

__global__ __launch_bounds__(256) void hist_t3(const int* __restrict__ c,
                                               const int* __restrict__ u,
                                               const int* __restrict__ v,
                                               int* __restrict__ cc,
                                               int* __restrict__ cuv, int n) {
  int t = blockIdx.x * 256 + threadIdx.x;
  if (t >= n) return;
  atomicAdd(&cc[c[t]], 1);
  atomicAdd(&cuv[u[t]], 1);
  atomicAdd(&cuv[v[t]], 1);
}

__global__ __launch_bounds__(256) void scan4(const int* __restrict__ cnt,
                                             int* __restrict__ rowptr,
                                             int* __restrict__ cursor) {
  const int* c = cnt + (size_t)blockIdx.x * NN;
  int* rp = rowptr + (size_t)blockIdx.x * (NN + 1);
  int* cur = cursor + (size_t)blockIdx.x * NN;
  __shared__ int wt[4];
  int tid = threadIdx.x, lane = tid & 63, wid = tid >> 6;
  int base = 0;
  for (int i0 = 0; i0 < NN; i0 += 256) {
    int i = i0 + tid;
    int v = (i < NN) ? c[i] : 0;
    int x = v;
#pragma unroll
    for (int d = 1; d < 64; d <<= 1) {
      int y = __shfl_up(x, d, 64);
      if (lane >= d) x += y;
    }
    __syncthreads();
    if (lane == 63) wt[wid] = x;
    __syncthreads();
    int add = 0;
    for (int w = 0; w < wid; w++) add += wt[w];
    int excl = base + add + x - v;
    if (i < NN) { rp[i] = excl; cur[i] = excl; }
    base += wt[0] + wt[1] + wt[2] + wt[3];
  }
  if (tid == 0) rp[NN] = base;
}

__global__ __launch_bounds__(256) void scat2(const int* __restrict__ c2,
                                             const int* __restrict__ u2,
                                             const float* __restrict__ a2,
                                             int* __restrict__ cuc,
                                             int* __restrict__ cuu,
                                             int* __restrict__ part_c,
                                             float* __restrict__ apay_c,
                                             int* __restrict__ slot_u,
                                             int* __restrict__ part_u, int n) {
  int e = blockIdx.x * 256 + threadIdx.x;
  if (e >= n) return;
  int c = c2[e], u = u2[e];
  int p = atomicAdd(&cuc[c], 1);
  part_c[p] = u; apay_c[p] = a2[e];
  int p2 = atomicAdd(&cuu[u], 1);
  slot_u[p2] = p; part_u[p2] = c;
}

__global__ __launch_bounds__(256) void scat_t3(const int* __restrict__ c3,
                                               const int* __restrict__ u3,
                                               const int* __restrict__ v3,
                                               const int* __restrict__ ttau,
                                               int* __restrict__ cuc,
                                               int* __restrict__ cuv,
                                               int* __restrict__ pu_c,
                                               int* __restrict__ pv_c,
                                               int* __restrict__ ta_c,
                                               int* __restrict__ po,
                                               int* __restrict__ pc,
                                               int* __restrict__ spk, int n) {
  int t = blockIdx.x * 256 + threadIdx.x;
  if (t >= n) return;
  int c = c3[t], u = u3[t], v = v3[t], ta = ttau[t] & 1;
  int p = atomicAdd(&cuc[c], 1);
  pu_c[p] = u; pv_c[p] = v; ta_c[p] = ta;
  int sp = (p << 1) | ta;
  int q1 = atomicAdd(&cuv[u], 1);
  po[q1] = v; pc[q1] = c; spk[q1] = sp;
  int q2 = atomicAdd(&cuv[v], 1);
  po[q2] = u; pc[q2] = c; spk[q2] = sp;
}

// ---------------- fused e2 fwd + dQ2: 4 groups of 16 lanes, prefetched ----------------
__global__ __launch_bounds__(256) void e2_fused(const unsigned* __restrict__ QK,
                                                const float* __restrict__ P,
                                                const int* __restrict__ part,
                                                const float* __restrict__ apay,
                                                const int* __restrict__ rp,
                                                float* __restrict__ s2c,
                                                float* __restrict__ L2,
                                                unsigned* __restrict__ dAll) {
  int row = blockIdx.x * 4 + (threadIdx.x >> 6);
  if (row >= NN) return;
  int l = threadIdx.x & 63, g = l >> 4, j = l & 15;
  float b2s = P[0] * INV_SQRT_D, cw2 = P[3];
  float q[8];
  unp8(*(const uint4*)(QK + (size_t)row * UU + j * 4), q);
  int s = rp[row], e = rp[row + 1];
  float m = -3.0e38f, z = 0.f;
  float acc[8] = {0.f, 0.f, 0.f, 0.f, 0.f, 0.f, 0.f, 0.f};
  int i = s + g;
  bool have = (i < e);
  uint4 kw; float a = 0.f;
  if (have) {
    int u = part[i]; a = apay[i];
    kw = *(const uint4*)(QK + (size_t)u * UU + 64 + j * 4);
  }
  while (have) {
    int i2 = i + 4;
    bool have2 = (i2 < e);
    uint4 kw2; float a2v = 0.f;
    if (have2) {
      int u2 = part[i2]; a2v = apay[i2];
      kw2 = *(const uint4*)(QK + (size_t)u2 * UU + 64 + j * 4);
    }
    float k[8]; unp8(kw, k);
    float d = 0.f;
#pragma unroll
    for (int t = 0; t < 8; t++) d = fmaf(q[t], k[t], d);
    d = redsum16(d);
    float sv = b2s * d + a;
    if (j == 0) s2c[i] = sv;
    if (sv <= m) {
      float p = __expf(sv - m);
      z += p;
#pragma unroll
      for (int t = 0; t < 8; t++) acc[t] = fmaf(p, k[t], acc[t]);
    } else {
      float r = __expf(m - sv);
      z = fmaf(z, r, 1.f);
#pragma unroll
      for (int t = 0; t < 8; t++) acc[t] = fmaf(acc[t], r, k[t]);
      m = sv;
    }
    i = i2; have = have2; kw = kw2; a = a2v;
  }
  float mx = fmaxf(m, __shfl_xor(m, 16, 64));
  mx = fmaxf(mx, __shfl_xor(mx, 32, 64));
  float r = (z > 0.f) ? __expf(m - mx) : 0.f;
  float zz = z * r;
  zz += __shfl_xor(zz, 16, 64);
  zz += __shfl_xor(zz, 32, 64);
#pragma unroll
  for (int t = 0; t < 8; t++) {
    float v = acc[t] * r;
    v += __shfl_xor(v, 16, 64);
    v += __shfl_xor(v, 32, 64);
    acc[t] = v;
  }
  if (l == 0) L2[row] = (zz > 0.f) ? (mx + __logf(zz)) : 0.f;
  if (g == 0) {
    float coef = (zz > 0.f) ? cw2 / zz : 0.f;
    float o[8];
#pragma unroll
    for (int t = 0; t < 8; t++) o[t] = coef * acc[t];
    *(uint4*)(dAll + (size_t)row * UU + 0 + j * 4) = pk8(o);
  }
}

// ---------------- dK2 gather ----------------
__global__ __launch_bounds__(256) void dk2_gather(const unsigned* __restrict__ QK,
                                                  const float* __restrict__ s2c,
                                                  const float* __restrict__ L2,
                                                  const float* __restrict__ P,
                                                  const int* __restrict__ slot,
                                                  const int* __restrict__ part,
                                                  const int* __restrict__ rp,
                                                  unsigned* __restrict__ dAll) {
  int row = blockIdx.x * 4 + (threadIdx.x >> 6);
  if (row >= NN) return;
  int l = threadIdx.x & 63, g = l >> 4, j = l & 15;
  float cw2 = P[3];
  int s = rp[row], e = rp[row + 1];
  float acc[8] = {0.f, 0.f, 0.f, 0.f, 0.f, 0.f, 0.f, 0.f};
  int i = s + g;
  bool have = (i < e);
  uint4 qw; float sc = 0.f, lc = 0.f;
  if (have) {
    int c = part[i]; sc = s2c[slot[i]]; lc = L2[c];
    qw = *(const uint4*)(QK + (size_t)c * UU + 0 + j * 4);
  }
  while (have) {
    int i2 = i + 4;
    bool have2 = (i2 < e);
    uint4 qw2; float sc2 = 0.f, lc2 = 0.f;
    if (have2) {
      int c2_ = part[i2]; sc2 = s2c[slot[i2]]; lc2 = L2[c2_];
      qw2 = *(const uint4*)(QK + (size_t)c2_ * UU + 0 + j * 4);
    }
    float w = cw2 * __expf(sc - lc);
    float qv[8]; unp8(qw, qv);
#pragma unroll
    for (int t = 0; t < 8; t++) acc[t] = fmaf(w, qv[t], acc[t]);
    i = i2; have = have2; qw = qw2; sc = sc2; lc = lc2;
  }
#pragma unroll
  for (int t = 0; t < 8; t++) {
    float v = acc[t];
    v += __shfl_xor(v, 16, 64);
    v += __shfl_xor(v, 32, 64);
    acc[t] = v;
  }
  if (g == 0) *(uint4*)(dAll + (size_t)row * UU + 64 + j * 4) = pk8(acc);
}

// ---------------- fused t3 fwd + dQ3 ----------------
__global__ __launch_bounds__(256) void t3_fused(const unsigned* __restrict__ QK,
                                                const float* __restrict__ Tt,
                                                const float* __restrict__ P,
                                                const int* __restrict__ pu,
                                                const int* __restrict__ pv,
                                                const int* __restrict__ tac,
                                                const int* __restrict__ rp,
                                                float* __restrict__ s3c,
                                                float* __restrict__ L3,
                                                unsigned* __restrict__ dAll) {
  __shared__ float sT[2 * DD];
  int tid = threadIdx.x;
  sT[tid] = Tt[tid];
  __syncthreads();
  int row = blockIdx.x * 4 + (tid >> 6);
  if (row >= NN) return;
  int l = tid & 63, g = l >> 4, j = l & 15;
  float b3s = P[1] * INV_D, cw3 = P[4];
  float q[8];
  unp8(*(const uint4*)(QK + (size_t)row * UU + 128 + j * 4), q);
  int s = rp[row], e = rp[row + 1];
  float m = -3.0e38f, z = 0.f;
  float acc[8] = {0.f, 0.f, 0.f, 0.f, 0.f, 0.f, 0.f, 0.f};
  int i = s + g;
  bool have = (i < e);
  uint4 kuw, kvw; int ta = 0;
  if (have) {
    int u = pu[i], v = pv[i]; ta = tac[i];
    kuw = *(const uint4*)(QK + (size_t)u * UU + 192 + j * 4);
    kvw = *(const uint4*)(QK + (size_t)v * UU + 192 + j * 4);
  }
  while (have) {
    int i2 = i + 4;
    bool have2 = (i2 < e);
    uint4 kuw2, kvw2; int ta2 = 0;
    if (have2) {
      int u2 = pu[i2], v2 = pv[i2]; ta2 = tac[i2];
      kuw2 = *(const uint4*)(QK + (size_t)u2 * UU + 192 + j * 4);
      kvw2 = *(const uint4*)(QK + (size_t)v2 * UU + 192 + j * 4);
    }
    float ku[8], kv[8]; unp8(kuw, ku); unp8(kvw, kv);
    const float* tv = &sT[ta * DD + j * 8];
    float et[8], d = 0.f;
#pragma unroll
    for (int t = 0; t < 8; t++) { et[t] = ku[t] * kv[t] * tv[t]; d = fmaf(q[t], et[t], d); }
    d = redsum16(d);
    float sv = b3s * d;
    if (j == 0) s3c[i] = sv;
    if (sv <= m) {
      float p = __expf(sv - m);
      z += p;
#pragma unroll
      for (int t = 0; t < 8; t++) acc[t] = fmaf(p, et[t], acc[t]);
    } else {
      float r = __expf(m - sv);
      z = fmaf(z, r, 1.f);
#pragma unroll
      for (int t = 0; t < 8; t++) acc[t] = fmaf(acc[t], r, et[t]);
      m = sv;
    }
    i = i2; have = have2; kuw = kuw2; kvw = kvw2; ta = ta2;
  }
  float mx = fmaxf(m, __shfl_xor(m, 16, 64));
  mx = fmaxf(mx, __shfl_xor(mx, 32, 64));
  float r = (z > 0.f) ? __expf(m - mx) : 0.f;
  float zz = z * r;
  zz += __shfl_xor(zz, 16, 64);
  zz += __shfl_xor(zz, 32, 64);
#pragma unroll
  for (int t = 0; t < 8; t++) {
    float v = acc[t] * r;
    v += __shfl_xor(v, 16, 64);
    v += __shfl_xor(v, 32, 64);
    acc[t] = v;
  }
  if (l == 0) L3[row] = (zz > 0.f) ? (mx + __logf(zz)) : 0.f;
  if (g == 0) {
    float coef = (zz > 0.f) ? cw3 / zz : 0.f;
    float o[8];
#pragma unroll
    for (int t = 0; t < 8; t++) o[t] = coef * acc[t];
    *(uint4*)(dAll + (size_t)row * UU + 128 + j * 4) = pk8(o);
  }
}

// ---------------- dK3 gather ----------------
__global__ __launch_bounds__(256) void dk3_gather(const unsigned* __restrict__ QK,
                                                  const float* __restrict__ Tt,
                                                  const float* __restrict__ s3c,
                                                  const float* __restrict__ L3,
                                                  const float* __restrict__ P,
                                                  const int* __restrict__ po,
                                                  const int* __restrict__ pc,
                                                  const int* __restrict__ spk,
                                                  const int* __restrict__ rp,
                                                  unsigned* __restrict__ dAll) {
  __shared__ float sT[2 * DD];
  int tid = threadIdx.x;
  sT[tid] = Tt[tid];
  __syncthreads();
  int row = blockIdx.x * 4 + (tid >> 6);
  if (row >= NN) return;
  int l = tid & 63, g = l >> 4, j = l & 15;
  float cw3 = P[4];
  int s = rp[row], e = rp[row + 1];
  float acc[8] = {0.f, 0.f, 0.f, 0.f, 0.f, 0.f, 0.f, 0.f};
  int i = s + g;
  bool have = (i < e);
  uint4 qw, kw; int ta = 0; float sc = 0.f, lc = 0.f;
  if (have) {
    int o = po[i], c = pc[i], sp = spk[i];
    ta = sp & 1; sc = s3c[sp >> 1]; lc = L3[c];
    qw = *(const uint4*)(QK + (size_t)c * UU + 128 + j * 4);
    kw = *(const uint4*)(QK + (size_t)o * UU + 192 + j * 4);
  }
  while (have) {
    int i2 = i + 4;
    bool have2 = (i2 < e);
    uint4 qw2, kw2; int ta_2 = 0; float sc2 = 0.f, lc2 = 0.f;
    if (have2) {
      int o2 = po[i2], c2_ = pc[i2], sp2 = spk[i2];
      ta_2 = sp2 & 1; sc2 = s3c[sp2 >> 1]; lc2 = L3[c2_];
      qw2 = *(const uint4*)(QK + (size_t)c2_ * UU + 128 + j * 4);
      kw2 = *(const uint4*)(QK + (size_t)o2 * UU + 192 + j * 4);
    }
    float w = cw3 * __expf(sc - lc);
    float qv[8], ko[8]; unp8(qw, qv); unp8(kw, ko);
    const float* tv = &sT[ta * DD + j * 8];
#pragma unroll
    for (int t = 0; t < 8; t++) acc[t] = fmaf(w * tv[t], qv[t] * ko[t], acc[t]);
    i = i2; have = have2; qw = qw2; kw = kw2; ta = ta_2; sc = sc2; lc = lc2;
  }
#pragma unroll
  for (int t = 0; t < 8; t++) {
    float v = acc[t];
    v += __shfl_xor(v, 16, 64);
    v += __shfl_xor(v, 32, 64);
    acc[t] = v;
  }
  if (g == 0) *(uint4*)(dAll + (size_t)row * UU + 192 + j * 4) = pk8(acc);
}

// ---------------- memory-bank energy ----------------
__global__ __launch_bounds__(256) void em_row(const unsigned* __restrict__ QK,
                                              const float* __restrict__ Km,
                                              const float* __restrict__ P,
                                              unsigned* __restrict__ dAll,
                                              float* __restrict__ Lm) {
  __shared__ float sKm[KM * DD];
  int tid = threadIdx.x;
  for (int i = tid; i < KM * DD; i += 256) sKm[i] = Km[i];
  __syncthreads();
  int row = blockIdx.x * 4 + (tid >> 6);
  if (row >= NN) return;
  int l = tid & 63, g = l >> 4, j = l & 15;
  float bms = P[2] * INV_SQRT_D, cwm = P[5];
  float q[8];
  unp8(*(const uint4*)(QK + (size_t)row * UU + 256 + j * 4), q);
  float dk[8];
#pragma unroll
  for (int kk = 0; kk < 8; kk++) {
    int k = g * 8 + kk;
    const float* kr = &sKm[k * DD + j * 8];
    float d = 0.f;
#pragma unroll
    for (int t = 0; t < 8; t++) d = fmaf(q[t], kr[t], d);
    dk[kk] = redsum16(d) * bms;
  }
  float m = dk[0];
#pragma unroll
  for (int kk = 1; kk < 8; kk++) m = fmaxf(m, dk[kk]);
  float mx = fmaxf(m, __shfl_xor(m, 16, 64));
  mx = fmaxf(mx, __shfl_xor(mx, 32, 64));
  float p[8], z = 0.f;
#pragma unroll
  for (int kk = 0; kk < 8; kk++) { p[kk] = __expf(dk[kk] - mx); z += p[kk]; }
  float zz = z;
  zz += __shfl_xor(zz, 16, 64);
  zz += __shfl_xor(zz, 32, 64);
  if (l == 0) Lm[row] = mx + __logf(zz);
  float coef = cwm / zz;
  float acc[8] = {0.f, 0.f, 0.f, 0.f, 0.f, 0.f, 0.f, 0.f};
#pragma unroll
  for (int kk = 0; kk < 8; kk++) {
    int k = g * 8 + kk;
    const float* kr = &sKm[k * DD + j * 8];
    float pc_ = p[kk] * coef;
#pragma unroll
    for (int t = 0; t < 8; t++) acc[t] = fmaf(pc_, kr[t], acc[t]);
  }
#pragma unroll
  for (int t = 0; t < 8; t++) {
    float v = acc[t];
    v += __shfl_xor(v, 16, 64);
    v += __shfl_xor(v, 32, 64);
    acc[t] = v;
  }
  if (g == 0) *(uint4*)(dAll + (size_t)row * UU + 256 + j * 4) = pk8(acc);
}

// ---------------- LN backward + clips + update ----------------
__global__ __launch_bounds__(256) void ln_bwd(const float* __restrict__ X,
                                              const unsigned* __restrict__ dG,
                                              const float* __restrict__ gamma,
                                              const float* __restrict__ meanv,
                                              const float* __restrict__ rstdv,
                                              float* __restrict__ out) {
  int row = blockIdx.x * 4 + (threadIdx.x >> 6);
  if (row >= NN) return;
  int l = threadIdx.x & 63;
  float mu = meanv[row], rstd = rstdv[row];
  float2 x2 = *(const float2*)(X + row * DD + 2 * l);
  unsigned gw = dG[(size_t)row * 64 + l];
  float2 ga = *(const float2*)(gamma + 2 * l);
  float xh0 = (x2.x - mu) * rstd, xh1 = (x2.y - mu) * rstd;
  float dh0 = blo(gw) * ga.x, dh1 = bhi(gw) * ga.y;
  float sa = wredsum(dh0 + dh1) * (1.f / DD);
  float sb = wredsum(dh0 * xh0 + dh1 * xh1) * (1.f / DD);
  float dx0 = rstd * (dh0 - sa - xh0 * sb);
  float dx1 = rstd * (dh1 - sa - xh1 * sb);
  float gn = fmaxf(sqrtf(wredsum(dx0 * dx0 + dx1 * dx1)), 1e-6f);
  float sc = fminf(1.f / gn, 1.f);
  dx0 *= sc; dx1 *= sc;
  float xn0 = x2.x - 0.1f * 0.9999f * dx0;
  float xn1 = x2.y - 0.1f * 0.9999f * dx1;
  float sn = fmaxf(sqrtf(wredsum(xn0 * xn0 + xn1 * xn1)), 1e-6f);
  float sc2 = fminf(10.f / sn, 1.f);
  float2 o; o.x = xn0 * sc2; o.y = xn1 * sc2;
  *(float2*)(out + row * DD + 2 * l) = o;
}

// ---------------- final energy scalar ----------------
__global__ __launch_bounds__(256) void eval_write(const float* __restrict__ L2,
                                                  const float* __restrict__ L3,
                                                  const float* __restrict__ Lm,
                                                  const float* __restrict__ P,
                                                  float* __restrict__ out) {
  int tid = threadIdx.x;
  float a2 = 0.f, a3 = 0.f, am = 0.f;
  for (int i = tid; i < NN; i += 256) { a2 += L2[i]; a3 += L3[i]; am += Lm[i]; }
  a2 = wredsum(a2); a3 = wredsum(a3); am = wredsum(am);
  __shared__ float r2[4], r3[4], rm[4];
  int wv = tid >> 6, l = tid & 63;
  if (l == 0) { r2[wv] = a2; r3[wv] = a3; rm[wv] = am; }
  __syncthreads();
  if (tid == 0) {
    float S2 = r2[0] + r2[1] + r2[2] + r2[3];
    float S3 = r3[0] + r3[1] + r3[2] + r3[3];
    float Sm = rm[0] + rm[1] + rm[2] + rm[3];
    out[0] = P[6] * S2 + P[7] * S3 + P[8] * Sm;
  }
}

extern "C" void kernel_launch(void* const* d_in, const int* in_sizes, int n_in,
                              void* d_out, int out_size, void* d_ws, size_t ws_size,
                              hipStream_t stream) {
  (void)in_sizes; (void)n_in; (void)out_size;
  const float* X = (const float*)d_in[0];
  const float* EA = (const float*)d_in[1];
  const float* ln_g = (const float*)d_in[2];
  const float* ln_b = (const float*)d_in[3];
  const float* W_Q2 = (const float*)d_in[4];
  const float* W_K2 = (const float*)d_in[5];
  const float* W_Q3 = (const float*)d_in[6];
  const float* W_K3 = (const float*)d_in[7];
  const float* T_tau = (const float*)d_in[8];
  const float* W_Qm = (const float*)d_in[9];
  const float* W_Km = (const float*)d_in[10];
  const float* B_mem = (const float*)d_in[11];
  const float* We1 = (const float*)d_in[12];
  const float* be1 = (const float*)d_in[13];
  const float* We2 = (const float*)d_in[14];
  const float* be2 = (const float*)d_in[15];
  const float* l2s = (const float*)d_in[16];
  const float* l3s = (const float*)d_in[17];
  const float* lms = (const float*)d_in[18];
  const float* b2s = (const float*)d_in[19];
  const float* b3s = (const float*)d_in[20];
  const float* bms = (const float*)d_in[21];
  const int* c2 = (const int*)d_in[22];
  const int* u2 = (const int*)d_in[23];
  const int* c3 = (const int*)d_in[24];
  const int* u3 = (const int*)d_in[25];
  const int* v3 = (const int*)d_in[26];
  const int* ttau = (const int*)d_in[27];
  float* out = (float*)d_out;

  float* ws = (float*)d_ws;
  size_t off = 0;
  auto alloc = [&](size_t n) { float* p = ws + off; off += n; return p; };
  const size_t ND = (size_t)NN * DD;
  unsigned* Gb = (unsigned*)alloc(ND / 2);           // bf16 G [N,128]
  unsigned* QKall = (unsigned*)alloc((size_t)NN * UU); // bf16 [N,640]
  unsigned* dAll = (unsigned*)alloc((size_t)NN * UU);  // bf16 [N,640]
  unsigned* dG = (unsigned*)alloc(ND / 2);           // bf16 [N,128]
  ushort_t* Wt5 = (ushort_t*)alloc(640 * 128 / 2);
  ushort_t* Wcat = (ushort_t*)alloc(640 * 128 / 2);
  float* Km = alloc((size_t)KM * DD);
  float* a2 = alloc(EE);
  float* s2c = alloc(EE);
  float* s3c = alloc(TT);
  float* meanv = alloc(NN);
  float* rstdv = alloc(NN);
  float* L2 = alloc(NN);
  float* L3 = alloc(NN);
  float* Lm = alloc(NN);
  float* Pparams = alloc(16);
  int* cnt = (int*)alloc(4 * (size_t)NN);
  int* rowptr = (int*)alloc(4 * (size_t)(NN + 1));
  int* cursor = (int*)alloc(4 * (size_t)NN);
  int* part_c2 = (int*)alloc(EE);
  float* apay_c2 = alloc(EE);
  int* slot_u2 = (int*)alloc(EE);
  int* part_u2 = (int*)alloc(EE);
  int* pu_c3 = (int*)alloc(TT);
  int* pv_c3 = (int*)alloc(TT);
  int* ta_c3 = (int*)alloc(TT);
  int* po_uv = (int*)alloc(2 * (size_t)TT);
  int* pc_uv = (int*)alloc(2 * (size_t)TT);
  int* spk_uv = (int*)alloc(2 * (size_t)TT);
  if (off * sizeof(float) > ws_size) return;

  int* cnt_c2 = cnt, *cnt_u2 = cnt + NN, *cnt_c3 = cnt + 2 * NN, *cnt_uv = cnt + 3 * NN;
  int* rp_c2 = rowptr, *rp_u2 = rowptr + (NN + 1), *rp_c3 = rowptr + 2 * (NN + 1), *rp_uv = rowptr + 3 * (NN + 1);
  int* cu_c2 = cursor, *cu_u2 = cursor + NN, *cu_c3 = cursor + 2 * NN, *cu_uv = cursor + 3 * NN;

  hipMemsetAsync(cnt, 0, 4ull * NN * sizeof(int), stream);

  params_k<<<1, 64, 0, stream>>>(l2s, l3s, lms, b2s, b3s, bms, Pparams);

  int rowB = (NN + 3) / 4;
  int mB = (NN + 63) / 64;

  ln_fwd<<<rowB, 256, 0, stream>>>(X, ln_g, ln_b, Gb, meanv, rstdv);
  w_conv<<<320, 256, 0, stream>>>(W_Q2, W_K2, W_Q3, W_K3, W_Qm, Wt5, Wcat);
  mfma_fwd<<<dim3(mB, 10), 256, 0, stream>>>((const ushort_t*)Gb, Wt5, (ushort_t*)QKall, NN);
  gemm_km<<<1, 256, 0, stream>>>(B_mem, W_Km, Km, KM);
  edge_mlp<<<(EE + 255) / 256, 256, 0, stream>>>(EA, We1, be1, We2, be2, a2);

  hist2<<<(EE + 255) / 256, 256, 0, stream>>>(c2, u2, cnt_c2, cnt_u2, EE);
  hist_t3<<<(TT + 255) / 256, 256, 0, stream>>>(c3, u3, v3, cnt_c3, cnt_uv, TT);
  scan4<<<4, 256, 0, stream>>>(cnt, rowptr, cursor);
  scat2<<<(EE + 255) / 256, 256, 0, stream>>>(c2, u2, a2, cu_c2, cu_u2,
                                              part_c2, apay_c2, slot_u2, part_u2, EE);
  scat_t3<<<(TT + 255) / 256, 256, 0, stream>>>(c3, u3, v3, ttau, cu_c3, cu_uv,
                                                pu_c3, pv_c3, ta_c3,
                                                po_uv, pc_uv, spk_uv, TT);

  e2_fused<<<rowB, 256, 0, stream>>>(QKall, Pparams, part_c2, apay_c2, rp_c2, s2c, L2, dAll);
  dk2_gather<<<rowB, 256, 0, stream>>>(QKall, s2c, L2, Pparams, slot_u2, part_u2, rp_u2, dAll);
  t3_fused<<<rowB, 256, 0, stream>>>(QKall, T_tau, Pparams, pu_c3, pv_c3, ta_c3, rp_c3, s3c, L3, dAll);
  dk3_gather<<<rowB, 256, 0, stream>>>(QKall, T_tau, s3c, L3, Pparams, po_uv, pc_uv, spk_uv, rp_uv, dAll);
  em_row<<<rowB, 256, 0, stream>>>(QKall, Km, Pparams, dAll, Lm);

  mfma_bwd<<<dim3(mB, 2), 256, 0, stream>>>((const ushort_t*)dAll, Wcat, dG, NN);

  ln_bwd<<<rowB, 256, 0, stream>>>(X, dG, ln_g, meanv, rstdv, out);
  eval_write<<<1, 256, 0, stream>>>(L2, L3, Lm, Pparams, out + ND);
}

// Round 5
// 947.781 us; speedup vs baseline: 4.3019x; 1.1749x over previous
//
#include <hip/hip_runtime.h>

#define NN 50000
#define DD 128
#define EE 800000
#define TT 400000
#define KM 32
#define UU 320  // uints per 640-col bf16 row
#define SCAN_TILE 2048
#define SCAN_NB ((NN + SCAN_TILE - 1) / SCAN_TILE)  // 25

static constexpr float INV_SQRT_D = 0.08838834764831845f; // 1/sqrt(128)
static constexpr float INV_D = 1.f / 128.f;

typedef __attribute__((ext_vector_type(8))) short bf16x8;
typedef __attribute__((ext_vector_type(4))) float f32x4;
typedef unsigned short ushort_t;

__device__ __forceinline__ float softplus_f(float x) {
  return (x > 20.f) ? x : log1pf(__expf(x));
}

__device__ __forceinline__ float gelu_tanh(float x) {
  float x3 = x * x * x;
  float u = 0.7978845608028654f * (x + 0.044715f * x3);
  u = fminf(fmaxf(u, -15.f), 15.f);
  float e = __expf(2.f * u);
  float t = (e - 1.f) / (e + 1.f);
  return 0.5f * x * (1.f + t);
}

__device__ __forceinline__ float wredsum(float v) {
#pragma unroll
  for (int m = 32; m; m >>= 1) v += __shfl_xor(v, m, 64);
  return v;
}

__device__ __forceinline__ float redsum16(float v) {
#pragma unroll
  for (int m = 1; m < 16; m <<= 1) v += __shfl_xor(v, m, 64);
  return v;
}

__device__ __forceinline__ float blo(unsigned w) { return __uint_as_float(w << 16); }
__device__ __forceinline__ float bhi(unsigned w) { return __uint_as_float(w & 0xffff0000u); }
__device__ __forceinline__ unsigned pack_bf16(float a, float b) {
  unsigned ua = __float_as_uint(a); ua += 0x7fff + ((ua >> 16) & 1);
  unsigned ub = __float_as_uint(b); ub += 0x7fff + ((ub >> 16) & 1);
  return (ua >> 16) | (ub & 0xffff0000u);
}
__device__ __forceinline__ ushort_t bf16_1(float x) {
  unsigned u = __float_as_uint(x); u += 0x7fff + ((u >> 16) & 1);
  return (ushort_t)(u >> 16);
}
__device__ __forceinline__ void unp8(uint4 w, float* f) {
  f[0] = blo(w.x); f[1] = bhi(w.x); f[2] = blo(w.y); f[3] = bhi(w.y);
  f[4] = blo(w.z); f[5] = bhi(w.z); f[6] = blo(w.w); f[7] = bhi(w.w);
}
__device__ __forceinline__ uint4 pk8(const float* f) {
  uint4 r;
  r.x = pack_bf16(f[0], f[1]); r.y = pack_bf16(f[2], f[3]);
  r.z = pack_bf16(f[4], f[5]); r.w = pack_bf16(f[6], f[7]);
  return r;
}

// params: [0]=b2 [1]=b3 [2]=bm [3]=cw2 [4]=cw3 [5]=cwm [6]=-sp2/b2 [7]=-sp3/b3 [8]=-spm/bm
__global__ void params_k(const float* l2, const float* l3, const float* lm,
                         const float* b2, const float* b3, const float* bm,
                         float* __restrict__ P) {
  if (threadIdx.x != 0) return;
  float B2 = fminf(softplus_f(b2[0]), 5.f);
  float B3 = fminf(softplus_f(b3[0]), 5.f);
  float Bm = fminf(softplus_f(bm[0]), 5.f);
  float S2 = softplus_f(l2[0]);
  float S3 = softplus_f(l3[0]);
  float Sm = softplus_f(lm[0]);
  P[0] = B2; P[1] = B3; P[2] = Bm;
  P[3] = -S2 * INV_SQRT_D; P[4] = -S3 * INV_D; P[5] = -Sm * INV_SQRT_D;
  P[6] = -S2 / B2; P[7] = -S3 / B3; P[8] = -Sm / Bm;
}

// ---------------- LayerNorm forward -> bf16 G ----------------
__global__ __launch_bounds__(256) void ln_fwd(const float* __restrict__ X,
                                              const float* __restrict__ gamma,
                                              const float* __restrict__ beta,
                                              unsigned* __restrict__ Gb,
                                              float* __restrict__ meanv,
                                              float* __restrict__ rstdv) {
  int row = blockIdx.x * 4 + (threadIdx.x >> 6);
  if (row >= NN) return;
  int l = threadIdx.x & 63;
  float2 x2 = *(const float2*)(X + row * DD + 2 * l);
  float mu = wredsum(x2.x + x2.y) * (1.f / DD);
  float d0 = x2.x - mu, d1 = x2.y - mu;
  float var = wredsum(d0 * d0 + d1 * d1) * (1.f / DD);
  float rstd = rsqrtf(var + 1e-5f);
  float2 g2 = *(const float2*)(gamma + 2 * l);
  float2 b2 = *(const float2*)(beta + 2 * l);
  float o0 = d0 * rstd * g2.x + b2.x;
  float o1 = d1 * rstd * g2.y + b2.y;
  Gb[(size_t)row * 64 + l] = pack_bf16(o0, o1);
  if (l == 0) { meanv[row] = mu; rstdv[row] = rstd; }
}

// ---------------- weight conversion ----------------
__global__ __launch_bounds__(256) void w_conv(const float* W0, const float* W1, const float* W2,
                                              const float* W3, const float* W4,
                                              ushort_t* __restrict__ Wt,
                                              ushort_t* __restrict__ Wc) {
  int idx = blockIdx.x * 256 + threadIdx.x;
  if (idx >= 640 * 128) return;
  const float* Ws[5] = {W0, W1, W2, W3, W4};
  int n = idx >> 7, k = idx & 127;
  Wt[idx] = bf16_1(Ws[n >> 7][(size_t)k * 128 + (n & 127)]);
  int k2 = idx >> 7, n2 = idx & 127;
  Wc[(size_t)n2 * 640 + k2] = bf16_1(Ws[k2 >> 7][(size_t)n2 * 128 + (k2 & 127)]);
}

// ---------------- fwd MFMA GEMM: QK[M,640](bf16) = Gb[M,128](bf16) @ Wt^T ----------------
__global__ __launch_bounds__(256) void mfma_fwd(const ushort_t* __restrict__ Gb,
                                                const ushort_t* __restrict__ Wt,
                                                ushort_t* __restrict__ QK, int M) {
  __shared__ ushort_t sB[64][136];
  int tid = threadIdx.x;
  int nb = blockIdx.y * 64;
  for (int idx = tid; idx < 64 * 16; idx += 256) {
    int r = idx >> 4, c8 = idx & 15;
    *(bf16x8*)&sB[r][c8 * 8] = *(const bf16x8*)(Wt + (size_t)(nb + r) * 128 + c8 * 8);
  }
  __syncthreads();
  int w = tid >> 6, l = tid & 63, quad = l >> 4, j = l & 15;
  int row0 = blockIdx.x * 64 + w * 16;
  int arow = row0 + j; if (arow >= M) arow = M - 1;
  const bf16x8* ap = (const bf16x8*)(Gb + (size_t)arow * 128);
  f32x4 acc[4];
#pragma unroll
  for (int nt = 0; nt < 4; nt++) acc[nt] = (f32x4){0.f, 0.f, 0.f, 0.f};
#pragma unroll
  for (int kc = 0; kc < 4; kc++) {
    bf16x8 a = ap[kc * 4 + quad];
#pragma unroll
    for (int nt = 0; nt < 4; nt++) {
      bf16x8 b = *(const bf16x8*)&sB[nt * 16 + j][kc * 32 + quad * 8];
      acc[nt] = __builtin_amdgcn_mfma_f32_16x16x32_bf16(a, b, acc[nt], 0, 0, 0);
    }
  }
#pragma unroll
  for (int nt = 0; nt < 4; nt++)
#pragma unroll
    for (int r = 0; r < 4; r++) {
      int row = row0 + quad * 4 + r;
      if (row < M) QK[(size_t)row * 640 + nb + nt * 16 + j] = bf16_1(acc[nt][r]);
    }
}

// ---------------- bwd MFMA GEMM: dG[M,128](bf16) = dAll[M,640](bf16) @ Wc^T ----------------
__global__ __launch_bounds__(256) void mfma_bwd(const ushort_t* __restrict__ dAll,
                                                const ushort_t* __restrict__ Wc,
                                                unsigned* __restrict__ dG, int M) {
  __shared__ ushort_t sB[64][40];
  int tid = threadIdx.x;
  int nb = blockIdx.y * 64;
  int w = tid >> 6, l = tid & 63, quad = l >> 4, j = l & 15;
  int row0 = blockIdx.x * 64 + w * 16;
  int arow = row0 + j; if (arow >= M) arow = M - 1;
  const ushort_t* arp = dAll + (size_t)arow * 640;
  f32x4 acc[4];
#pragma unroll
  for (int nt = 0; nt < 4; nt++) acc[nt] = (f32x4){0.f, 0.f, 0.f, 0.f};
  int sr = tid >> 2, sc = tid & 3;
  for (int kc = 0; kc < 20; kc++) {
    __syncthreads();
    *(bf16x8*)&sB[sr][sc * 8] = *(const bf16x8*)(Wc + (size_t)(nb + sr) * 640 + kc * 32 + sc * 8);
    __syncthreads();
    bf16x8 a = *(const bf16x8*)(arp + kc * 32 + quad * 8);
#pragma unroll
    for (int nt = 0; nt < 4; nt++) {
      bf16x8 b = *(const bf16x8*)&sB[nt * 16 + j][quad * 8];
      acc[nt] = __builtin_amdgcn_mfma_f32_16x16x32_bf16(a, b, acc[nt], 0, 0, 0);
    }
  }
#pragma unroll
  for (int nt = 0; nt < 4; nt++)
#pragma unroll
    for (int r = 0; r < 4; r++) {
      int row = row0 + quad * 4 + r;
      if (row < M) ((ushort_t*)dG)[(size_t)row * 128 + nb + nt * 16 + j] = bf16_1(acc[nt][r]);
    }
}

// ---------------- small fp32 GEMM for Km = B_mem @ W_Km ----------------
__global__ __launch_bounds__(256, 1) void gemm_km(const float* __restrict__ A,
                                                  const float* __restrict__ W,
                                                  float* __restrict__ C, int M) {
  __shared__ float As[32][132];
  __shared__ float Wst[128][136];
  const int tid = threadIdx.x;
  for (int idx = tid; idx < 128 * 128; idx += 256) {
    int k = idx >> 7, jj = idx & 127;
    Wst[k][jj] = W[k * 128 + jj];
  }
  for (int idx = tid; idx < 32 * 128; idx += 256) {
    int r = idx >> 7, d = idx & 127;
    As[r][d] = A[r * 128 + d];
  }
  __syncthreads();
  int r = tid >> 3, c0 = (tid & 7) * 16;
  float acc[16];
#pragma unroll
  for (int q = 0; q < 16; q++) acc[q] = 0.f;
  for (int k = 0; k < 128; k++) {
    float av = As[r][k];
#pragma unroll
    for (int q = 0; q < 16; q++) acc[q] = fmaf(av, Wst[k][c0 + q], acc[q]);
  }
#pragma unroll
  for (int q = 0; q < 16; q++) C[r * 128 + c0 + q] = acc[q];
}

// ---------------- edge MLP ----------------
__global__ __launch_bounds__(256) void edge_mlp(const float* __restrict__ EA,
                                                const float* __restrict__ We1,
                                                const float* __restrict__ be1,
                                                const float* __restrict__ We2,
                                                const float* __restrict__ be2,
                                                float* __restrict__ a2) {
  __shared__ float sW1[16 * 128];
  __shared__ float sb1[128];
  __shared__ float sW2[128];
  int tid = threadIdx.x;
  for (int i = tid; i < 2048; i += 256) sW1[i] = We1[i];
  if (tid < 128) { sb1[tid] = be1[tid]; sW2[tid] = We2[tid]; }
  __syncthreads();
  int e = blockIdx.x * 256 + tid;
  if (e >= EE) return;
  float ea[16];
#pragma unroll
  for (int q = 0; q < 4; q++) {
    float4 v = *(const float4*)(EA + (size_t)e * 16 + q * 4);
    ea[q * 4 + 0] = v.x; ea[q * 4 + 1] = v.y; ea[q * 4 + 2] = v.z; ea[q * 4 + 3] = v.w;
  }
  float acc = 0.f;
  for (int j = 0; j < 128; j += 4) {
    float4 h = *(const float4*)&sb1[j];
#pragma unroll
    for (int k = 0; k < 16; k++) {
      float4 wv = *(const float4*)&sW1[k * 128 + j];
      h.x = fmaf(ea[k], wv.x, h.x);
      h.y = fmaf(ea[k], wv.y, h.y);
      h.z = fmaf(ea[k], wv.z, h.z);
      h.w = fmaf(ea[k], wv.w, h.w);
    }
    float4 w2 = *(const float4*)&sW2[j];
    acc = fmaf(gelu_tanh(h.x), w2.x, acc);
    acc = fmaf(gelu_tanh(h.y), w2.y, acc);
    acc = fmaf(gelu_tanh(h.z), w2.z, acc);
    acc = fmaf(gelu_tanh(h.w), w2.w, acc);
  }
  a2[e] = acc + be2[0];
}

// ---------------- CSR build ----------------
__global__ __launch_bounds__(256) void hist2(const int* __restrict__ a,
                                             const int* __restrict__ b,
                                             int* __restrict__ ca,
                                             int* __restrict__ cb, int n) {
  int e = blockIdx.x * 256 + threadIdx.x;
  if (e >= n) return;
  atomicAdd(&ca[a[e]], 1);
  atomicAdd(&cb[b[e]], 1);
}

__global__ __launch_bounds__(256) void hist_t3(const int* __restrict__ c,
                                               const int* __restrict__ u,
                                               const int* __restrict__ v,
                                               int* __restrict__ cc,
                                               int* __restrict__ cuv, int n) {
  int t = blockIdx.x * 256 + threadIdx.x;
  if (t >= n) return;
  atomicAdd(&cc[c[t]], 1);
  atomicAdd(&cuv[u[t]], 1);
  atomicAdd(&cuv[v[t]], 1);
}

// ---------------- parallel 3-phase scan over 4 count arrays ----------------
__global__ __launch_bounds__(256) void scan_p1(const int* __restrict__ cnt,
                                               int* __restrict__ part) {
  int arr = blockIdx.y, b = blockIdx.x;
  const int* c = cnt + (size_t)arr * NN;
  int gi = b * SCAN_TILE + threadIdx.x * 8;
  int s = 0;
#pragma unroll
  for (int t = 0; t < 8; t++) s += (gi + t < NN) ? c[gi + t] : 0;
#pragma unroll
  for (int m = 32; m; m >>= 1) s += __shfl_xor(s, m, 64);
  __shared__ int wt[4];
  int lane = threadIdx.x & 63, wid = threadIdx.x >> 6;
  if (lane == 0) wt[wid] = s;
  __syncthreads();
  if (threadIdx.x == 0) part[arr * SCAN_NB + b] = wt[0] + wt[1] + wt[2] + wt[3];
}

__global__ __launch_bounds__(256) void scan_p2(int* __restrict__ part) {
  int w = threadIdx.x >> 6, l = threadIdx.x & 63;
  int v = (l < SCAN_NB) ? part[w * SCAN_NB + l] : 0;
  int x = v;
#pragma unroll
  for (int d = 1; d < 64; d <<= 1) {
    int y = __shfl_up(x, d, 64);
    if (l >= d) x += y;
  }
  if (l < SCAN_NB) part[w * SCAN_NB + l] = x - v;
}

__global__ __launch_bounds__(256) void scan_p3(const int* __restrict__ cnt,
                                               const int* __restrict__ part,
                                               int* __restrict__ rowptr,
                                               int* __restrict__ cursor) {
  int arr = blockIdx.y, b = blockIdx.x;
  const int* c = cnt + (size_t)arr * NN;
  int* rp = rowptr + (size_t)arr * (NN + 1);
  int* cur = cursor + (size_t)arr * NN;
  int tid = threadIdx.x;
  int gi = b * SCAN_TILE + tid * 8;
  int vals[8];
#pragma unroll
  for (int t = 0; t < 8; t++) vals[t] = (gi + t < NN) ? c[gi + t] : 0;
  int tsum = 0;
#pragma unroll
  for (int t = 0; t < 8; t++) tsum += vals[t];
  int lane = tid & 63, wid = tid >> 6;
  int x = tsum;
#pragma unroll
  for (int d = 1; d < 64; d <<= 1) {
    int y = __shfl_up(x, d, 64);
    if (lane >= d) x += y;
  }
  __shared__ int wt[4];
  if (lane == 63) wt[wid] = x;
  __syncthreads();
  int wadd = 0;
  for (int w = 0; w < wid; w++) wadd += wt[w];
  int running = part[arr * SCAN_NB + b] + wadd + x - tsum;
#pragma unroll
  for (int t = 0; t < 8; t++) {
    if (gi + t < NN) { rp[gi + t] = running; cur[gi + t] = running; }
    running += vals[t];
  }
  if (b == SCAN_NB - 1 && tid == 255) rp[NN] = running;
}

__global__ __launch_bounds__(256) void scat2(const int* __restrict__ c2,
                                             const int* __restrict__ u2,
                                             const float* __restrict__ a2,
                                             int* __restrict__ cuc,
                                             int* __restrict__ cuu,
                                             int* __restrict__ part_c,
                                             float* __restrict__ apay_c,
                                             int* __restrict__ slot_u,
                                             int* __restrict__ part_u, int n) {
  int e = blockIdx.x * 256 + threadIdx.x;
  if (e >= n) return;
  int c = c2[e], u = u2[e];
  int p = atomicAdd(&cuc[c], 1);
  part_c[p] = u; apay_c[p] = a2[e];
  int p2 = atomicAdd(&cuu[u], 1);
  slot_u[p2] = p; part_u[p2] = c;
}

__global__ __launch_bounds__(256) void scat_t3(const int* __restrict__ c3,
                                               const int* __restrict__ u3,
                                               const int* __restrict__ v3,
                                               const int* __restrict__ ttau,
                                               int* __restrict__ cuc,
                                               int* __restrict__ cuv,
                                               int* __restrict__ pu_c,
                                               int* __restrict__ pv_c,
                                               int* __restrict__ ta_c,
                                               int* __restrict__ po,
                                               int* __restrict__ pc,
                                               int* __restrict__ spk, int n) {
  int t = blockIdx.x * 256 + threadIdx.x;
  if (t >= n) return;
  int c = c3[t], u = u3[t], v = v3[t], ta = ttau[t] & 1;
  int p = atomicAdd(&cuc[c], 1);
  pu_c[p] = u; pv_c[p] = v; ta_c[p] = ta;
  int sp = (p << 1) | ta;
  int q1 = atomicAdd(&cuv[u], 1);
  po[q1] = v; pc[q1] = c; spk[q1] = sp;
  int q2 = atomicAdd(&cuv[v], 1);
  po[q2] = u; pc[q2] = c; spk[q2] = sp;
}

// ---------------- fused e2 fwd + dQ2 ----------------
__global__ __launch_bounds__(256) void e2_fused(const unsigned* __restrict__ QK,
                                                const float* __restrict__ P,
                                                const int* __restrict__ part,
                                                const float* __restrict__ apay,
                                                const int* __restrict__ rp,
                                                float* __restrict__ s2c,
                                                float* __restrict__ L2,
                                                unsigned* __restrict__ dAll) {
  int row = blockIdx.x * 4 + (threadIdx.x >> 6);
  if (row >= NN) return;
  int l = threadIdx.x & 63, g = l >> 4, j = l & 15;
  float b2s = P[0] * INV_SQRT_D, cw2 = P[3];
  float q[8];
  unp8(*(const uint4*)(QK + (size_t)row * UU + j * 4), q);
  int s = rp[row], e = rp[row + 1];
  float m = -3.0e38f, z = 0.f;
  float acc[8] = {0.f, 0.f, 0.f, 0.f, 0.f, 0.f, 0.f, 0.f};
  int i = s + g;
  bool have = (i < e);
  uint4 kw; float a = 0.f;
  if (have) {
    int u = part[i]; a = apay[i];
    kw = *(const uint4*)(QK + (size_t)u * UU + 64 + j * 4);
  }
  while (have) {
    int i2 = i + 4;
    bool have2 = (i2 < e);
    uint4 kw2; float a2v = 0.f;
    if (have2) {
      int u2 = part[i2]; a2v = apay[i2];
      kw2 = *(const uint4*)(QK + (size_t)u2 * UU + 64 + j * 4);
    }
    float k[8]; unp8(kw, k);
    float d = 0.f;
#pragma unroll
    for (int t = 0; t < 8; t++) d = fmaf(q[t], k[t], d);
    d = redsum16(d);
    float sv = b2s * d + a;
    if (j == 0) s2c[i] = sv;
    if (sv <= m) {
      float p = __expf(sv - m);
      z += p;
#pragma unroll
      for (int t = 0; t < 8; t++) acc[t] = fmaf(p, k[t], acc[t]);
    } else {
      float r = __expf(m - sv);
      z = fmaf(z, r, 1.f);
#pragma unroll
      for (int t = 0; t < 8; t++) acc[t] = fmaf(acc[t], r, k[t]);
      m = sv;
    }
    i = i2; have = have2; kw = kw2; a = a2v;
  }
  float mx = fmaxf(m, __shfl_xor(m, 16, 64));
  mx = fmaxf(mx, __shfl_xor(mx, 32, 64));
  float r = (z > 0.f) ? __expf(m - mx) : 0.f;
  float zz = z * r;
  zz += __shfl_xor(zz, 16, 64);
  zz += __shfl_xor(zz, 32, 64);
#pragma unroll
  for (int t = 0; t < 8; t++) {
    float v = acc[t] * r;
    v += __shfl_xor(v, 16, 64);
    v += __shfl_xor(v, 32, 64);
    acc[t] = v;
  }
  if (l == 0) L2[row] = (zz > 0.f) ? (mx + __logf(zz)) : 0.f;
  if (g == 0) {
    float coef = (zz > 0.f) ? cw2 / zz : 0.f;
    float o[8];
#pragma unroll
    for (int t = 0; t < 8; t++) o[t] = coef * acc[t];
    *(uint4*)(dAll + (size_t)row * UU + 0 + j * 4) = pk8(o);
  }
}

// ---------------- dK2 gather ----------------
__global__ __launch_bounds__(256) void dk2_gather(const unsigned* __restrict__ QK,
                                                  const float* __restrict__ s2c,
                                                  const float* __restrict__ L2,
                                                  const float* __restrict__ P,
                                                  const int* __restrict__ slot,
                                                  const int* __restrict__ part,
                                                  const int* __restrict__ rp,
                                                  unsigned* __restrict__ dAll) {
  int row = blockIdx.x * 4 + (threadIdx.x >> 6);
  if (row >= NN) return;
  int l = threadIdx.x & 63, g = l >> 4, j = l & 15;
  float cw2 = P[3];
  int s = rp[row], e = rp[row + 1];
  float acc[8] = {0.f, 0.f, 0.f, 0.f, 0.f, 0.f, 0.f, 0.f};
  int i = s + g;
  bool have = (i < e);
  uint4 qw; float sc = 0.f, lc = 0.f;
  if (have) {
    int c = part[i]; sc = s2c[slot[i]]; lc = L2[c];
    qw = *(const uint4*)(QK + (size_t)c * UU + 0 + j * 4);
  }
  while (have) {
    int i2 = i + 4;
    bool have2 = (i2 < e);
    uint4 qw2; float sc2 = 0.f, lc2 = 0.f;
    if (have2) {
      int c2_ = part[i2]; sc2 = s2c[slot[i2]]; lc2 = L2[c2_];
      qw2 = *(const uint4*)(QK + (size_t)c2_ * UU + 0 + j * 4);
    }
    float w = cw2 * __expf(sc - lc);
    float qv[8]; unp8(qw, qv);
#pragma unroll
    for (int t = 0; t < 8; t++) acc[t] = fmaf(w, qv[t], acc[t]);
    i = i2; have = have2; qw = qw2; sc = sc2; lc = lc2;
  }
#pragma unroll
  for (int t = 0; t < 8; t++) {
    float v = acc[t];
    v += __shfl_xor(v, 16, 64);
    v += __shfl_xor(v, 32, 64);
    acc[t] = v;
  }
  if (g == 0) *(uint4*)(dAll + (size_t)row * UU + 64 + j * 4) = pk8(acc);
}

// ---------------- fused t3 fwd + dQ3 ----------------
__global__ __launch_bounds__(256) void t3_fused(const unsigned* __restrict__ QK,
                                                const float* __restrict__ Tt,
                                                const float* __restrict__ P,
                                                const int* __restrict__ pu,
                                                const int* __restrict__ pv,
                                                const int* __restrict__ tac,
                                                const int* __restrict__ rp,
                                                float* __restrict__ s3c,
                                                float* __restrict__ L3,
                                                unsigned* __restrict__ dAll) {
  __shared__ float sT[2 * DD];
  int tid = threadIdx.x;
  sT[tid] = Tt[tid];
  __syncthreads();
  int row = blockIdx.x * 4 + (tid >> 6);
  if (row >= NN) return;
  int l = tid & 63, g = l >> 4, j = l & 15;
  float b3s = P[1] * INV_D, cw3 = P[4];
  float q[8];
  unp8(*(const uint4*)(QK + (size_t)row * UU + 128 + j * 4), q);
  int s = rp[row], e = rp[row + 1];
  float m = -3.0e38f, z = 0.f;
  float acc[8] = {0.f, 0.f, 0.f, 0.f, 0.f, 0.f, 0.f, 0.f};
  int i = s + g;
  bool have = (i < e);
  uint4 kuw, kvw; int ta = 0;
  if (have) {
    int u = pu[i], v = pv[i]; ta = tac[i];
    kuw = *(const uint4*)(QK + (size_t)u * UU + 192 + j * 4);
    kvw = *(const uint4*)(QK + (size_t)v * UU + 192 + j * 4);
  }
  while (have) {
    int i2 = i + 4;
    bool have2 = (i2 < e);
    uint4 kuw2, kvw2; int ta2 = 0;
    if (have2) {
      int u2 = pu[i2], v2 = pv[i2]; ta2 = tac[i2];
      kuw2 = *(const uint4*)(QK + (size_t)u2 * UU + 192 + j * 4);
      kvw2 = *(const uint4*)(QK + (size_t)v2 * UU + 192 + j * 4);
    }
    float ku[8], kv[8]; unp8(kuw, ku); unp8(kvw, kv);
    const float* tv = &sT[ta * DD + j * 8];
    float et[8], d = 0.f;
#pragma unroll
    for (int t = 0; t < 8; t++) { et[t] = ku[t] * kv[t] * tv[t]; d = fmaf(q[t], et[t], d); }
    d = redsum16(d);
    float sv = b3s * d;
    if (j == 0) s3c[i] = sv;
    if (sv <= m) {
      float p = __expf(sv - m);
      z += p;
#pragma unroll
      for (int t = 0; t < 8; t++) acc[t] = fmaf(p, et[t], acc[t]);
    } else {
      float r = __expf(m - sv);
      z = fmaf(z, r, 1.f);
#pragma unroll
      for (int t = 0; t < 8; t++) acc[t] = fmaf(acc[t], r, et[t]);
      m = sv;
    }
    i = i2; have = have2; kuw = kuw2; kvw = kvw2; ta = ta2;
  }
  float mx = fmaxf(m, __shfl_xor(m, 16, 64));
  mx = fmaxf(mx, __shfl_xor(mx, 32, 64));
  float r = (z > 0.f) ? __expf(m - mx) : 0.f;
  float zz = z * r;
  zz += __shfl_xor(zz, 16, 64);
  zz += __shfl_xor(zz, 32, 64);
#pragma unroll
  for (int t = 0; t < 8; t++) {
    float v = acc[t] * r;
    v += __shfl_xor(v, 16, 64);
    v += __shfl_xor(v, 32, 64);
    acc[t] = v;
  }
  if (l == 0) L3[row] = (zz > 0.f) ? (mx + __logf(zz)) : 0.f;
  if (g == 0) {
    float coef = (zz > 0.f) ? cw3 / zz : 0.f;
    float o[8];
#pragma unroll
    for (int t = 0; t < 8; t++) o[t] = coef * acc[t];
    *(uint4*)(dAll + (size_t)row * UU + 128 + j * 4) = pk8(o);
  }
}

// ---------------- dK3 gather ----------------
__global__ __launch_bounds__(256) void dk3_gather(const unsigned* __restrict__ QK,
                                                  const float* __restrict__ Tt,
                                                  const float* __restrict__ s3c,
                                                  const float* __restrict__ L3,
                                                  const float* __restrict__ P,
                                                  const int* __restrict__ po,
                                                  const int* __restrict__ pc,
                                                  const int* __restrict__ spk,
                                                  const int* __restrict__ rp,
                                                  unsigned* __restrict__ dAll) {
  __shared__ float sT[2 * DD];
  int tid = threadIdx.x;
  sT[tid] = Tt[tid];
  __syncthreads();
  int row = blockIdx.x * 4 + (tid >> 6);
  if (row >= NN) return;
  int l = tid & 63, g = l >> 4, j = l & 15;
  float cw3 = P[4];
  int s = rp[row], e = rp[row + 1];
  float acc[8] = {0.f, 0.f, 0.f, 0.f, 0.f, 0.f, 0.f, 0.f};
  int i = s + g;
  bool have = (i < e);
  uint4 qw, kw; int ta = 0; float sc = 0.f, lc = 0.f;
  if (have) {
    int o = po[i], c = pc[i], sp = spk[i];
    ta = sp & 1; sc = s3c[sp >> 1]; lc = L3[c];
    qw = *(const uint4*)(QK + (size_t)c * UU + 128 + j * 4);
    kw = *(const uint4*)(QK + (size_t)o * UU + 192 + j * 4);
  }
  while (have) {
    int i2 = i + 4;
    bool have2 = (i2 < e);
    uint4 qw2, kw2; int ta_2 = 0; float sc2 = 0.f, lc2 = 0.f;
    if (have2) {
      int o2 = po[i2], c2_ = pc[i2], sp2 = spk[i2];
      ta_2 = sp2 & 1; sc2 = s3c[sp2 >> 1]; lc2 = L3[c2_];
      qw2 = *(const uint4*)(QK + (size_t)c2_ * UU + 128 + j * 4);
      kw2 = *(const uint4*)(QK + (size_t)o2 * UU + 192 + j * 4);
    }
    float w = cw3 * __expf(sc - lc);
    float qv[8], ko[8]; unp8(qw, qv); unp8(kw, ko);
    const float* tv = &sT[ta * DD + j * 8];
#pragma unroll
    for (int t = 0; t < 8; t++) acc[t] = fmaf(w * tv[t], qv[t] * ko[t], acc[t]);
    i = i2; have = have2; qw = qw2; kw = kw2; ta = ta_2; sc = sc2; lc = lc2;
  }
#pragma unroll
  for (int t = 0; t < 8; t++) {
    float v = acc[t];
    v += __shfl_xor(v, 16, 64);
    v += __shfl_xor(v, 32, 64);
    acc[t] = v;
  }
  if (g == 0) *(uint4*)(dAll + (size_t)row * UU + 192 + j * 4) = pk8(acc);
}

// ---------------- memory-bank energy ----------------
__global__ __launch_bounds__(256) void em_row(const unsigned* __restrict__ QK,
                                              const float* __restrict__ Km,
                                              const float* __restrict__ P,
                                              unsigned* __restrict__ dAll,
                                              float* __restrict__ Lm) {
  __shared__ float sKm[KM * DD];
  int tid = threadIdx.x;
  for (int i = tid; i < KM * DD; i += 256) sKm[i] = Km[i];
  __syncthreads();
  int row = blockIdx.x * 4 + (tid >> 6);
  if (row >= NN) return;
  int l = tid & 63, g = l >> 4, j = l & 15;
  float bms = P[2] * INV_SQRT_D, cwm = P[5];
  float q[8];
  unp8(*(const uint4*)(QK + (size_t)row * UU + 256 + j * 4), q);
  float dk[8];
#pragma unroll
  for (int kk = 0; kk < 8; kk++) {
    int k = g * 8 + kk;
    const float* kr = &sKm[k * DD + j * 8];
    float d = 0.f;
#pragma unroll
    for (int t = 0; t < 8; t++) d = fmaf(q[t], kr[t], d);
    dk[kk] = redsum16(d) * bms;
  }
  float m = dk[0];
#pragma unroll
  for (int kk = 1; kk < 8; kk++) m = fmaxf(m, dk[kk]);
  float mx = fmaxf(m, __shfl_xor(m, 16, 64));
  mx = fmaxf(mx, __shfl_xor(mx, 32, 64));
  float p[8], z = 0.f;
#pragma unroll
  for (int kk = 0; kk < 8; kk++) { p[kk] = __expf(dk[kk] - mx); z += p[kk]; }
  float zz = z;
  zz += __shfl_xor(zz, 16, 64);
  zz += __shfl_xor(zz, 32, 64);
  if (l == 0) Lm[row] = mx + __logf(zz);
  float coef = cwm / zz;
  float acc[8] = {0.f, 0.f, 0.f, 0.f, 0.f, 0.f, 0.f, 0.f};
#pragma unroll
  for (int kk = 0; kk < 8; kk++) {
    int k = g * 8 + kk;
    const float* kr = &sKm[k * DD + j * 8];
    float pc_ = p[kk] * coef;
#pragma unroll
    for (int t = 0; t < 8; t++) acc[t] = fmaf(pc_, kr[t], acc[t]);
  }
#pragma unroll
  for (int t = 0; t < 8; t++) {
    float v = acc[t];
    v += __shfl_xor(v, 16, 64);
    v += __shfl_xor(v, 32, 64);
    acc[t] = v;
  }
  if (g == 0) *(uint4*)(dAll + (size_t)row * UU + 256 + j * 4) = pk8(acc);
}

// ---------------- LN backward + clips + update ----------------
__global__ __launch_bounds__(256) void ln_bwd(const float* __restrict__ X,
                                              const unsigned* __restrict__ dG,
                                              const float* __restrict__ gamma,
                                              const float* __restrict__ meanv,
                                              const float* __restrict__ rstdv,
                                              float* __restrict__ out) {
  int row = blockIdx.x * 4 + (threadIdx.x >> 6);
  if (row >= NN) return;
  int l = threadIdx.x & 63;
  float mu = meanv[row], rstd = rstdv[row];
  float2 x2 = *(const float2*)(X + row * DD + 2 * l);
  unsigned gw = dG[(size_t)row * 64 + l];
  float2 ga = *(const float2*)(gamma + 2 * l);
  float xh0 = (x2.x - mu) * rstd, xh1 = (x2.y - mu) * rstd;
  float dh0 = blo(gw) * ga.x, dh1 = bhi(gw) * ga.y;
  float sa = wredsum(dh0 + dh1) * (1.f / DD);
  float sb = wredsum(dh0 * xh0 + dh1 * xh1) * (1.f / DD);
  float dx0 = rstd * (dh0 - sa - xh0 * sb);
  float dx1 = rstd * (dh1 - sa - xh1 * sb);
  float gn = fmaxf(sqrtf(wredsum(dx0 * dx0 + dx1 * dx1)), 1e-6f);
  float sc = fminf(1.f / gn, 1.f);
  dx0 *= sc; dx1 *= sc;
  float xn0 = x2.x - 0.1f * 0.9999f * dx0;
  float xn1 = x2.y - 0.1f * 0.9999f * dx1;
  float sn = fmaxf(sqrtf(wredsum(xn0 * xn0 + xn1 * xn1)), 1e-6f);
  float sc2 = fminf(10.f / sn, 1.f);
  float2 o; o.x = xn0 * sc2; o.y = xn1 * sc2;
  *(float2*)(out + row * DD + 2 * l) = o;
}

// ---------------- final energy scalar (parallel, atomic) ----------------
__global__ __launch_bounds__(256) void eval_write(const float* __restrict__ L2,
                                                  const float* __restrict__ L3,
                                                  const float* __restrict__ Lm,
                                                  const float* __restrict__ P,
                                                  float* __restrict__ out) {
  int i = blockIdx.x * 256 + threadIdx.x;
  float a2 = 0.f, a3 = 0.f, am = 0.f;
  if (i < NN) { a2 = L2[i]; a3 = L3[i]; am = Lm[i]; }
  a2 = wredsum(a2); a3 = wredsum(a3); am = wredsum(am);
  __shared__ float r2[4], r3[4], rm[4];
  int wv = threadIdx.x >> 6, l = threadIdx.x & 63;
  if (l == 0) { r2[wv] = a2; r3[wv] = a3; rm[wv] = am; }
  __syncthreads();
  if (threadIdx.x == 0) {
    float S2 = r2[0] + r2[1] + r2[2] + r2[3];
    float S3 = r3[0] + r3[1] + r3[2] + r3[3];
    float Sm = rm[0] + rm[1] + rm[2] + rm[3];
    atomicAdd(out, P[6] * S2 + P[7] * S3 + P[8] * Sm);
  }
}

extern "C" void kernel_launch(void* const* d_in, const int* in_sizes, int n_in,
                              void* d_out, int out_size, void* d_ws, size_t ws_size,
                              hipStream_t stream) {
  (void)in_sizes; (void)n_in; (void)out_size;
  const float* X = (const float*)d_in[0];
  const float* EA = (const float*)d_in[1];
  const float* ln_g = (const float*)d_in[2];
  const float* ln_b = (const float*)d_in[3];
  const float* W_Q2 = (const float*)d_in[4];
  const float* W_K2 = (const float*)d_in[5];
  const float* W_Q3 = (const float*)d_in[6];
  const float* W_K3 = (const float*)d_in[7];
  const float* T_tau = (const float*)d_in[8];
  const float* W_Qm = (const float*)d_in[9];
  const float* W_Km = (const float*)d_in[10];
  const float* B_mem = (const float*)d_in[11];
  const float* We1 = (const float*)d_in[12];
  const float* be1 = (const float*)d_in[13];
  const float* We2 = (const float*)d_in[14];
  const float* be2 = (const float*)d_in[15];
  const float* l2s = (const float*)d_in[16];
  const float* l3s = (const float*)d_in[17];
  const float* lms = (const float*)d_in[18];
  const float* b2s = (const float*)d_in[19];
  const float* b3s = (const float*)d_in[20];
  const float* bms = (const float*)d_in[21];
  const int* c2 = (const int*)d_in[22];
  const int* u2 = (const int*)d_in[23];
  const int* c3 = (const int*)d_in[24];
  const int* u3 = (const int*)d_in[25];
  const int* v3 = (const int*)d_in[26];
  const int* ttau = (const int*)d_in[27];
  float* out = (float*)d_out;

  float* ws = (float*)d_ws;
  size_t off = 0;
  auto alloc = [&](size_t n) { float* p = ws + off; off += n; return p; };
  const size_t ND = (size_t)NN * DD;
  unsigned* Gb = (unsigned*)alloc(ND / 2);
  unsigned* QKall = (unsigned*)alloc((size_t)NN * UU);
  unsigned* dAll = (unsigned*)alloc((size_t)NN * UU);
  unsigned* dG = (unsigned*)alloc(ND / 2);
  ushort_t* Wt5 = (ushort_t*)alloc(640 * 128 / 2);
  ushort_t* Wcat = (ushort_t*)alloc(640 * 128 / 2);
  float* Km = alloc((size_t)KM * DD);
  float* a2 = alloc(EE);
  float* s2c = alloc(EE);
  float* s3c = alloc(TT);
  float* meanv = alloc(NN);
  float* rstdv = alloc(NN);
  float* L2 = alloc(NN);
  float* L3 = alloc(NN);
  float* Lm = alloc(NN);
  float* Pparams = alloc(16);
  int* cnt = (int*)alloc(4 * (size_t)NN);
  int* rowptr = (int*)alloc(4 * (size_t)(NN + 1));
  int* cursor = (int*)alloc(4 * (size_t)NN);
  int* spart = (int*)alloc(4 * SCAN_NB);
  int* part_c2 = (int*)alloc(EE);
  float* apay_c2 = alloc(EE);
  int* slot_u2 = (int*)alloc(EE);
  int* part_u2 = (int*)alloc(EE);
  int* pu_c3 = (int*)alloc(TT);
  int* pv_c3 = (int*)alloc(TT);
  int* ta_c3 = (int*)alloc(TT);
  int* po_uv = (int*)alloc(2 * (size_t)TT);
  int* pc_uv = (int*)alloc(2 * (size_t)TT);
  int* spk_uv = (int*)alloc(2 * (size_t)TT);
  if (off * sizeof(float) > ws_size) return;

  int* cnt_c2 = cnt, *cnt_u2 = cnt + NN, *cnt_c3 = cnt + 2 * NN, *cnt_uv = cnt + 3 * NN;
  int* rp_c2 = rowptr, *rp_u2 = rowptr + (NN + 1), *rp_c3 = rowptr + 2 * (NN + 1), *rp_uv = rowptr + 3 * (NN + 1);
  int* cu_c2 = cursor, *cu_u2 = cursor + NN, *cu_c3 = cursor + 2 * NN, *cu_uv = cursor + 3 * NN;

  hipMemsetAsync(cnt, 0, 4ull * NN * sizeof(int), stream);
  hipMemsetAsync(out + ND, 0, sizeof(float), stream);

  params_k<<<1, 64, 0, stream>>>(l2s, l3s, lms, b2s, b3s, bms, Pparams);

  int rowB = (NN + 3) / 4;
  int mB = (NN + 63) / 64;

  ln_fwd<<<rowB, 256, 0, stream>>>(X, ln_g, ln_b, Gb, meanv, rstdv);
  w_conv<<<320, 256, 0, stream>>>(W_Q2, W_K2, W_Q3, W_K3, W_Qm, Wt5, Wcat);
  mfma_fwd<<<dim3(mB, 10), 256, 0, stream>>>((const ushort_t*)Gb, Wt5, (ushort_t*)QKall, NN);
  gemm_km<<<1, 256, 0, stream>>>(B_mem, W_Km, Km, KM);
  edge_mlp<<<(EE + 255) / 256, 256, 0, stream>>>(EA, We1, be1, We2, be2, a2);

  hist2<<<(EE + 255) / 256, 256, 0, stream>>>(c2, u2, cnt_c2, cnt_u2, EE);
  hist_t3<<<(TT + 255) / 256, 256, 0, stream>>>(c3, u3, v3, cnt_c3, cnt_uv, TT);
  scan_p1<<<dim3(SCAN_NB, 4), 256, 0, stream>>>(cnt, spart);
  scan_p2<<<1, 256, 0, stream>>>(spart);
  scan_p3<<<dim3(SCAN_NB, 4), 256, 0, stream>>>(cnt, spart, rowptr, cursor);
  scat2<<<(EE + 255) / 256, 256, 0, stream>>>(c2, u2, a2, cu_c2, cu_u2,
                                              part_c2, apay_c2, slot_u2, part_u2, EE);
  scat_t3<<<(TT + 255) / 256, 256, 0, stream>>>(c3, u3, v3, ttau, cu_c3, cu_uv,
                                                pu_c3, pv_c3, ta_c3,
                                                po_uv, pc_uv, spk_uv, TT);

  e2_fused<<<rowB, 256, 0, stream>>>(QKall, Pparams, part_c2, apay_c2, rp_c2, s2c, L2, dAll);
  dk2_gather<<<rowB, 256, 0, stream>>>(QKall, s2c, L2, Pparams, slot_u2, part_u2, rp_u2, dAll);
  t3_fused<<<rowB, 256, 0, stream>>>(QKall, T_tau, Pparams, pu_c3, pv_c3, ta_c3, rp_c3, s3c, L3, dAll);
  dk3_gather<<<rowB, 256, 0, stream>>>(QKall, T_tau, s3c, L3, Pparams, po_uv, pc_uv, spk_uv, rp_uv, dAll);
  em_row<<<rowB, 256, 0, stream>>>(QKall, Km, Pparams, dAll, Lm);

  mfma_bwd<<<dim3(mB, 2), 256, 0, stream>>>((const ushort_t*)dAll, Wcat, dG, NN);

  ln_bwd<<<rowB, 256, 0, stream>>>(X, dG, ln_g, meanv, rstdv, out);
  eval_write<<<(NN + 255) / 256, 256, 0, stream>>>(L2, L3, Lm, Pparams, out + ND);
}

// Round 6
// 905.979 us; speedup vs baseline: 4.5004x; 1.0461x over previous
//
#include <hip/hip_runtime.h>

#define NN 50000
#define DD 128
#define EE 800000
#define TT 400000
#define KM 32
#define UU 320  // uints per 640-col bf16 row
#define SCAN_TILE 2048
#define SCAN_NB ((NN + SCAN_TILE - 1) / SCAN_TILE)  // 25

static constexpr float INV_SQRT_D = 0.08838834764831845f; // 1/sqrt(128)
static constexpr float INV_D = 1.f / 128.f;

typedef __attribute__((ext_vector_type(8))) short bf16x8;
typedef __attribute__((ext_vector_type(4))) float f32x4;
typedef unsigned short ushort_t;

__device__ __forceinline__ float softplus_f(float x) {
  return (x > 20.f) ? x : log1pf(__expf(x));
}

__device__ __forceinline__ float gelu_tanh(float x) {
  float x3 = x * x * x;
  float u = 0.7978845608028654f * (x + 0.044715f * x3);
  u = fminf(fmaxf(u, -15.f), 15.f);
  float e = __expf(2.f * u);
  float t = (e - 1.f) / (e + 1.f);
  return 0.5f * x * (1.f + t);
}

__device__ __forceinline__ float wredsum(float v) {
#pragma unroll
  for (int m = 32; m; m >>= 1) v += __shfl_xor(v, m, 64);
  return v;
}

__device__ __forceinline__ float redsum16(float v) {
#pragma unroll
  for (int m = 1; m < 16; m <<= 1) v += __shfl_xor(v, m, 64);
  return v;
}

__device__ __forceinline__ float blo(unsigned w) { return __uint_as_float(w << 16); }
__device__ __forceinline__ float bhi(unsigned w) { return __uint_as_float(w & 0xffff0000u); }
__device__ __forceinline__ unsigned pack_bf16(float a, float b) {
  unsigned ua = __float_as_uint(a); ua += 0x7fff + ((ua >> 16) & 1);
  unsigned ub = __float_as_uint(b); ub += 0x7fff + ((ub >> 16) & 1);
  return (ua >> 16) | (ub & 0xffff0000u);
}
__device__ __forceinline__ ushort_t bf16_1(float x) {
  unsigned u = __float_as_uint(x); u += 0x7fff + ((u >> 16) & 1);
  return (ushort_t)(u >> 16);
}
__device__ __forceinline__ void unp8(uint4 w, float* f) {
  f[0] = blo(w.x); f[1] = bhi(w.x); f[2] = blo(w.y); f[3] = bhi(w.y);
  f[4] = blo(w.z); f[5] = bhi(w.z); f[6] = blo(w.w); f[7] = bhi(w.w);
}
__device__ __forceinline__ uint4 pk8(const float* f) {
  uint4 r;
  r.x = pack_bf16(f[0], f[1]); r.y = pack_bf16(f[2], f[3]);
  r.z = pack_bf16(f[4], f[5]); r.w = pack_bf16(f[6], f[7]);
  return r;
}

// params: [0]=b2 [1]=b3 [2]=bm [3]=cw2 [4]=cw3 [5]=cwm [6]=-sp2/b2 [7]=-sp3/b3 [8]=-spm/bm
__global__ void params_k(const float* l2, const float* l3, const float* lm,
                         const float* b2, const float* b3, const float* bm,
                         float* __restrict__ P) {
  if (threadIdx.x != 0) return;
  float B2 = fminf(softplus_f(b2[0]), 5.f);
  float B3 = fminf(softplus_f(b3[0]), 5.f);
  float Bm = fminf(softplus_f(bm[0]), 5.f);
  float S2 = softplus_f(l2[0]);
  float S3 = softplus_f(l3[0]);
  float Sm = softplus_f(lm[0]);
  P[0] = B2; P[1] = B3; P[2] = Bm;
  P[3] = -S2 * INV_SQRT_D; P[4] = -S3 * INV_D; P[5] = -Sm * INV_SQRT_D;
  P[6] = -S2 / B2; P[7] = -S3 / B3; P[8] = -Sm / Bm;
}

// ---------------- LayerNorm forward -> bf16 G ----------------
__global__ __launch_bounds__(256) void ln_fwd(const float* __restrict__ X,
                                              const float* __restrict__ gamma,
                                              const float* __restrict__ beta,
                                              unsigned* __restrict__ Gb,
                                              float* __restrict__ meanv,
                                              float* __restrict__ rstdv) {
  int row = blockIdx.x * 4 + (threadIdx.x >> 6);
  if (row >= NN) return;
  int l = threadIdx.x & 63;
  float2 x2 = *(const float2*)(X + row * DD + 2 * l);
  float mu = wredsum(x2.x + x2.y) * (1.f / DD);
  float d0 = x2.x - mu, d1 = x2.y - mu;
  float var = wredsum(d0 * d0 + d1 * d1) * (1.f / DD);
  float rstd = rsqrtf(var + 1e-5f);
  float2 g2 = *(const float2*)(gamma + 2 * l);
  float2 b2 = *(const float2*)(beta + 2 * l);
  float o0 = d0 * rstd * g2.x + b2.x;
  float o1 = d1 * rstd * g2.y + b2.y;
  Gb[(size_t)row * 64 + l] = pack_bf16(o0, o1);
  if (l == 0) { meanv[row] = mu; rstdv[row] = rstd; }
}

// ---------------- weight conversion ----------------
__global__ __launch_bounds__(256) void w_conv(const float* W0, const float* W1, const float* W2,
                                              const float* W3, const float* W4,
                                              ushort_t* __restrict__ Wt,
                                              ushort_t* __restrict__ Wc) {
  int idx = blockIdx.x * 256 + threadIdx.x;
  if (idx >= 640 * 128) return;
  const float* Ws[5] = {W0, W1, W2, W3, W4};
  int n = idx >> 7, k = idx & 127;
  Wt[idx] = bf16_1(Ws[n >> 7][(size_t)k * 128 + (n & 127)]);
  int k2 = idx >> 7, n2 = idx & 127;
  Wc[(size_t)n2 * 640 + k2] = bf16_1(Ws[k2 >> 7][(size_t)n2 * 128 + (k2 & 127)]);
}

// ---------------- fwd MFMA GEMM: QK[M,640](bf16) = Gb[M,128](bf16) @ Wt^T ----------------
__global__ __launch_bounds__(256) void mfma_fwd(const ushort_t* __restrict__ Gb,
                                                const ushort_t* __restrict__ Wt,
                                                ushort_t* __restrict__ QK, int M) {
  __shared__ ushort_t sB[64][136];
  int tid = threadIdx.x;
  int nb = blockIdx.y * 64;
  for (int idx = tid; idx < 64 * 16; idx += 256) {
    int r = idx >> 4, c8 = idx & 15;
    *(bf16x8*)&sB[r][c8 * 8] = *(const bf16x8*)(Wt + (size_t)(nb + r) * 128 + c8 * 8);
  }
  __syncthreads();
  int w = tid >> 6, l = tid & 63, quad = l >> 4, j = l & 15;
  int row0 = blockIdx.x * 64 + w * 16;
  int arow = row0 + j; if (arow >= M) arow = M - 1;
  const bf16x8* ap = (const bf16x8*)(Gb + (size_t)arow * 128);
  f32x4 acc[4];
#pragma unroll
  for (int nt = 0; nt < 4; nt++) acc[nt] = (f32x4){0.f, 0.f, 0.f, 0.f};
#pragma unroll
  for (int kc = 0; kc < 4; kc++) {
    bf16x8 a = ap[kc * 4 + quad];
#pragma unroll
    for (int nt = 0; nt < 4; nt++) {
      bf16x8 b = *(const bf16x8*)&sB[nt * 16 + j][kc * 32 + quad * 8];
      acc[nt] = __builtin_amdgcn_mfma_f32_16x16x32_bf16(a, b, acc[nt], 0, 0, 0);
    }
  }
#pragma unroll
  for (int nt = 0; nt < 4; nt++)
#pragma unroll
    for (int r = 0; r < 4; r++) {
      int row = row0 + quad * 4 + r;
      if (row < M) QK[(size_t)row * 640 + nb + nt * 16 + j] = bf16_1(acc[nt][r]);
    }
}

// ---------------- bwd MFMA GEMM: dG[M,128](bf16) = dAll[M,640](bf16) @ Wc^T ----------------
__global__ __launch_bounds__(256) void mfma_bwd(const ushort_t* __restrict__ dAll,
                                                const ushort_t* __restrict__ Wc,
                                                unsigned* __restrict__ dG, int M) {
  __shared__ ushort_t sB[64][40];
  int tid = threadIdx.x;
  int nb = blockIdx.y * 64;
  int w = tid >> 6, l = tid & 63, quad = l >> 4, j = l & 15;
  int row0 = blockIdx.x * 64 + w * 16;
  int arow = row0 + j; if (arow >= M) arow = M - 1;
  const ushort_t* arp = dAll + (size_t)arow * 640;
  f32x4 acc[4];
#pragma unroll
  for (int nt = 0; nt < 4; nt++) acc[nt] = (f32x4){0.f, 0.f, 0.f, 0.f};
  int sr = tid >> 2, sc = tid & 3;
  for (int kc = 0; kc < 20; kc++) {
    __syncthreads();
    *(bf16x8*)&sB[sr][sc * 8] = *(const bf16x8*)(Wc + (size_t)(nb + sr) * 640 + kc * 32 + sc * 8);
    __syncthreads();
    bf16x8 a = *(const bf16x8*)(arp + kc * 32 + quad * 8);
#pragma unroll
    for (int nt = 0; nt < 4; nt++) {
      bf16x8 b = *(const bf16x8*)&sB[nt * 16 + j][quad * 8];
      acc[nt] = __builtin_amdgcn_mfma_f32_16x16x32_bf16(a, b, acc[nt], 0, 0, 0);
    }
  }
#pragma unroll
  for (int nt = 0; nt < 4; nt++)
#pragma unroll
    for (int r = 0; r < 4; r++) {
      int row = row0 + quad * 4 + r;
      if (row < M) ((ushort_t*)dG)[(size_t)row * 128 + nb + nt * 16 + j] = bf16_1(acc[nt][r]);
    }
}

// ---------------- small fp32 GEMM for Km = B_mem @ W_Km ----------------
__global__ __launch_bounds__(256, 1) void gemm_km(const float* __restrict__ A,
                                                  const float* __restrict__ W,
                                                  float* __restrict__ C, int M) {
  __shared__ float As[32][132];
  __shared__ float Wst[128][136];
  const int tid = threadIdx.x;
  for (int idx = tid; idx < 128 * 128; idx += 256) {
    int k = idx >> 7, jj = idx & 127;
    Wst[k][jj] = W[k * 128 + jj];
  }
  for (int idx = tid; idx < 32 * 128; idx += 256) {
    int r = idx >> 7, d = idx & 127;
    As[r][d] = A[r * 128 + d];
  }
  __syncthreads();
  int r = tid >> 3, c0 = (tid & 7) * 16;
  float acc[16];
#pragma unroll
  for (int q = 0; q < 16; q++) acc[q] = 0.f;
  for (int k = 0; k < 128; k++) {
    float av = As[r][k];
#pragma unroll
    for (int q = 0; q < 16; q++) acc[q] = fmaf(av, Wst[k][c0 + q], acc[q]);
  }
#pragma unroll
  for (int q = 0; q < 16; q++) C[r * 128 + c0 + q] = acc[q];
}

// ---------------- edge MLP via MFMA: one wave = 16 edges ----------------
// Layer1: [16e x 16f] @ [16f x 128h] via 8x mfma_16x16x32_bf16 (K zero-padded to 32)
__global__ __launch_bounds__(256) void edge_mlp(const float* __restrict__ EA,
                                                const float* __restrict__ We1,
                                                const float* __restrict__ be1,
                                                const float* __restrict__ We2,
                                                const float* __restrict__ be2,
                                                float* __restrict__ a2) {
  __shared__ float sW1[16 * 128];
  __shared__ float sb1[128];
  __shared__ float sW2[128];
  int tid = threadIdx.x;
  for (int i = tid; i < 2048; i += 256) sW1[i] = We1[i];
  if (tid < 128) { sb1[tid] = be1[tid]; sW2[tid] = We2[tid]; }
  __syncthreads();
  int w = tid >> 6, l = tid & 63;
  int m = l & 15, q = l >> 4;
  // B fragments: lane holds We1[k=q*8+j][n=nt*16+m] (k>=16 -> 0)
  union u8 { bf16x8 v; ushort_t s[8]; };
  u8 bf[8];
  float bb[8], ww[8];
#pragma unroll
  for (int nt = 0; nt < 8; nt++) {
    int n = nt * 16 + m;
#pragma unroll
    for (int j = 0; j < 8; j++) {
      int k = q * 8 + j;
      bf[nt].s[j] = (k < 16) ? bf16_1(sW1[k * 128 + n]) : (ushort_t)0;
    }
    bb[nt] = sb1[n];
    ww[nt] = sW2[n];
  }
  float be2v = be2[0];
  for (int batch = 0; batch < 4; batch++) {
    int e0 = blockIdx.x * 256 + batch * 64 + w * 16;
    u8 af;
    if (q < 2) {
      const float* ep = EA + (size_t)(e0 + m) * 16 + q * 8;
      float4 v0 = *(const float4*)ep;
      float4 v1 = *(const float4*)(ep + 4);
      af.s[0] = bf16_1(v0.x); af.s[1] = bf16_1(v0.y);
      af.s[2] = bf16_1(v0.z); af.s[3] = bf16_1(v0.w);
      af.s[4] = bf16_1(v1.x); af.s[5] = bf16_1(v1.y);
      af.s[6] = bf16_1(v1.z); af.s[7] = bf16_1(v1.w);
    } else {
#pragma unroll
      for (int j = 0; j < 8; j++) af.s[j] = 0;
    }
    f32x4 z4 = (f32x4){0.f, 0.f, 0.f, 0.f};
    float s0 = 0.f, s1 = 0.f, s2 = 0.f, s3 = 0.f;
#pragma unroll
    for (int nt = 0; nt < 8; nt++) {
      f32x4 acc = __builtin_amdgcn_mfma_f32_16x16x32_bf16(af.v, bf[nt].v, z4, 0, 0, 0);
      float bias = bb[nt], w2v = ww[nt];
      s0 = fmaf(gelu_tanh(acc[0] + bias), w2v, s0);
      s1 = fmaf(gelu_tanh(acc[1] + bias), w2v, s1);
      s2 = fmaf(gelu_tanh(acc[2] + bias), w2v, s2);
      s3 = fmaf(gelu_tanh(acc[3] + bias), w2v, s3);
    }
    s0 = redsum16(s0); s1 = redsum16(s1); s2 = redsum16(s2); s3 = redsum16(s3);
    if (m == 0) {
      int eb = e0 + q * 4;
      a2[eb + 0] = s0 + be2v;
      a2[eb + 1] = s1 + be2v;
      a2[eb + 2] = s2 + be2v;
      a2[eb + 3] = s3 + be2v;
    }
  }
}

// ---------------- CSR build ----------------
__global__ __launch_bounds__(256) void hist2(const int* __restrict__ a,
                                             const int* __restrict__ b,
                                             int* __restrict__ ca,
                                             int* __restrict__ cb, int n) {
  int e = blockIdx.x * 256 + threadIdx.x;
  if (e >= n) return;
  atomicAdd(&ca[a[e]], 1);
  atomicAdd(&cb[b[e]], 1);
}

__global__ __launch_bounds__(256) void hist_t3(const int* __restrict__ c,
                                               const int* __restrict__ u,
                                               const int* __restrict__ v,
                                               int* __restrict__ cc,
                                               int* __restrict__ cuv, int n) {
  int t = blockIdx.x * 256 + threadIdx.x;
  if (t >= n) return;
  atomicAdd(&cc[c[t]], 1);
  atomicAdd(&cuv[u[t]], 1);
  atomicAdd(&cuv[v[t]], 1);
}

// ---------------- parallel 3-phase scan over 4 count arrays ----------------
__global__ __launch_bounds__(256) void scan_p1(const int* __restrict__ cnt,
                                               int* __restrict__ part) {
  int arr = blockIdx.y, b = blockIdx.x;
  const int* c = cnt + (size_t)arr * NN;
  int gi = b * SCAN_TILE + threadIdx.x * 8;
  int s = 0;
#pragma unroll
  for (int t = 0; t < 8; t++) s += (gi + t < NN) ? c[gi + t] : 0;
#pragma unroll
  for (int m = 32; m; m >>= 1) s += __shfl_xor(s, m, 64);
  __shared__ int wt[4];
  int lane = threadIdx.x & 63, wid = threadIdx.x >> 6;
  if (lane == 0) wt[wid] = s;
  __syncthreads();
  if (threadIdx.x == 0) part[arr * SCAN_NB + b] = wt[0] + wt[1] + wt[2] + wt[3];
}

__global__ __launch_bounds__(256) void scan_p2(int* __restrict__ part) {
  int w = threadIdx.x >> 6, l = threadIdx.x & 63;
  int v = (l < SCAN_NB) ? part[w * SCAN_NB + l] : 0;
  int x = v;
#pragma unroll
  for (int d = 1; d < 64; d <<= 1) {
    int y = __shfl_up(x, d, 64);
    if (l >= d) x += y;
  }
  if (l < SCAN_NB) part[w * SCAN_NB + l] = x - v;
}

__global__ __launch_bounds__(256) void scan_p3(const int* __restrict__ cnt,
                                               const int* __restrict__ part,
                                               int* __restrict__ rowptr,
                                               int* __restrict__ cursor) {
  int arr = blockIdx.y, b = blockIdx.x;
  const int* c = cnt + (size_t)arr * NN;
  int* rp = rowptr + (size_t)arr * (NN + 1);
  int* cur = cursor + (size_t)arr * NN;
  int tid = threadIdx.x;
  int gi = b * SCAN_TILE + tid * 8;
  int vals[8];
#pragma unroll
  for (int t = 0; t < 8; t++) vals[t] = (gi + t < NN) ? c[gi + t] : 0;
  int tsum = 0;
#pragma unroll
  for (int t = 0; t < 8; t++) tsum += vals[t];
  int lane = tid & 63, wid = tid >> 6;
  int x = tsum;
#pragma unroll
  for (int d = 1; d < 64; d <<= 1) {
    int y = __shfl_up(x, d, 64);
    if (lane >= d) x += y;
  }
  __shared__ int wt[4];
  if (lane == 63) wt[wid] = x;
  __syncthreads();
  int wadd = 0;
  for (int w = 0; w < wid; w++) wadd += wt[w];
  int running = part[arr * SCAN_NB + b] + wadd + x - tsum;
#pragma unroll
  for (int t = 0; t < 8; t++) {
    if (gi + t < NN) { rp[gi + t] = running; cur[gi + t] = running; }
    running += vals[t];
  }
  if (b == SCAN_NB - 1 && tid == 255) rp[NN] = running;
}

__global__ __launch_bounds__(256) void scat2(const int* __restrict__ c2,
                                             const int* __restrict__ u2,
                                             const float* __restrict__ a2,
                                             int* __restrict__ cuc,
                                             int* __restrict__ cuu,
                                             int* __restrict__ part_c,
                                             float* __restrict__ apay_c,
                                             int* __restrict__ slot_u,
                                             int* __restrict__ part_u, int n) {
  int e = blockIdx.x * 256 + threadIdx.x;
  if (e >= n) return;
  int c = c2[e], u = u2[e];
  int p = atomicAdd(&cuc[c], 1);
  part_c[p] = u; apay_c[p] = a2[e];
  int p2 = atomicAdd(&cuu[u], 1);
  slot_u[p2] = p; part_u[p2] = c;
}

__global__ __launch_bounds__(256) void scat_t3(const int* __restrict__ c3,
                                               const int* __restrict__ u3,
                                               const int* __restrict__ v3,
                                               const int* __restrict__ ttau,
                                               int* __restrict__ cuc,
                                               int* __restrict__ cuv,
                                               int* __restrict__ pu_c,
                                               int* __restrict__ pv_c,
                                               int* __restrict__ ta_c,
                                               int* __restrict__ po,
                                               int* __restrict__ pc,
                                               int* __restrict__ spk, int n) {
  int t = blockIdx.x * 256 + threadIdx.x;
  if (t >= n) return;
  int c = c3[t], u = u3[t], v = v3[t], ta = ttau[t] & 1;
  int p = atomicAdd(&cuc[c], 1);
  pu_c[p] = u; pv_c[p] = v; ta_c[p] = ta;
  int sp = (p << 1) | ta;
  int q1 = atomicAdd(&cuv[u], 1);
  po[q1] = v; pc[q1] = c; spk[q1] = sp;
  int q2 = atomicAdd(&cuv[v], 1);
  po[q2] = u; pc[q2] = c; spk[q2] = sp;
}

// ---------------- fused e2 fwd + dQ2 (3-deep pipeline) ----------------
__global__ __launch_bounds__(256) void e2_fused(const unsigned* __restrict__ QK,
                                                const float* __restrict__ P,
                                                const int* __restrict__ part,
                                                const float* __restrict__ apay,
                                                const int* __restrict__ rp,
                                                float* __restrict__ s2c,
                                                float* __restrict__ L2,
                                                unsigned* __restrict__ dAll) {
  int row = blockIdx.x * 4 + (threadIdx.x >> 6);
  if (row >= NN) return;
  int l = threadIdx.x & 63, g = l >> 4, j = l & 15;
  float b2s = P[0] * INV_SQRT_D, cw2 = P[3];
  float q[8];
  unp8(*(const uint4*)(QK + (size_t)row * UU + j * 4), q);
  int s = rp[row], e = rp[row + 1];
  float m = -3.0e38f, z = 0.f;
  float acc[8] = {0.f, 0.f, 0.f, 0.f, 0.f, 0.f, 0.f, 0.f};
  int i0 = s + g;
  uint4 kA = {0, 0, 0, 0}, kB = {0, 0, 0, 0};
  float aA = 0.f, aB = 0.f;
  if (i0 < e) {
    int u = part[i0]; aA = apay[i0];
    kA = *(const uint4*)(QK + (size_t)u * UU + 64 + j * 4);
  }
  if (i0 + 4 < e) {
    int u = part[i0 + 4]; aB = apay[i0 + 4];
    kB = *(const uint4*)(QK + (size_t)u * UU + 64 + j * 4);
  }
  for (int i = i0; i < e; i += 4) {
    uint4 kC = {0, 0, 0, 0}; float aC = 0.f;
    if (i + 8 < e) {
      int u = part[i + 8]; aC = apay[i + 8];
      kC = *(const uint4*)(QK + (size_t)u * UU + 64 + j * 4);
    }
    float k[8]; unp8(kA, k);
    float d = 0.f;
#pragma unroll
    for (int t = 0; t < 8; t++) d = fmaf(q[t], k[t], d);
    d = redsum16(d);
    float sv = b2s * d + aA;
    if (j == 0) s2c[i] = sv;
    if (sv <= m) {
      float p = __expf(sv - m);
      z += p;
#pragma unroll
      for (int t = 0; t < 8; t++) acc[t] = fmaf(p, k[t], acc[t]);
    } else {
      float r = __expf(m - sv);
      z = fmaf(z, r, 1.f);
#pragma unroll
      for (int t = 0; t < 8; t++) acc[t] = fmaf(acc[t], r, k[t]);
      m = sv;
    }
    kA = kB; aA = aB; kB = kC; aB = aC;
  }
  float mx = fmaxf(m, __shfl_xor(m, 16, 64));
  mx = fmaxf(mx, __shfl_xor(mx, 32, 64));
  float r = (z > 0.f) ? __expf(m - mx) : 0.f;
  float zz = z * r;
  zz += __shfl_xor(zz, 16, 64);
  zz += __shfl_xor(zz, 32, 64);
#pragma unroll
  for (int t = 0; t < 8; t++) {
    float v = acc[t] * r;
    v += __shfl_xor(v, 16, 64);
    v += __shfl_xor(v, 32, 64);
    acc[t] = v;
  }
  if (l == 0) L2[row] = (zz > 0.f) ? (mx + __logf(zz)) : 0.f;
  if (g == 0) {
    float coef = (zz > 0.f) ? cw2 / zz : 0.f;
    float o[8];
#pragma unroll
    for (int t = 0; t < 8; t++) o[t] = coef * acc[t];
    *(uint4*)(dAll + (size_t)row * UU + 0 + j * 4) = pk8(o);
  }
}

// ---------------- dK2 gather (3-deep pipeline) ----------------
__global__ __launch_bounds__(256) void dk2_gather(const unsigned* __restrict__ QK,
                                                  const float* __restrict__ s2c,
                                                  const float* __restrict__ L2,
                                                  const float* __restrict__ P,
                                                  const int* __restrict__ slot,
                                                  const int* __restrict__ part,
                                                  const int* __restrict__ rp,
                                                  unsigned* __restrict__ dAll) {
  int row = blockIdx.x * 4 + (threadIdx.x >> 6);
  if (row >= NN) return;
  int l = threadIdx.x & 63, g = l >> 4, j = l & 15;
  float cw2 = P[3];
  int s = rp[row], e = rp[row + 1];
  float acc[8] = {0.f, 0.f, 0.f, 0.f, 0.f, 0.f, 0.f, 0.f};
  int i0 = s + g;
  uint4 qA = {0, 0, 0, 0}, qB = {0, 0, 0, 0};
  float scA = 0.f, lcA = 0.f, scB = 0.f, lcB = 0.f;
  if (i0 < e) {
    int c = part[i0]; scA = s2c[slot[i0]]; lcA = L2[c];
    qA = *(const uint4*)(QK + (size_t)c * UU + 0 + j * 4);
  }
  if (i0 + 4 < e) {
    int c = part[i0 + 4]; scB = s2c[slot[i0 + 4]]; lcB = L2[c];
    qB = *(const uint4*)(QK + (size_t)c * UU + 0 + j * 4);
  }
  for (int i = i0; i < e; i += 4) {
    uint4 qC = {0, 0, 0, 0}; float scC = 0.f, lcC = 0.f;
    if (i + 8 < e) {
      int c = part[i + 8]; scC = s2c[slot[i + 8]]; lcC = L2[c];
      qC = *(const uint4*)(QK + (size_t)c * UU + 0 + j * 4);
    }
    float w = cw2 * __expf(scA - lcA);
    float qv[8]; unp8(qA, qv);
#pragma unroll
    for (int t = 0; t < 8; t++) acc[t] = fmaf(w, qv[t], acc[t]);
    qA = qB; scA = scB; lcA = lcB;
    qB = qC; scB = scC; lcB = lcC;
  }
#pragma unroll
  for (int t = 0; t < 8; t++) {
    float v = acc[t];
    v += __shfl_xor(v, 16, 64);
    v += __shfl_xor(v, 32, 64);
    acc[t] = v;
  }
  if (g == 0) *(uint4*)(dAll + (size_t)row * UU + 64 + j * 4) = pk8(acc);
}

// ---------------- fused t3 fwd + dQ3 (3-deep pipeline) ----------------
__global__ __launch_bounds__(256) void t3_fused(const unsigned* __restrict__ QK,
                                                const float* __restrict__ Tt,
                                                const float* __restrict__ P,
                                                const int* __restrict__ pu,
                                                const int* __restrict__ pv,
                                                const int* __restrict__ tac,
                                                const int* __restrict__ rp,
                                                float* __restrict__ s3c,
                                                float* __restrict__ L3,
                                                unsigned* __restrict__ dAll) {
  __shared__ float sT[2 * DD];
  int tid = threadIdx.x;
  sT[tid] = Tt[tid];
  __syncthreads();
  int row = blockIdx.x * 4 + (tid >> 6);
  if (row >= NN) return;
  int l = tid & 63, g = l >> 4, j = l & 15;
  float b3s = P[1] * INV_D, cw3 = P[4];
  float q[8];
  unp8(*(const uint4*)(QK + (size_t)row * UU + 128 + j * 4), q);
  int s = rp[row], e = rp[row + 1];
  float m = -3.0e38f, z = 0.f;
  float acc[8] = {0.f, 0.f, 0.f, 0.f, 0.f, 0.f, 0.f, 0.f};
  int i0 = s + g;
  uint4 kuA = {0, 0, 0, 0}, kvA = {0, 0, 0, 0};
  uint4 kuB = {0, 0, 0, 0}, kvB = {0, 0, 0, 0};
  int taA = 0, taB = 0;
  if (i0 < e) {
    int u = pu[i0], v = pv[i0]; taA = tac[i0];
    kuA = *(const uint4*)(QK + (size_t)u * UU + 192 + j * 4);
    kvA = *(const uint4*)(QK + (size_t)v * UU + 192 + j * 4);
  }
  if (i0 + 4 < e) {
    int u = pu[i0 + 4], v = pv[i0 + 4]; taB = tac[i0 + 4];
    kuB = *(const uint4*)(QK + (size_t)u * UU + 192 + j * 4);
    kvB = *(const uint4*)(QK + (size_t)v * UU + 192 + j * 4);
  }
  for (int i = i0; i < e; i += 4) {
    uint4 kuC = {0, 0, 0, 0}, kvC = {0, 0, 0, 0}; int taC = 0;
    if (i + 8 < e) {
      int u = pu[i + 8], v = pv[i + 8]; taC = tac[i + 8];
      kuC = *(const uint4*)(QK + (size_t)u * UU + 192 + j * 4);
      kvC = *(const uint4*)(QK + (size_t)v * UU + 192 + j * 4);
    }
    float ku[8], kv[8]; unp8(kuA, ku); unp8(kvA, kv);
    const float* tv = &sT[taA * DD + j * 8];
    float et[8], d = 0.f;
#pragma unroll
    for (int t = 0; t < 8; t++) { et[t] = ku[t] * kv[t] * tv[t]; d = fmaf(q[t], et[t], d); }
    d = redsum16(d);
    float sv = b3s * d;
    if (j == 0) s3c[i] = sv;
    if (sv <= m) {
      float p = __expf(sv - m);
      z += p;
#pragma unroll
      for (int t = 0; t < 8; t++) acc[t] = fmaf(p, et[t], acc[t]);
    } else {
      float r = __expf(m - sv);
      z = fmaf(z, r, 1.f);
#pragma unroll
      for (int t = 0; t < 8; t++) acc[t] = fmaf(acc[t], r, et[t]);
      m = sv;
    }
    kuA = kuB; kvA = kvB; taA = taB;
    kuB = kuC; kvB = kvC; taB = taC;
  }
  float mx = fmaxf(m, __shfl_xor(m, 16, 64));
  mx = fmaxf(mx, __shfl_xor(mx, 32, 64));
  float r = (z > 0.f) ? __expf(m - mx) : 0.f;
  float zz = z * r;
  zz += __shfl_xor(zz, 16, 64);
  zz += __shfl_xor(zz, 32, 64);
#pragma unroll
  for (int t = 0; t < 8; t++) {
    float v = acc[t] * r;
    v += __shfl_xor(v, 16, 64);
    v += __shfl_xor(v, 32, 64);
    acc[t] = v;
  }
  if (l == 0) L3[row] = (zz > 0.f) ? (mx + __logf(zz)) : 0.f;
  if (g == 0) {
    float coef = (zz > 0.f) ? cw3 / zz : 0.f;
    float o[8];
#pragma unroll
    for (int t = 0; t < 8; t++) o[t] = coef * acc[t];
    *(uint4*)(dAll + (size_t)row * UU + 128 + j * 4) = pk8(o);
  }
}

// ---------------- dK3 gather (3-deep pipeline) ----------------
__global__ __launch_bounds__(256) void dk3_gather(const unsigned* __restrict__ QK,
                                                  const float* __restrict__ Tt,
                                                  const float* __restrict__ s3c,
                                                  const float* __restrict__ L3,
                                                  const float* __restrict__ P,
                                                  const int* __restrict__ po,
                                                  const int* __restrict__ pc,
                                                  const int* __restrict__ spk,
                                                  const int* __restrict__ rp,
                                                  unsigned* __restrict__ dAll) {
  __shared__ float sT[2 * DD];
  int tid = threadIdx.x;
  sT[tid] = Tt[tid];
  __syncthreads();
  int row = blockIdx.x * 4 + (tid >> 6);
  if (row >= NN) return;
  int l = tid & 63, g = l >> 4, j = l & 15;
  float cw3 = P[4];
  int s = rp[row], e = rp[row + 1];
  float acc[8] = {0.f, 0.f, 0.f, 0.f, 0.f, 0.f, 0.f, 0.f};
  int i0 = s + g;
  uint4 qA = {0, 0, 0, 0}, kA = {0, 0, 0, 0};
  uint4 qB = {0, 0, 0, 0}, kB = {0, 0, 0, 0};
  int taA = 0, taB = 0;
  float scA = 0.f, lcA = 0.f, scB = 0.f, lcB = 0.f;
  if (i0 < e) {
    int o = po[i0], c = pc[i0], sp = spk[i0];
    taA = sp & 1; scA = s3c[sp >> 1]; lcA = L3[c];
    qA = *(const uint4*)(QK + (size_t)c * UU + 128 + j * 4);
    kA = *(const uint4*)(QK + (size_t)o * UU + 192 + j * 4);
  }
  if (i0 + 4 < e) {
    int o = po[i0 + 4], c = pc[i0 + 4], sp = spk[i0 + 4];
    taB = sp & 1; scB = s3c[sp >> 1]; lcB = L3[c];
    qB = *(const uint4*)(QK + (size_t)c * UU + 128 + j * 4);
    kB = *(const uint4*)(QK + (size_t)o * UU + 192 + j * 4);
  }
  for (int i = i0; i < e; i += 4) {
    uint4 qC = {0, 0, 0, 0}, kC = {0, 0, 0, 0}; int taC = 0;
    float scC = 0.f, lcC = 0.f;
    if (i + 8 < e) {
      int o = po[i + 8], c = pc[i + 8], sp = spk[i + 8];
      taC = sp & 1; scC = s3c[sp >> 1]; lcC = L3[c];
      qC = *(const uint4*)(QK + (size_t)c * UU + 128 + j * 4);
      kC = *(const uint4*)(QK + (size_t)o * UU + 192 + j * 4);
    }
    float w = cw3 * __expf(scA - lcA);
    float qv[8], ko[8]; unp8(qA, qv); unp8(kA, ko);
    const float* tv = &sT[taA * DD + j * 8];
#pragma unroll
    for (int t = 0; t < 8; t++) acc[t] = fmaf(w * tv[t], qv[t] * ko[t], acc[t]);
    qA = qB; kA = kB; taA = taB; scA = scB; lcA = lcB;
    qB = qC; kB = kC; taB = taC; scB = scC; lcB = lcC;
  }
#pragma unroll
  for (int t = 0; t < 8; t++) {
    float v = acc[t];
    v += __shfl_xor(v, 16, 64);
    v += __shfl_xor(v, 32, 64);
    acc[t] = v;
  }
  if (g == 0) *(uint4*)(dAll + (size_t)row * UU + 192 + j * 4) = pk8(acc);
}

// ---------------- memory-bank energy ----------------
__global__ __launch_bounds__(256) void em_row(const unsigned* __restrict__ QK,
                                              const float* __restrict__ Km,
                                              const float* __restrict__ P,
                                              unsigned* __restrict__ dAll,
                                              float* __restrict__ Lm) {
  __shared__ float sKm[KM * DD];
  int tid = threadIdx.x;
  for (int i = tid; i < KM * DD; i += 256) sKm[i] = Km[i];
  __syncthreads();
  int row = blockIdx.x * 4 + (tid >> 6);
  if (row >= NN) return;
  int l = tid & 63, g = l >> 4, j = l & 15;
  float bms = P[2] * INV_SQRT_D, cwm = P[5];
  float q[8];
  unp8(*(const uint4*)(QK + (size_t)row * UU + 256 + j * 4), q);
  float dk[8];
#pragma unroll
  for (int kk = 0; kk < 8; kk++) {
    int k = g * 8 + kk;
    const float* kr = &sKm[k * DD + j * 8];
    float d = 0.f;
#pragma unroll
    for (int t = 0; t < 8; t++) d = fmaf(q[t], kr[t], d);
    dk[kk] = redsum16(d) * bms;
  }
  float m = dk[0];
#pragma unroll
  for (int kk = 1; kk < 8; kk++) m = fmaxf(m, dk[kk]);
  float mx = fmaxf(m, __shfl_xor(m, 16, 64));
  mx = fmaxf(mx, __shfl_xor(mx, 32, 64));
  float p[8], z = 0.f;
#pragma unroll
  for (int kk = 0; kk < 8; kk++) { p[kk] = __expf(dk[kk] - mx); z += p[kk]; }
  float zz = z;
  zz += __shfl_xor(zz, 16, 64);
  zz += __shfl_xor(zz, 32, 64);
  if (l == 0) Lm[row] = mx + __logf(zz);
  float coef = cwm / zz;
  float acc[8] = {0.f, 0.f, 0.f, 0.f, 0.f, 0.f, 0.f, 0.f};
#pragma unroll
  for (int kk = 0; kk < 8; kk++) {
    int k = g * 8 + kk;
    const float* kr = &sKm[k * DD + j * 8];
    float pc_ = p[kk] * coef;
#pragma unroll
    for (int t = 0; t < 8; t++) acc[t] = fmaf(pc_, kr[t], acc[t]);
  }
#pragma unroll
  for (int t = 0; t < 8; t++) {
    float v = acc[t];
    v += __shfl_xor(v, 16, 64);
    v += __shfl_xor(v, 32, 64);
    acc[t] = v;
  }
  if (g == 0) *(uint4*)(dAll + (size_t)row * UU + 256 + j * 4) = pk8(acc);
}

// ---------------- LN backward + clips + update ----------------
__global__ __launch_bounds__(256) void ln_bwd(const float* __restrict__ X,
                                              const unsigned* __restrict__ dG,
                                              const float* __restrict__ gamma,
                                              const float* __restrict__ meanv,
                                              const float* __restrict__ rstdv,
                                              float* __restrict__ out) {
  int row = blockIdx.x * 4 + (threadIdx.x >> 6);
  if (row >= NN) return;
  int l = threadIdx.x & 63;
  float mu = meanv[row], rstd = rstdv[row];
  float2 x2 = *(const float2*)(X + row * DD + 2 * l);
  unsigned gw = dG[(size_t)row * 64 + l];
  float2 ga = *(const float2*)(gamma + 2 * l);
  float xh0 = (x2.x - mu) * rstd, xh1 = (x2.y - mu) * rstd;
  float dh0 = blo(gw) * ga.x, dh1 = bhi(gw) * ga.y;
  float sa = wredsum(dh0 + dh1) * (1.f / DD);
  float sb = wredsum(dh0 * xh0 + dh1 * xh1) * (1.f / DD);
  float dx0 = rstd * (dh0 - sa - xh0 * sb);
  float dx1 = rstd * (dh1 - sa - xh1 * sb);
  float gn = fmaxf(sqrtf(wredsum(dx0 * dx0 + dx1 * dx1)), 1e-6f);
  float sc = fminf(1.f / gn, 1.f);
  dx0 *= sc; dx1 *= sc;
  float xn0 = x2.x - 0.1f * 0.9999f * dx0;
  float xn1 = x2.y - 0.1f * 0.9999f * dx1;
  float sn = fmaxf(sqrtf(wredsum(xn0 * xn0 + xn1 * xn1)), 1e-6f);
  float sc2 = fminf(10.f / sn, 1.f);
  float2 o; o.x = xn0 * sc2; o.y = xn1 * sc2;
  *(float2*)(out + row * DD + 2 * l) = o;
}

// ---------------- final energy scalar (parallel, atomic) ----------------
__global__ __launch_bounds__(256) void eval_write(const float* __restrict__ L2,
                                                  const float* __restrict__ L3,
                                                  const float* __restrict__ Lm,
                                                  const float* __restrict__ P,
                                                  float* __restrict__ out) {
  int i = blockIdx.x * 256 + threadIdx.x;
  float a2 = 0.f, a3 = 0.f, am = 0.f;
  if (i < NN) { a2 = L2[i]; a3 = L3[i]; am = Lm[i]; }
  a2 = wredsum(a2); a3 = wredsum(a3); am = wredsum(am);
  __shared__ float r2[4], r3[4], rm[4];
  int wv = threadIdx.x >> 6, l = threadIdx.x & 63;
  if (l == 0) { r2[wv] = a2; r3[wv] = a3; rm[wv] = am; }
  __syncthreads();
  if (threadIdx.x == 0) {
    float S2 = r2[0] + r2[1] + r2[2] + r2[3];
    float S3 = r3[0] + r3[1] + r3[2] + r3[3];
    float Sm = rm[0] + rm[1] + rm[2] + rm[3];
    atomicAdd(out, P[6] * S2 + P[7] * S3 + P[8] * Sm);
  }
}

extern "C" void kernel_launch(void* const* d_in, const int* in_sizes, int n_in,
                              void* d_out, int out_size, void* d_ws, size_t ws_size,
                              hipStream_t stream) {
  (void)in_sizes; (void)n_in; (void)out_size;
  const float* X = (const float*)d_in[0];
  const float* EA = (const float*)d_in[1];
  const float* ln_g = (const float*)d_in[2];
  const float* ln_b = (const float*)d_in[3];
  const float* W_Q2 = (const float*)d_in[4];
  const float* W_K2 = (const float*)d_in[5];
  const float* W_Q3 = (const float*)d_in[6];
  const float* W_K3 = (const float*)d_in[7];
  const float* T_tau = (const float*)d_in[8];
  const float* W_Qm = (const float*)d_in[9];
  const float* W_Km = (const float*)d_in[10];
  const float* B_mem = (const float*)d_in[11];
  const float* We1 = (const float*)d_in[12];
  const float* be1 = (const float*)d_in[13];
  const float* We2 = (const float*)d_in[14];
  const float* be2 = (const float*)d_in[15];
  const float* l2s = (const float*)d_in[16];
  const float* l3s = (const float*)d_in[17];
  const float* lms = (const float*)d_in[18];
  const float* b2s = (const float*)d_in[19];
  const float* b3s = (const float*)d_in[20];
  const float* bms = (const float*)d_in[21];
  const int* c2 = (const int*)d_in[22];
  const int* u2 = (const int*)d_in[23];
  const int* c3 = (const int*)d_in[24];
  const int* u3 = (const int*)d_in[25];
  const int* v3 = (const int*)d_in[26];
  const int* ttau = (const int*)d_in[27];
  float* out = (float*)d_out;

  float* ws = (float*)d_ws;
  size_t off = 0;
  auto alloc = [&](size_t n) { float* p = ws + off; off += n; return p; };
  const size_t ND = (size_t)NN * DD;
  unsigned* Gb = (unsigned*)alloc(ND / 2);
  unsigned* QKall = (unsigned*)alloc((size_t)NN * UU);
  unsigned* dAll = (unsigned*)alloc((size_t)NN * UU);
  unsigned* dG = (unsigned*)alloc(ND / 2);
  ushort_t* Wt5 = (ushort_t*)alloc(640 * 128 / 2);
  ushort_t* Wcat = (ushort_t*)alloc(640 * 128 / 2);
  float* Km = alloc((size_t)KM * DD);
  float* a2 = alloc(EE);
  float* s2c = alloc(EE);
  float* s3c = alloc(TT);
  float* meanv = alloc(NN);
  float* rstdv = alloc(NN);
  float* L2 = alloc(NN);
  float* L3 = alloc(NN);
  float* Lm = alloc(NN);
  float* Pparams = alloc(16);
  int* cnt = (int*)alloc(4 * (size_t)NN);
  int* rowptr = (int*)alloc(4 * (size_t)(NN + 1));
  int* cursor = (int*)alloc(4 * (size_t)NN);
  int* spart = (int*)alloc(4 * SCAN_NB);
  int* part_c2 = (int*)alloc(EE);
  float* apay_c2 = alloc(EE);
  int* slot_u2 = (int*)alloc(EE);
  int* part_u2 = (int*)alloc(EE);
  int* pu_c3 = (int*)alloc(TT);
  int* pv_c3 = (int*)alloc(TT);
  int* ta_c3 = (int*)alloc(TT);
  int* po_uv = (int*)alloc(2 * (size_t)TT);
  int* pc_uv = (int*)alloc(2 * (size_t)TT);
  int* spk_uv = (int*)alloc(2 * (size_t)TT);
  if (off * sizeof(float) > ws_size) return;

  int* cnt_c2 = cnt, *cnt_u2 = cnt + NN, *cnt_c3 = cnt + 2 * NN, *cnt_uv = cnt + 3 * NN;
  int* rp_c2 = rowptr, *rp_u2 = rowptr + (NN + 1), *rp_c3 = rowptr + 2 * (NN + 1), *rp_uv = rowptr + 3 * (NN + 1);
  int* cu_c2 = cursor, *cu_u2 = cursor + NN, *cu_c3 = cursor + 2 * NN, *cu_uv = cursor + 3 * NN;

  hipMemsetAsync(cnt, 0, 4ull * NN * sizeof(int), stream);
  hipMemsetAsync(out + ND, 0, sizeof(float), stream);

  params_k<<<1, 64, 0, stream>>>(l2s, l3s, lms, b2s, b3s, bms, Pparams);

  int rowB = (NN + 3) / 4;
  int mB = (NN + 63) / 64;

  ln_fwd<<<rowB, 256, 0, stream>>>(X, ln_g, ln_b, Gb, meanv, rstdv);
  w_conv<<<320, 256, 0, stream>>>(W_Q2, W_K2, W_Q3, W_K3, W_Qm, Wt5, Wcat);
  mfma_fwd<<<dim3(mB, 10), 256, 0, stream>>>((const ushort_t*)Gb, Wt5, (ushort_t*)QKall, NN);
  gemm_km<<<1, 256, 0, stream>>>(B_mem, W_Km, Km, KM);
  edge_mlp<<<EE / 256, 256, 0, stream>>>(EA, We1, be1, We2, be2, a2);

  hist2<<<(EE + 255) / 256, 256, 0, stream>>>(c2, u2, cnt_c2, cnt_u2, EE);
  hist_t3<<<(TT + 255) / 256, 256, 0, stream>>>(c3, u3, v3, cnt_c3, cnt_uv, TT);
  scan_p1<<<dim3(SCAN_NB, 4), 256, 0, stream>>>(cnt, spart);
  scan_p2<<<1, 256, 0, stream>>>(spart);
  scan_p3<<<dim3(SCAN_NB, 4), 256, 0, stream>>>(cnt, spart, rowptr, cursor);
  scat2<<<(EE + 255) / 256, 256, 0, stream>>>(c2, u2, a2, cu_c2, cu_u2,
                                              part_c2, apay_c2, slot_u2, part_u2, EE);
  scat_t3<<<(TT + 255) / 256, 256, 0, stream>>>(c3, u3, v3, ttau, cu_c3, cu_uv,
                                                pu_c3, pv_c3, ta_c3,
                                                po_uv, pc_uv, spk_uv, TT);

  e2_fused<<<rowB, 256, 0, stream>>>(QKall, Pparams, part_c2, apay_c2, rp_c2, s2c, L2, dAll);
  dk2_gather<<<rowB, 256, 0, stream>>>(QKall, s2c, L2, Pparams, slot_u2, part_u2, rp_u2, dAll);
  t3_fused<<<rowB, 256, 0, stream>>>(QKall, T_tau, Pparams, pu_c3, pv_c3, ta_c3, rp_c3, s3c, L3, dAll);
  dk3_gather<<<rowB, 256, 0, stream>>>(QKall, T_tau, s3c, L3, Pparams, po_uv, pc_uv, spk_uv, rp_uv, dAll);
  em_row<<<rowB, 256, 0, stream>>>(QKall, Km, Pparams, dAll, Lm);

  mfma_bwd<<<dim3(mB, 2), 256, 0, stream>>>((const ushort_t*)dAll, Wcat, dG, NN);

  ln_bwd<<<rowB, 256, 0, stream>>>(X, dG, ln_g, meanv, rstdv, out);
  eval_write<<<(NN + 255) / 256, 256, 0, stream>>>(L2, L3, Lm, Pparams, out + ND);
}